// Round 1
// baseline (820.259 us; speedup 1.0000x reference)
//
#include <hip/hip_runtime.h>
#include <math.h>

// ---------------------------------------------------------------------------
// LoRA T5 decoder layer on MI355X (gfx950).
// B=4, L=ENC=512, D=1024, H=16, HD=64, MLP=4096, R=32.
// All dense matmuls: bf16 MFMA 16x16x32, 128x128 tiles (m97 structure),
// global_load_lds width-16 staging, weights pre-transposed to [N][K] bf16.
// ---------------------------------------------------------------------------

#define DEV __device__ __forceinline__

typedef __bf16 bf16x8 __attribute__((ext_vector_type(8)));
typedef float floatx4 __attribute__((ext_vector_type(4)));

typedef __attribute__((address_space(1))) void* gas_ptr;
typedef __attribute__((address_space(3))) void* las_ptr;

DEV unsigned short f2bf(float f) {
  union { float f; unsigned int u; } v; v.f = f;
  unsigned int r = v.u + 0x7fffu + ((v.u >> 16) & 1u);
  return (unsigned short)(r >> 16);
}
DEV float bf2f(unsigned short u) {
  union { unsigned int u; float f; } v; v.u = ((unsigned int)u) << 16;
  return v.f;
}

#define GLOAD_LDS16(g, l) __builtin_amdgcn_global_load_lds((gas_ptr)(g), (las_ptr)(l), 16, 0, 0)

// Stage a tile of `nrows` rows x 64 bf16 (128 B/row) from global (row stride
// ldbytes) into contiguous LDS. 1 KiB chunk per wave-instruction (64 lanes x 16B).
template<int NW>
DEV void stage_tile(const char* gbase, char* lds, int nrows, int ldbytes, int wave, int lane) {
  int nchunks = nrows >> 3;               // 8 rows per 1 KiB chunk
  for (int c = wave; c < nchunks; c += NW) {
    int row  = (c << 3) + (lane >> 3);
    int colb = (lane & 7) << 4;
    GLOAD_LDS16(gbase + (size_t)row * ldbytes + colb, lds + (c << 10));
  }
}

// C[m0..m0+64*WM, n0..n0+64*WN] = A[M,K] * Bt[N,K]^T, bf16 in / fp32 out.
// Wave (wm,wn) owns a 64x64 subtile = 4x4 MFMA tiles.
// Fragment layouts (measured, guide §3): A: lane holds A[m=lane&15][k=quad*8+j];
// Bt frag identical with n=lane&15; D: row=quad*4+r, col=lane&15.
template<int WM, int WN, bool RESID, bool MIRROR>
DEV void gemm_core(const unsigned short* A, const unsigned short* Bt, float* C,
                   const float* resid, unsigned short* mirror,
                   int K, int lda, int ldb, int ldc, int m0, int n0,
                   char* ldsA, char* ldsB) {
  constexpr int NW = WM * WN;
  const int tid  = threadIdx.x;
  const int lane = tid & 63;
  const int wave = tid >> 6;
  const int wm   = wave % WM;
  const int wn   = wave / WM;
  const int quad = lane >> 4;
  const int l15  = lane & 15;

  floatx4 acc[4][4];
#pragma unroll
  for (int i = 0; i < 4; ++i)
#pragma unroll
    for (int j = 0; j < 4; ++j) acc[i][j] = (floatx4){0.f, 0.f, 0.f, 0.f};

  const char* gA = (const char*)(A + (size_t)m0 * lda);
  const char* gB = (const char*)(Bt + (size_t)n0 * ldb);

  for (int k0 = 0; k0 < K; k0 += 64) {
    stage_tile<NW>(gA + (size_t)k0 * 2, ldsA, WM * 64, lda * 2, wave, lane);
    stage_tile<NW>(gB + (size_t)k0 * 2, ldsB, WN * 64, ldb * 2, wave, lane);
    __syncthreads();   // compiler drains vmcnt for global_load_lds here
#pragma unroll
    for (int kk = 0; kk < 64; kk += 32) {
      bf16x8 af[4], bv[4];
      const char* baseA = ldsA + (size_t)(wm * 64 + l15) * 128 + (kk + quad * 8) * 2;
      const char* baseB = ldsB + (size_t)(wn * 64 + l15) * 128 + (kk + quad * 8) * 2;
#pragma unroll
      for (int mi = 0; mi < 4; ++mi) af[mi] = *(const bf16x8*)(baseA + mi * 2048);
#pragma unroll
      for (int ni = 0; ni < 4; ++ni) bv[ni] = *(const bf16x8*)(baseB + ni * 2048);
#pragma unroll
      for (int mi = 0; mi < 4; ++mi)
#pragma unroll
        for (int ni = 0; ni < 4; ++ni)
          acc[mi][ni] = __builtin_amdgcn_mfma_f32_16x16x32_bf16(af[mi], bv[ni], acc[mi][ni], 0, 0, 0);
    }
    __syncthreads();
  }

#pragma unroll
  for (int mi = 0; mi < 4; ++mi) {
#pragma unroll
    for (int r = 0; r < 4; ++r) {
      int row = m0 + wm * 64 + mi * 16 + quad * 4 + r;
#pragma unroll
      for (int ni = 0; ni < 4; ++ni) {
        int col = n0 + wn * 64 + ni * 16 + l15;
        float v = acc[mi][ni][r];
        if (RESID) v += resid[(size_t)row * ldc + col];
        C[(size_t)row * ldc + col] = v;
        if (MIRROR) mirror[(size_t)row * ldc + col] = f2bf(v);
      }
    }
  }
}

// ---------------- GEMM wrappers ----------------

struct G3 {
  const unsigned short* A[3];
  const unsigned short* B[3];
  float* C[3];
  int K, lda, ldb, ldc;
};
__global__ __launch_bounds__(256) void k_gemm3(G3 g) {
  __shared__ char lds[32768];
  int z = blockIdx.z;
  gemm_core<2, 2, false, false>(g.A[z], g.B[z], g.C[z], nullptr, nullptr,
                                g.K, g.lda, g.ldb, g.ldc,
                                blockIdx.y * 128, blockIdx.x * 128, lds, lds + 16384);
}

template<bool RESID>
__global__ __launch_bounds__(256) void k_gemm1(const unsigned short* A, const unsigned short* Bt,
                                               float* C, const float* resid,
                                               int K, int lda, int ldb, int ldc) {
  __shared__ char lds[32768];
  gemm_core<2, 2, RESID, false>(A, Bt, C, resid, nullptr, K, lda, ldb, ldc,
                                blockIdx.y * 128, blockIdx.x * 128, lds, lds + 16384);
}

// scores[z][q][k] = sum_d q[b,q,h,d] * k[b,k,h,d]   (z = b*16+h, K=64)
__global__ __launch_bounds__(256) void k_gemm_qk(const unsigned short* q, const unsigned short* kmat,
                                                 float* scores) {
  __shared__ char lds[32768];
  int z = blockIdx.z, b = z >> 4, h = z & 15;
  const unsigned short* A  = q    + (size_t)b * 512 * 1024 + h * 64;
  const unsigned short* Bt = kmat + (size_t)b * 512 * 1024 + h * 64;
  float* C = scores + (size_t)z * 512 * 512;
  gemm_core<2, 2, false, false>(A, Bt, C, nullptr, nullptr, 64, 1024, 1024, 512,
                                blockIdx.y * 128, blockIdx.x * 128, lds, lds + 16384);
}

// ctx[b,q,h,d] = sum_k probs[z][q][k] * vt[z][d][k]
__global__ __launch_bounds__(128) void k_gemm_pv(const unsigned short* probs, const unsigned short* vt,
                                                 float* ctx, unsigned short* ctxb) {
  __shared__ char lds[24576];
  int z = blockIdx.z, b = z >> 4, h = z & 15;
  const unsigned short* A  = probs + (size_t)z * 512 * 512;
  const unsigned short* Bt = vt    + (size_t)z * 64 * 512;
  float* C            = ctx  + (size_t)b * 512 * 1024 + h * 64;
  unsigned short* Mi  = ctxb + (size_t)b * 512 * 1024 + h * 64;
  gemm_core<2, 1, false, true>(A, Bt, C, nullptr, Mi, 512, 512, 512, 1024,
                               blockIdx.y * 128, 0, lds, lds + 16384);
}

// ---------------- small kernels ----------------

// fp32 [K][N] -> bf16 [N][K] for all 11 weight matrices in one launch.
struct WtArgs {
  const float* src[11];
  unsigned short* dst[11];
  int K[11], N[11];
  int tstart[12];
};
__global__ __launch_bounds__(256) void k_wtconv(WtArgs a) {
  int bid = blockIdx.x;
  int z = 0;
  while (z < 10 && bid >= a.tstart[z + 1]) ++z;
  int tile = bid - a.tstart[z];
  int N = a.N[z], K = a.K[z];
  int ntn = N >> 5;
  int tn = tile % ntn, tk = tile / ntn;
  __shared__ float tl[32][33];
  int t = threadIdx.x, tx = t & 31, ty = t >> 5;
  const float* src = a.src[z];
  unsigned short* dst = a.dst[z];
#pragma unroll
  for (int i = 0; i < 32; i += 8)
    tl[ty + i][tx] = src[(size_t)(tk * 32 + ty + i) * N + tn * 32 + tx];
  __syncthreads();
#pragma unroll
  for (int i = 0; i < 32; i += 8)
    dst[(size_t)(tn * 32 + ty + i) * K + tk * 32 + tx] = f2bf(tl[tx][ty + i]);
}

__global__ void k_f2bf(const float* in, unsigned short* out) {
  int i = blockIdx.x * 256 + threadIdx.x;
  float4 v = ((const float4*)in)[i];
  ushort4 o;
  o.x = f2bf(v.x); o.y = f2bf(v.y); o.z = f2bf(v.z); o.w = f2bf(v.w);
  ((ushort4*)out)[i] = o;
}

// T5 relative-position bias: rb[h][d] for d = q-k in [0,511]
__global__ void k_relbias(const float* table, float* rb) {
  int i = blockIdx.x * 256 + threadIdx.x;
  if (i >= 16 * 512) return;
  int h = i >> 9, d = i & 511;
  int bucket;
  if (d < 16) bucket = d;
  else {
    int lb = 16 + (int)(logf((float)d / 16.0f) / logf(8.0f) * 16.0f);
    bucket = lb < 31 ? lb : 31;
  }
  rb[i] = table[bucket * 16 + h];
}

__global__ __launch_bounds__(256) void k_rmsnorm(const float* x, const float* sc, unsigned short* out) {
  int row = blockIdx.x, t = threadIdx.x;
  float4 v = ((const float4*)(x + (size_t)row * 1024))[t];
  float ss = v.x * v.x + v.y * v.y + v.z * v.z + v.w * v.w;
  for (int o = 32; o; o >>= 1) ss += __shfl_down(ss, o);
  __shared__ float red[4];
  if ((t & 63) == 0) red[t >> 6] = ss;
  __syncthreads();
  float tot = red[0] + red[1] + red[2] + red[3];
  float rs = rsqrtf(tot * (1.0f / 1024.0f) + 1e-6f);
  float4 s4 = ((const float4*)sc)[t];
  ushort4 o;
  o.x = f2bf(v.x * rs * s4.x); o.y = f2bf(v.y * rs * s4.y);
  o.z = f2bf(v.z * rs * s4.z); o.w = f2bf(v.w * rs * s4.w);
  ((ushort4*)(out + (size_t)row * 1024))[t] = o;
}

// softmax over k of scores*0.125 (+ rel bias + causal mask if CAUSAL) -> bf16 probs
template<bool CAUSAL>
__global__ __launch_bounds__(256) void k_softmax(const float* scores, const float* rb, unsigned short* probs) {
  int q = blockIdx.x, z = blockIdx.y, h = z & 15;
  const float* srow = scores + ((size_t)z * 512 + q) * 512;
  unsigned short* prow = probs + ((size_t)z * 512 + q) * 512;
  int t = threadIdx.x;
  float v0 = srow[t] * 0.125f;
  float v1 = srow[t + 256] * 0.125f;
  if (CAUSAL) {
    v0 = (t <= q) ? v0 + rb[h * 512 + (q - t)] : -1e30f;
    int k1 = t + 256;
    v1 = (k1 <= q) ? v1 + rb[h * 512 + (q - k1)] : -1e30f;
  }
  float m = fmaxf(v0, v1);
  for (int o = 32; o; o >>= 1) m = fmaxf(m, __shfl_down(m, o));
  __shared__ float redm[4], reds[4];
  if ((t & 63) == 0) redm[t >> 6] = m;
  __syncthreads();
  m = fmaxf(fmaxf(redm[0], redm[1]), fmaxf(redm[2], redm[3]));
  float e0 = expf(v0 - m), e1 = expf(v1 - m);
  float s = e0 + e1;
  for (int o = 32; o; o >>= 1) s += __shfl_down(s, o);
  if ((t & 63) == 0) reds[t >> 6] = s;
  __syncthreads();
  s = reds[0] + reds[1] + reds[2] + reds[3];
  float inv = 1.0f / s;
  prow[t] = f2bf(e0 * inv);
  prow[t + 256] = f2bf(e1 * inv);
}

// v[b,k,h,d] fp32 -> vt[z=b*16+h][d][k] bf16
__global__ __launch_bounds__(256) void k_vtrans(const float* vf, unsigned short* vt) {
  int z = blockIdx.y, b = z >> 4, h = z & 15;
  int k0 = blockIdx.x * 64;
  __shared__ float tl[64][65];
  int t = threadIdx.x;
  int d = t & 63, kr = t >> 6;
#pragma unroll
  for (int i = 0; i < 64; i += 4)
    tl[kr + i][d] = vf[(size_t)(b * 512 + k0 + kr + i) * 1024 + h * 64 + d];
  __syncthreads();
  int dw = t >> 2, kc = (t & 3) * 16;
  unsigned short* dst = vt + ((size_t)z * 64 + dw) * 512 + k0 + kc;
#pragma unroll
  for (int j = 0; j < 16; ++j) dst[j] = f2bf(tl[kc + j][dw]);
}

// low[z][row][r] = sum_k x[row][k] * a[b][k][r]   (a pre-offset by sel)
struct Low3 {
  const unsigned short* x[3];
  const float* a[3];
  float* low[3];
};
__global__ __launch_bounds__(256) void k_lora_low(Low3 g) {
  int z = blockIdx.z, row = blockIdx.x;
  int b = row >> 9;
  const unsigned short* x = g.x[z] + (size_t)row * 1024;
  const float* a = g.a[z] + ((size_t)b << 16);   // b stride = 2*D*R = 65536
  int t = threadIdx.x, r = t & 31, kc = t >> 5;
  float s = 0.f;
  int kbase = kc * 128;
  for (int i = 0; i < 128; ++i) {
    int k = kbase + i;
    s += bf2f(x[k]) * a[(size_t)k * 32 + r];
  }
  __shared__ float red[256];
  red[t] = s;
  __syncthreads();
  if (t < 32) {
    float tot = 0.f;
    for (int j = 0; j < 8; ++j) tot += red[j * 32 + t];
    g.low[z][(size_t)row * 32 + t] = tot;
  }
}

// gout = gin + low@bmat (+resid), optional bf16 mirror
struct Addb3 {
  const float* low[3];
  const float* bm[3];
  const float* gin[3];
  float* gout[3];
  const float* resid[3];
  unsigned short* mirror[3];
};
__global__ __launch_bounds__(256) void k_lora_addb(Addb3 g) {
  int z = blockIdx.z, row = blockIdx.x;
  int b = row >> 9;
  const float* bm = g.bm[z] + ((size_t)b << 16);
  int t = threadIdx.x;
  __shared__ float lsh[32];
  if (t < 32) lsh[t] = g.low[z][(size_t)row * 32 + t];
  __syncthreads();
  float ax = 0, ay = 0, az = 0, aw = 0;
  for (int r = 0; r < 32; ++r) {
    float lv = lsh[r];
    float4 b4 = ((const float4*)(bm + (size_t)r * 1024))[t];
    ax += lv * b4.x; ay += lv * b4.y; az += lv * b4.z; aw += lv * b4.w;
  }
  size_t idx = (size_t)row * 256 + t;
  float4 gv = ((const float4*)g.gin[z])[idx];
  ax += gv.x; ay += gv.y; az += gv.z; aw += gv.w;
  if (g.resid[z]) {
    float4 rv = ((const float4*)g.resid[z])[idx];
    ax += rv.x; ay += rv.y; az += rv.z; aw += rv.w;
  }
  float4 o; o.x = ax; o.y = ay; o.z = az; o.w = aw;
  ((float4*)g.gout[z])[idx] = o;
  if (g.mirror[z]) {
    ushort4 mo; mo.x = f2bf(ax); mo.y = f2bf(ay); mo.z = f2bf(az); mo.w = f2bf(aw);
    ((ushort4*)g.mirror[z])[idx] = mo;
  }
}

// h = gelu_exact(h0) * h1 -> bf16
__global__ void k_gelumul(const float* h0, const float* h1, unsigned short* out) {
  int i = blockIdx.x * 256 + threadIdx.x;
  float4 a = ((const float4*)h0)[i];
  float4 b = ((const float4*)h1)[i];
  ushort4 o;
  o.x = f2bf(0.5f * a.x * (1.0f + erff(a.x * 0.70710678f)) * b.x);
  o.y = f2bf(0.5f * a.y * (1.0f + erff(a.y * 0.70710678f)) * b.y);
  o.z = f2bf(0.5f * a.z * (1.0f + erff(a.z * 0.70710678f)) * b.z);
  o.w = f2bf(0.5f * a.w * (1.0f + erff(a.w * 0.70710678f)) * b.w);
  ((ushort4*)out)[i] = o;
}

// ---------------------------------------------------------------------------

extern "C" void kernel_launch(void* const* d_in, const int* in_sizes, int n_in,
                              void* d_out, int out_size, void* d_ws, size_t ws_size,
                              hipStream_t stream) {
  const float* f_inputs  = (const float*)d_in[0];
  const float* f_encoded = (const float*)d_in[1];
  const float* f_qa = (const float*)d_in[2];
  const float* f_qb = (const float*)d_in[3];
  const float* f_ka = (const float*)d_in[4];
  const float* f_kb = (const float*)d_in[5];
  const float* f_va = (const float*)d_in[6];
  const float* f_vb = (const float*)d_in[7];
  const float* f_oa = (const float*)d_in[8];
  const float* f_ob = (const float*)d_in[9];
  const float* f_table = (const float*)d_in[10];
  const float* f_ln1 = (const float*)d_in[11];
  const float* f_ln2 = (const float*)d_in[12];
  const float* f_ln3 = (const float*)d_in[13];
  const float* f_W[8] = { (const float*)d_in[14], (const float*)d_in[15],
                          (const float*)d_in[16], (const float*)d_in[17],
                          (const float*)d_in[18], (const float*)d_in[19],
                          (const float*)d_in[20], (const float*)d_in[21] };
  const float* f_wi0 = (const float*)d_in[22];
  const float* f_wi1 = (const float*)d_in[23];
  const float* f_wo  = (const float*)d_in[24];

  const size_t SEL1 = 32768;   // sel stride in lora a/b arrays (D*R = R*D)

  // ---- workspace arena (~228 MB) ----
  char* w = (char*)d_ws;
  size_t off = 0;
  auto alloc = [&](size_t bytes) -> char* {
    off = (off + 255) & ~(size_t)255;
    char* p = w + off;
    off += bytes;
    return p;
  };
  unsigned short* wt[8];
  for (int i = 0; i < 8; ++i) wt[i] = (unsigned short*)alloc(1024 * 1024 * 2);
  unsigned short* wi0t = (unsigned short*)alloc(4096 * 1024 * 2);
  unsigned short* wi1t = (unsigned short*)alloc(4096 * 1024 * 2);
  unsigned short* wot  = (unsigned short*)alloc(1024 * 4096 * 2);
  unsigned short* encbf = (unsigned short*)alloc(2048 * 1024 * 2);
  float* rb = (float*)alloc(16 * 512 * 4);
  unsigned short* xn = (unsigned short*)alloc(2048 * 1024 * 2);
  float* qf = (float*)alloc(2048 * 1024 * 4);
  float* kf = (float*)alloc(2048 * 1024 * 4);
  float* vf = (float*)alloc(2048 * 1024 * 4);
  unsigned short* qbf = (unsigned short*)alloc(2048 * 1024 * 2);
  unsigned short* kbf = (unsigned short*)alloc(2048 * 1024 * 2);
  unsigned short* vtb = (unsigned short*)alloc((size_t)64 * 64 * 512 * 2);
  float* low0 = (float*)alloc(2048 * 32 * 4);
  float* low1 = (float*)alloc(2048 * 32 * 4);
  float* low2 = (float*)alloc(2048 * 32 * 4);
  float* scores = (float*)alloc((size_t)64 * 512 * 512 * 4);
  unsigned short* probs = (unsigned short*)alloc((size_t)64 * 512 * 512 * 2);
  float* ctxf = (float*)alloc(2048 * 1024 * 4);
  unsigned short* ctxb = (unsigned short*)alloc(2048 * 1024 * 2);
  float* octx = (float*)alloc(2048 * 1024 * 4);
  float* xres = (float*)alloc(2048 * 1024 * 4);
  float* yres = (float*)alloc(2048 * 1024 * 4);
  // MLP intermediates alias attention scratch (attention is finished by then)
  float* h0 = scores;                       // 2048*4096 floats
  float* h1 = scores + (size_t)2048 * 4096; // second half of scores region
  unsigned short* hbf = probs;              // 2048*4096 bf16 fits in probs region
  (void)ws_size; (void)in_sizes; (void)n_in; (void)out_size;

  // ---- weight convert + transpose (every launch: ws is re-poisoned) ----
  WtArgs wa;
  int ts = 0;
  for (int i = 0; i < 8; ++i) {
    wa.src[i] = f_W[i]; wa.dst[i] = wt[i]; wa.K[i] = 1024; wa.N[i] = 1024;
    wa.tstart[i] = ts; ts += 32 * 32;
  }
  wa.src[8] = f_wi0; wa.dst[8] = wi0t; wa.K[8] = 1024; wa.N[8] = 4096; wa.tstart[8] = ts; ts += 32 * 128;
  wa.src[9] = f_wi1; wa.dst[9] = wi1t; wa.K[9] = 1024; wa.N[9] = 4096; wa.tstart[9] = ts; ts += 32 * 128;
  wa.src[10] = f_wo; wa.dst[10] = wot; wa.K[10] = 4096; wa.N[10] = 1024; wa.tstart[10] = ts; ts += 128 * 32;
  wa.tstart[11] = ts;
  k_wtconv<<<dim3(ts), dim3(256), 0, stream>>>(wa);

  k_f2bf<<<dim3(2048), dim3(256), 0, stream>>>(f_encoded, encbf);
  k_relbias<<<dim3(32), dim3(256), 0, stream>>>(f_table, rb);

  // ================= self-attention =================
  k_rmsnorm<<<dim3(2048), dim3(256), 0, stream>>>(f_inputs, f_ln1, xn);

  G3 g_qkv = { {xn, xn, xn}, {wt[0], wt[1], wt[2]}, {qf, kf, vf}, 1024, 1024, 1024, 1024 };
  k_gemm3<<<dim3(8, 16, 3), dim3(256), 0, stream>>>(g_qkv);

  Low3 lo_s = { {xn, xn, xn}, {f_qa, f_ka, f_va}, {low0, low1, low2} };
  k_lora_low<<<dim3(2048, 1, 3), dim3(256), 0, stream>>>(lo_s);
  Addb3 ab_s = { {low0, low1, low2}, {f_qb, f_kb, f_vb}, {qf, kf, vf}, {qf, kf, vf},
                 {nullptr, nullptr, nullptr}, {qbf, kbf, nullptr} };
  k_lora_addb<<<dim3(2048, 1, 3), dim3(256), 0, stream>>>(ab_s);

  k_gemm_qk<<<dim3(4, 4, 64), dim3(256), 0, stream>>>(qbf, kbf, scores);
  k_softmax<true><<<dim3(512, 64), dim3(256), 0, stream>>>(scores, rb, probs);
  k_vtrans<<<dim3(8, 64), dim3(256), 0, stream>>>(vf, vtb);
  k_gemm_pv<<<dim3(1, 4, 64), dim3(128), 0, stream>>>(probs, vtb, ctxf, ctxb);

  k_gemm1<false><<<dim3(8, 16), dim3(256), 0, stream>>>(ctxb, wt[3], octx, nullptr, 1024, 1024, 1024, 1024);
  Low3 lo_o = { {ctxb, ctxb, ctxb}, {f_oa, f_oa, f_oa}, {low0, low0, low0} };
  k_lora_low<<<dim3(2048, 1, 1), dim3(256), 0, stream>>>(lo_o);
  Addb3 ab_o = { {low0, low0, low0}, {f_ob, f_ob, f_ob}, {octx, octx, octx}, {xres, xres, xres},
                 {f_inputs, f_inputs, f_inputs}, {nullptr, nullptr, nullptr} };
  k_lora_addb<<<dim3(2048, 1, 1), dim3(256), 0, stream>>>(ab_o);

  // ================= cross-attention =================
  k_rmsnorm<<<dim3(2048), dim3(256), 0, stream>>>(xres, f_ln2, xn);

  G3 g_cqkv = { {xn, encbf, encbf}, {wt[4], wt[5], wt[6]}, {qf, kf, vf}, 1024, 1024, 1024, 1024 };
  k_gemm3<<<dim3(8, 16, 3), dim3(256), 0, stream>>>(g_cqkv);

  Low3 lo_c = { {xn, encbf, encbf}, {f_qa + SEL1, f_ka + SEL1, f_va + SEL1}, {low0, low1, low2} };
  k_lora_low<<<dim3(2048, 1, 3), dim3(256), 0, stream>>>(lo_c);
  Addb3 ab_c = { {low0, low1, low2}, {f_qb + SEL1, f_kb + SEL1, f_vb + SEL1}, {qf, kf, vf}, {qf, kf, vf},
                 {nullptr, nullptr, nullptr}, {qbf, kbf, nullptr} };
  k_lora_addb<<<dim3(2048, 1, 3), dim3(256), 0, stream>>>(ab_c);

  k_gemm_qk<<<dim3(4, 4, 64), dim3(256), 0, stream>>>(qbf, kbf, scores);
  k_softmax<false><<<dim3(512, 64), dim3(256), 0, stream>>>(scores, rb, probs);
  k_vtrans<<<dim3(8, 64), dim3(256), 0, stream>>>(vf, vtb);
  k_gemm_pv<<<dim3(1, 4, 64), dim3(128), 0, stream>>>(probs, vtb, ctxf, ctxb);

  k_gemm1<false><<<dim3(8, 16), dim3(256), 0, stream>>>(ctxb, wt[7], octx, nullptr, 1024, 1024, 1024, 1024);
  Low3 lo_co = { {ctxb, ctxb, ctxb}, {f_oa + SEL1, f_oa + SEL1, f_oa + SEL1}, {low0, low0, low0} };
  k_lora_low<<<dim3(2048, 1, 1), dim3(256), 0, stream>>>(lo_co);
  Addb3 ab_co = { {low0, low0, low0}, {f_ob + SEL1, f_ob + SEL1, f_ob + SEL1}, {octx, octx, octx},
                  {yres, yres, yres}, {xres, xres, xres}, {nullptr, nullptr, nullptr} };
  k_lora_addb<<<dim3(2048, 1, 1), dim3(256), 0, stream>>>(ab_co);

  // ================= gated-gelu MLP =================
  k_rmsnorm<<<dim3(2048), dim3(256), 0, stream>>>(yres, f_ln3, xn);
  G3 g_mlp = { {xn, xn, xn}, {wi0t, wi1t, wi1t}, {h0, h1, h1}, 1024, 1024, 1024, 4096 };
  k_gemm3<<<dim3(32, 16, 2), dim3(256), 0, stream>>>(g_mlp);
  k_gelumul<<<dim3(8192), dim3(256), 0, stream>>>(h0, h1, hbf);
  k_gemm1<true><<<dim3(8, 16), dim3(256), 0, stream>>>(hbf, wot, (float*)d_out, yres, 4096, 4096, 4096, 1024);
}

// Round 2
// 744.476 us; speedup vs baseline: 1.1018x; 1.1018x over previous
//
#include <hip/hip_runtime.h>
#include <math.h>

// ---------------------------------------------------------------------------
// LoRA T5 decoder layer on MI355X (gfx950).
// B=4, L=ENC=512, D=1024, H=16, HD=64, MLP=4096, R=32.
// All dense matmuls: bf16 MFMA 16x16x32, 128x128 tiles (m97 structure),
// global_load_lds width-16 staging, weights pre-transposed to [N][K] bf16.
// R1->R2: split-K on the flat GEMMs (QKV S=2, out-proj S=2, MLP-final S=4)
// to fix grid starvation (128-384 blocks on 256 CUs -> >=512 blocks).
// Partials alias dead scores/probs regions; epilogues fuse the partial sums.
// ---------------------------------------------------------------------------

#define DEV __device__ __forceinline__

typedef __bf16 bf16x8 __attribute__((ext_vector_type(8)));
typedef float floatx4 __attribute__((ext_vector_type(4)));

typedef __attribute__((address_space(1))) void* gas_ptr;
typedef __attribute__((address_space(3))) void* las_ptr;

DEV unsigned short f2bf(float f) {
  union { float f; unsigned int u; } v; v.f = f;
  unsigned int r = v.u + 0x7fffu + ((v.u >> 16) & 1u);
  return (unsigned short)(r >> 16);
}
DEV float bf2f(unsigned short u) {
  union { unsigned int u; float f; } v; v.u = ((unsigned int)u) << 16;
  return v.f;
}

#define GLOAD_LDS16(g, l) __builtin_amdgcn_global_load_lds((gas_ptr)(g), (las_ptr)(l), 16, 0, 0)

template<int NW>
DEV void stage_tile(const char* gbase, char* lds, int nrows, int ldbytes, int wave, int lane) {
  int nchunks = nrows >> 3;               // 8 rows per 1 KiB chunk
  for (int c = wave; c < nchunks; c += NW) {
    int row  = (c << 3) + (lane >> 3);
    int colb = (lane & 7) << 4;
    GLOAD_LDS16(gbase + (size_t)row * ldbytes + colb, lds + (c << 10));
  }
}

// C[m0..m0+64*WM, n0..n0+64*WN] = A[M,K] * Bt[N,K]^T, bf16 in / fp32 out.
template<int WM, int WN, bool RESID, bool MIRROR>
DEV void gemm_core(const unsigned short* A, const unsigned short* Bt, float* C,
                   const float* resid, unsigned short* mirror,
                   int K, int lda, int ldb, int ldc, int m0, int n0,
                   char* ldsA, char* ldsB) {
  constexpr int NW = WM * WN;
  const int tid  = threadIdx.x;
  const int lane = tid & 63;
  const int wave = tid >> 6;
  const int wm   = wave % WM;
  const int wn   = wave / WM;
  const int quad = lane >> 4;
  const int l15  = lane & 15;

  floatx4 acc[4][4];
#pragma unroll
  for (int i = 0; i < 4; ++i)
#pragma unroll
    for (int j = 0; j < 4; ++j) acc[i][j] = (floatx4){0.f, 0.f, 0.f, 0.f};

  const char* gA = (const char*)(A + (size_t)m0 * lda);
  const char* gB = (const char*)(Bt + (size_t)n0 * ldb);

  for (int k0 = 0; k0 < K; k0 += 64) {
    stage_tile<NW>(gA + (size_t)k0 * 2, ldsA, WM * 64, lda * 2, wave, lane);
    stage_tile<NW>(gB + (size_t)k0 * 2, ldsB, WN * 64, ldb * 2, wave, lane);
    __syncthreads();
#pragma unroll
    for (int kk = 0; kk < 64; kk += 32) {
      bf16x8 af[4], bv[4];
      const char* baseA = ldsA + (size_t)(wm * 64 + l15) * 128 + (kk + quad * 8) * 2;
      const char* baseB = ldsB + (size_t)(wn * 64 + l15) * 128 + (kk + quad * 8) * 2;
#pragma unroll
      for (int mi = 0; mi < 4; ++mi) af[mi] = *(const bf16x8*)(baseA + mi * 2048);
#pragma unroll
      for (int ni = 0; ni < 4; ++ni) bv[ni] = *(const bf16x8*)(baseB + ni * 2048);
#pragma unroll
      for (int mi = 0; mi < 4; ++mi)
#pragma unroll
        for (int ni = 0; ni < 4; ++ni)
          acc[mi][ni] = __builtin_amdgcn_mfma_f32_16x16x32_bf16(af[mi], bv[ni], acc[mi][ni], 0, 0, 0);
    }
    __syncthreads();
  }

#pragma unroll
  for (int mi = 0; mi < 4; ++mi) {
#pragma unroll
    for (int r = 0; r < 4; ++r) {
      int row = m0 + wm * 64 + mi * 16 + quad * 4 + r;
#pragma unroll
      for (int ni = 0; ni < 4; ++ni) {
        int col = n0 + wn * 64 + ni * 16 + l15;
        float v = acc[mi][ni][r];
        if (RESID) v += resid[(size_t)row * ldc + col];
        C[(size_t)row * ldc + col] = v;
        if (MIRROR) mirror[(size_t)row * ldc + col] = f2bf(v);
      }
    }
  }
}

// ---------------- GEMM wrappers ----------------

// 3 batched GEMMs, each split S ways over K. blockIdx.z = gi*S + s.
// Partial s of gemm gi goes to C[gi] + s*pstride (elements).
struct G3S {
  const unsigned short* A[3];
  const unsigned short* B[3];
  float* C[3];
  int K, lda, ldb, ldc, S, Kchunk;
  size_t pstride;
};
__global__ __launch_bounds__(256) void k_gemm3s(G3S g) {
  __shared__ char lds[32768];
  int z = blockIdx.z;
  int gi = z / g.S, s = z - gi * g.S;
  size_t koff = (size_t)s * g.Kchunk;
  gemm_core<2, 2, false, false>(g.A[gi] + koff, g.B[gi] + koff,
                                g.C[gi] + (size_t)s * g.pstride, nullptr, nullptr,
                                g.Kchunk, g.lda, g.ldb, g.ldc,
                                blockIdx.y * 128, blockIdx.x * 128, lds, lds + 16384);
}

// single GEMM, split-K: blockIdx.z = s, partial to Cpart + s*pstride
__global__ __launch_bounds__(256) void k_gemm1s(const unsigned short* A, const unsigned short* Bt,
                                                float* Cpart, size_t pstride,
                                                int Kchunk, int lda, int ldb, int ldc) {
  __shared__ char lds[32768];
  int s = blockIdx.z;
  size_t koff = (size_t)s * Kchunk;
  gemm_core<2, 2, false, false>(A + koff, Bt + koff, Cpart + (size_t)s * pstride,
                                nullptr, nullptr, Kchunk, lda, ldb, ldc,
                                blockIdx.y * 128, blockIdx.x * 128, lds, lds + 16384);
}

// scores[z][q][k] = sum_d q[b,q,h,d] * k[b,k,h,d]   (z = b*16+h, K=64)
__global__ __launch_bounds__(256) void k_gemm_qk(const unsigned short* q, const unsigned short* kmat,
                                                 float* scores) {
  __shared__ char lds[32768];
  int z = blockIdx.z, b = z >> 4, h = z & 15;
  const unsigned short* A  = q    + (size_t)b * 512 * 1024 + h * 64;
  const unsigned short* Bt = kmat + (size_t)b * 512 * 1024 + h * 64;
  float* C = scores + (size_t)z * 512 * 512;
  gemm_core<2, 2, false, false>(A, Bt, C, nullptr, nullptr, 64, 1024, 1024, 512,
                                blockIdx.y * 128, blockIdx.x * 128, lds, lds + 16384);
}

// ctx[b,q,h,d] = sum_k probs[z][q][k] * vt[z][d][k]
__global__ __launch_bounds__(128) void k_gemm_pv(const unsigned short* probs, const unsigned short* vt,
                                                 float* ctx, unsigned short* ctxb) {
  __shared__ char lds[24576];
  int z = blockIdx.z, b = z >> 4, h = z & 15;
  const unsigned short* A  = probs + (size_t)z * 512 * 512;
  const unsigned short* Bt = vt    + (size_t)z * 64 * 512;
  float* C            = ctx  + (size_t)b * 512 * 1024 + h * 64;
  unsigned short* Mi  = ctxb + (size_t)b * 512 * 1024 + h * 64;
  gemm_core<2, 1, false, true>(A, Bt, C, nullptr, Mi, 512, 512, 512, 1024,
                               blockIdx.y * 128, 0, lds, lds + 16384);
}

// ---------------- small kernels ----------------

struct WtArgs {
  const float* src[11];
  unsigned short* dst[11];
  int K[11], N[11];
  int tstart[12];
};
__global__ __launch_bounds__(256) void k_wtconv(WtArgs a) {
  int bid = blockIdx.x;
  int z = 0;
  while (z < 10 && bid >= a.tstart[z + 1]) ++z;
  int tile = bid - a.tstart[z];
  int N = a.N[z], K = a.K[z];
  int ntn = N >> 5;
  int tn = tile % ntn, tk = tile / ntn;
  __shared__ float tl[32][33];
  int t = threadIdx.x, tx = t & 31, ty = t >> 5;
  const float* src = a.src[z];
  unsigned short* dst = a.dst[z];
#pragma unroll
  for (int i = 0; i < 32; i += 8)
    tl[ty + i][tx] = src[(size_t)(tk * 32 + ty + i) * N + tn * 32 + tx];
  __syncthreads();
#pragma unroll
  for (int i = 0; i < 32; i += 8)
    dst[(size_t)(tn * 32 + ty + i) * K + tk * 32 + tx] = f2bf(tl[tx][ty + i]);
}

__global__ void k_f2bf(const float* in, unsigned short* out) {
  int i = blockIdx.x * 256 + threadIdx.x;
  float4 v = ((const float4*)in)[i];
  ushort4 o;
  o.x = f2bf(v.x); o.y = f2bf(v.y); o.z = f2bf(v.z); o.w = f2bf(v.w);
  ((ushort4*)out)[i] = o;
}

__global__ void k_relbias(const float* table, float* rb) {
  int i = blockIdx.x * 256 + threadIdx.x;
  if (i >= 16 * 512) return;
  int h = i >> 9, d = i & 511;
  int bucket;
  if (d < 16) bucket = d;
  else {
    int lb = 16 + (int)(logf((float)d / 16.0f) / logf(8.0f) * 16.0f);
    bucket = lb < 31 ? lb : 31;
  }
  rb[i] = table[bucket * 16 + h];
}

__global__ __launch_bounds__(256) void k_rmsnorm(const float* x, const float* sc, unsigned short* out) {
  int row = blockIdx.x, t = threadIdx.x;
  float4 v = ((const float4*)(x + (size_t)row * 1024))[t];
  float ss = v.x * v.x + v.y * v.y + v.z * v.z + v.w * v.w;
  for (int o = 32; o; o >>= 1) ss += __shfl_down(ss, o);
  __shared__ float red[4];
  if ((t & 63) == 0) red[t >> 6] = ss;
  __syncthreads();
  float tot = red[0] + red[1] + red[2] + red[3];
  float rs = rsqrtf(tot * (1.0f / 1024.0f) + 1e-6f);
  float4 s4 = ((const float4*)sc)[t];
  ushort4 o;
  o.x = f2bf(v.x * rs * s4.x); o.y = f2bf(v.y * rs * s4.y);
  o.z = f2bf(v.z * rs * s4.z); o.w = f2bf(v.w * rs * s4.w);
  ((ushort4*)(out + (size_t)row * 1024))[t] = o;
}

template<bool CAUSAL>
__global__ __launch_bounds__(256) void k_softmax(const float* scores, const float* rb, unsigned short* probs) {
  int q = blockIdx.x, z = blockIdx.y, h = z & 15;
  const float* srow = scores + ((size_t)z * 512 + q) * 512;
  unsigned short* prow = probs + ((size_t)z * 512 + q) * 512;
  int t = threadIdx.x;
  float v0 = srow[t] * 0.125f;
  float v1 = srow[t + 256] * 0.125f;
  if (CAUSAL) {
    v0 = (t <= q) ? v0 + rb[h * 512 + (q - t)] : -1e30f;
    int k1 = t + 256;
    v1 = (k1 <= q) ? v1 + rb[h * 512 + (q - k1)] : -1e30f;
  }
  float m = fmaxf(v0, v1);
  for (int o = 32; o; o >>= 1) m = fmaxf(m, __shfl_down(m, o));
  __shared__ float redm[4], reds[4];
  if ((t & 63) == 0) redm[t >> 6] = m;
  __syncthreads();
  m = fmaxf(fmaxf(redm[0], redm[1]), fmaxf(redm[2], redm[3]));
  float e0 = expf(v0 - m), e1 = expf(v1 - m);
  float s = e0 + e1;
  for (int o = 32; o; o >>= 1) s += __shfl_down(s, o);
  if ((t & 63) == 0) reds[t >> 6] = s;
  __syncthreads();
  s = reds[0] + reds[1] + reds[2] + reds[3];
  float inv = 1.0f / s;
  prow[t] = f2bf(e0 * inv);
  prow[t + 256] = f2bf(e1 * inv);
}

__global__ __launch_bounds__(256) void k_vtrans(const float* vf, unsigned short* vt) {
  int z = blockIdx.y, b = z >> 4, h = z & 15;
  int k0 = blockIdx.x * 64;
  __shared__ float tl[64][65];
  int t = threadIdx.x;
  int d = t & 63, kr = t >> 6;
#pragma unroll
  for (int i = 0; i < 64; i += 4)
    tl[kr + i][d] = vf[(size_t)(b * 512 + k0 + kr + i) * 1024 + h * 64 + d];
  __syncthreads();
  int dw = t >> 2, kc = (t & 3) * 16;
  unsigned short* dst = vt + ((size_t)z * 64 + dw) * 512 + k0 + kc;
#pragma unroll
  for (int j = 0; j < 16; ++j) dst[j] = f2bf(tl[kc + j][dw]);
}

struct Low3 {
  const unsigned short* x[3];
  const float* a[3];
  float* low[3];
};
__global__ __launch_bounds__(256) void k_lora_low(Low3 g) {
  int z = blockIdx.z, row = blockIdx.x;
  int b = row >> 9;
  const unsigned short* x = g.x[z] + (size_t)row * 1024;
  const float* a = g.a[z] + ((size_t)b << 16);
  int t = threadIdx.x, r = t & 31, kc = t >> 5;
  float s = 0.f;
  int kbase = kc * 128;
  for (int i = 0; i < 128; ++i) {
    int k = kbase + i;
    s += bf2f(x[k]) * a[(size_t)k * 32 + r];
  }
  __shared__ float red[256];
  red[t] = s;
  __syncthreads();
  if (t < 32) {
    float tot = 0.f;
    for (int j = 0; j < 8; ++j) tot += red[j * 32 + t];
    g.low[z][(size_t)row * 32 + t] = tot;
  }
}

// gout = gin (+gin2) + low@bmat (+resid), optional bf16 mirror
struct Addb3 {
  const float* low[3];
  const float* bm[3];
  const float* gin[3];
  const float* gin2[3];
  float* gout[3];
  const float* resid[3];
  unsigned short* mirror[3];
};
__global__ __launch_bounds__(256) void k_lora_addb(Addb3 g) {
  int z = blockIdx.z, row = blockIdx.x;
  int b = row >> 9;
  const float* bm = g.bm[z] + ((size_t)b << 16);
  int t = threadIdx.x;
  __shared__ float lsh[32];
  if (t < 32) lsh[t] = g.low[z][(size_t)row * 32 + t];
  __syncthreads();
  float ax = 0, ay = 0, az = 0, aw = 0;
  for (int r = 0; r < 32; ++r) {
    float lv = lsh[r];
    float4 b4 = ((const float4*)(bm + (size_t)r * 1024))[t];
    ax += lv * b4.x; ay += lv * b4.y; az += lv * b4.z; aw += lv * b4.w;
  }
  size_t idx = (size_t)row * 256 + t;
  float4 gv = ((const float4*)g.gin[z])[idx];
  ax += gv.x; ay += gv.y; az += gv.z; aw += gv.w;
  if (g.gin2[z]) {
    float4 g2 = ((const float4*)g.gin2[z])[idx];
    ax += g2.x; ay += g2.y; az += g2.z; aw += g2.w;
  }
  if (g.resid[z]) {
    float4 rv = ((const float4*)g.resid[z])[idx];
    ax += rv.x; ay += rv.y; az += rv.z; aw += rv.w;
  }
  float4 o; o.x = ax; o.y = ay; o.z = az; o.w = aw;
  ((float4*)g.gout[z])[idx] = o;
  if (g.mirror[z]) {
    ushort4 mo; mo.x = f2bf(ax); mo.y = f2bf(ay); mo.z = f2bf(az); mo.w = f2bf(aw);
    ((ushort4*)g.mirror[z])[idx] = mo;
  }
}

__global__ void k_gelumul(const float* h0, const float* h1, unsigned short* out) {
  int i = blockIdx.x * 256 + threadIdx.x;
  float4 a = ((const float4*)h0)[i];
  float4 b = ((const float4*)h1)[i];
  ushort4 o;
  o.x = f2bf(0.5f * a.x * (1.0f + erff(a.x * 0.70710678f)) * b.x);
  o.y = f2bf(0.5f * a.y * (1.0f + erff(a.y * 0.70710678f)) * b.y);
  o.z = f2bf(0.5f * a.z * (1.0f + erff(a.z * 0.70710678f)) * b.z);
  o.w = f2bf(0.5f * a.w * (1.0f + erff(a.w * 0.70710678f)) * b.w);
  ((ushort4*)out)[i] = o;
}

// out = p0+p1+p2+p3 + resid  (S=4 split-K reduce, fused residual)
__global__ void k_sum4(const float* p, size_t pstride, const float* resid, float* out) {
  int i = blockIdx.x * 256 + threadIdx.x;
  float4 a = ((const float4*)p)[i];
  float4 b = ((const float4*)(p + pstride))[i];
  float4 c = ((const float4*)(p + 2 * pstride))[i];
  float4 d = ((const float4*)(p + 3 * pstride))[i];
  float4 r = ((const float4*)resid)[i];
  float4 o;
  o.x = a.x + b.x + c.x + d.x + r.x;
  o.y = a.y + b.y + c.y + d.y + r.y;
  o.z = a.z + b.z + c.z + d.z + r.z;
  o.w = a.w + b.w + c.w + d.w + r.w;
  ((float4*)out)[i] = o;
}

// ---------------------------------------------------------------------------

extern "C" void kernel_launch(void* const* d_in, const int* in_sizes, int n_in,
                              void* d_out, int out_size, void* d_ws, size_t ws_size,
                              hipStream_t stream) {
  const float* f_inputs  = (const float*)d_in[0];
  const float* f_encoded = (const float*)d_in[1];
  const float* f_qa = (const float*)d_in[2];
  const float* f_qb = (const float*)d_in[3];
  const float* f_ka = (const float*)d_in[4];
  const float* f_kb = (const float*)d_in[5];
  const float* f_va = (const float*)d_in[6];
  const float* f_vb = (const float*)d_in[7];
  const float* f_oa = (const float*)d_in[8];
  const float* f_ob = (const float*)d_in[9];
  const float* f_table = (const float*)d_in[10];
  const float* f_ln1 = (const float*)d_in[11];
  const float* f_ln2 = (const float*)d_in[12];
  const float* f_ln3 = (const float*)d_in[13];
  const float* f_W[8] = { (const float*)d_in[14], (const float*)d_in[15],
                          (const float*)d_in[16], (const float*)d_in[17],
                          (const float*)d_in[18], (const float*)d_in[19],
                          (const float*)d_in[20], (const float*)d_in[21] };
  const float* f_wi0 = (const float*)d_in[22];
  const float* f_wi1 = (const float*)d_in[23];
  const float* f_wo  = (const float*)d_in[24];

  const size_t SEL1 = 32768;   // sel stride in lora a/b arrays (D*R)
  const size_t PART = (size_t)2048 * 1024;  // one [2048,1024] fp32 partial (elements)

  char* w = (char*)d_ws;
  size_t off = 0;
  auto alloc = [&](size_t bytes) -> char* {
    off = (off + 255) & ~(size_t)255;
    char* p = w + off;
    off += bytes;
    return p;
  };
  unsigned short* wt[8];
  for (int i = 0; i < 8; ++i) wt[i] = (unsigned short*)alloc(1024 * 1024 * 2);
  unsigned short* wi0t = (unsigned short*)alloc(4096 * 1024 * 2);
  unsigned short* wi1t = (unsigned short*)alloc(4096 * 1024 * 2);
  unsigned short* wot  = (unsigned short*)alloc(1024 * 4096 * 2);
  unsigned short* encbf = (unsigned short*)alloc(2048 * 1024 * 2);
  float* rb = (float*)alloc(16 * 512 * 4);
  unsigned short* xn = (unsigned short*)alloc(2048 * 1024 * 2);
  float* qf = (float*)alloc(2048 * 1024 * 4);
  float* kf = (float*)alloc(2048 * 1024 * 4);
  float* vf = (float*)alloc(2048 * 1024 * 4);
  unsigned short* qbf = (unsigned short*)alloc(2048 * 1024 * 2);
  unsigned short* kbf = (unsigned short*)alloc(2048 * 1024 * 2);
  unsigned short* vtb = (unsigned short*)alloc((size_t)64 * 64 * 512 * 2);
  float* low0 = (float*)alloc(2048 * 32 * 4);
  float* low1 = (float*)alloc(2048 * 32 * 4);
  float* low2 = (float*)alloc(2048 * 32 * 4);
  float* scores = (float*)alloc((size_t)64 * 512 * 512 * 4);   // 64 MB scratch
  unsigned short* probs = (unsigned short*)alloc((size_t)64 * 512 * 512 * 2); // 32 MB
  float* ctxf = (float*)alloc(2048 * 1024 * 4);
  unsigned short* ctxb = (unsigned short*)alloc(2048 * 1024 * 2);
  float* xres = (float*)alloc(2048 * 1024 * 4);
  float* yres = (float*)alloc(2048 * 1024 * 4);
  // Aliases into dead regions (stream-serial lifetimes):
  // QKV split-K partials (live: gemm3s -> addb; dead before QK writes scores)
  float* qp = scores;                 // 2 partials
  float* kp = scores + 2 * PART;
  float* vp = scores + 4 * PART;      // 6*PART = 48 MB <= 64 MB
  // out-proj split-K partials (live: after PV consumed probs)
  float* op = (float*)probs;          // 2 partials = 16 MB <= 32 MB
  // MLP: h0/h1 in scores region, hbf in probs region, final partials back in scores
  float* h0 = scores;
  float* h1 = scores + (size_t)2048 * 4096;
  unsigned short* hbf = probs;
  float* fp = scores;                 // 4 partials = 32 MB (h0/h1 dead after gelumul)
  (void)ws_size; (void)in_sizes; (void)n_in; (void)out_size;

  // ---- weight convert + transpose ----
  WtArgs wa;
  int ts = 0;
  for (int i = 0; i < 8; ++i) {
    wa.src[i] = f_W[i]; wa.dst[i] = wt[i]; wa.K[i] = 1024; wa.N[i] = 1024;
    wa.tstart[i] = ts; ts += 32 * 32;
  }
  wa.src[8] = f_wi0; wa.dst[8] = wi0t; wa.K[8] = 1024; wa.N[8] = 4096; wa.tstart[8] = ts; ts += 32 * 128;
  wa.src[9] = f_wi1; wa.dst[9] = wi1t; wa.K[9] = 1024; wa.N[9] = 4096; wa.tstart[9] = ts; ts += 32 * 128;
  wa.src[10] = f_wo; wa.dst[10] = wot; wa.K[10] = 4096; wa.N[10] = 1024; wa.tstart[10] = ts; ts += 128 * 32;
  wa.tstart[11] = ts;
  k_wtconv<<<dim3(ts), dim3(256), 0, stream>>>(wa);

  k_f2bf<<<dim3(2048), dim3(256), 0, stream>>>(f_encoded, encbf);
  k_relbias<<<dim3(32), dim3(256), 0, stream>>>(f_table, rb);

  // ================= self-attention =================
  k_rmsnorm<<<dim3(2048), dim3(256), 0, stream>>>(f_inputs, f_ln1, xn);

  G3S g_qkv = { {xn, xn, xn}, {wt[0], wt[1], wt[2]}, {qp, kp, vp},
                1024, 1024, 1024, 1024, 2, 512, PART };
  k_gemm3s<<<dim3(8, 16, 6), dim3(256), 0, stream>>>(g_qkv);

  Low3 lo_s = { {xn, xn, xn}, {f_qa, f_ka, f_va}, {low0, low1, low2} };
  k_lora_low<<<dim3(2048, 1, 3), dim3(256), 0, stream>>>(lo_s);
  Addb3 ab_s = { {low0, low1, low2}, {f_qb, f_kb, f_vb},
                 {qp, kp, vp}, {qp + PART, kp + PART, vp + PART},
                 {qf, kf, vf}, {nullptr, nullptr, nullptr}, {qbf, kbf, nullptr} };
  k_lora_addb<<<dim3(2048, 1, 3), dim3(256), 0, stream>>>(ab_s);

  k_gemm_qk<<<dim3(4, 4, 64), dim3(256), 0, stream>>>(qbf, kbf, scores);
  k_softmax<true><<<dim3(512, 64), dim3(256), 0, stream>>>(scores, rb, probs);
  k_vtrans<<<dim3(8, 64), dim3(256), 0, stream>>>(vf, vtb);
  k_gemm_pv<<<dim3(1, 4, 64), dim3(128), 0, stream>>>(probs, vtb, ctxf, ctxb);

  k_gemm1s<<<dim3(8, 16, 2), dim3(256), 0, stream>>>(ctxb, wt[3], op, PART, 512, 1024, 1024, 1024);
  Low3 lo_o = { {ctxb, ctxb, ctxb}, {f_oa, f_oa, f_oa}, {low0, low0, low0} };
  k_lora_low<<<dim3(2048, 1, 1), dim3(256), 0, stream>>>(lo_o);
  Addb3 ab_o = { {low0, low0, low0}, {f_ob, f_ob, f_ob},
                 {op, op, op}, {op + PART, op + PART, op + PART},
                 {xres, xres, xres}, {f_inputs, f_inputs, f_inputs},
                 {nullptr, nullptr, nullptr} };
  k_lora_addb<<<dim3(2048, 1, 1), dim3(256), 0, stream>>>(ab_o);

  // ================= cross-attention =================
  k_rmsnorm<<<dim3(2048), dim3(256), 0, stream>>>(xres, f_ln2, xn);

  G3S g_cqkv = { {xn, encbf, encbf}, {wt[4], wt[5], wt[6]}, {qp, kp, vp},
                 1024, 1024, 1024, 1024, 2, 512, PART };
  k_gemm3s<<<dim3(8, 16, 6), dim3(256), 0, stream>>>(g_cqkv);

  Low3 lo_c = { {xn, encbf, encbf}, {f_qa + SEL1, f_ka + SEL1, f_va + SEL1}, {low0, low1, low2} };
  k_lora_low<<<dim3(2048, 1, 3), dim3(256), 0, stream>>>(lo_c);
  Addb3 ab_c = { {low0, low1, low2}, {f_qb + SEL1, f_kb + SEL1, f_vb + SEL1},
                 {qp, kp, vp}, {qp + PART, kp + PART, vp + PART},
                 {qf, kf, vf}, {nullptr, nullptr, nullptr}, {qbf, kbf, nullptr} };
  k_lora_addb<<<dim3(2048, 1, 3), dim3(256), 0, stream>>>(ab_c);

  k_gemm_qk<<<dim3(4, 4, 64), dim3(256), 0, stream>>>(qbf, kbf, scores);
  k_softmax<false><<<dim3(512, 64), dim3(256), 0, stream>>>(scores, rb, probs);
  k_vtrans<<<dim3(8, 64), dim3(256), 0, stream>>>(vf, vtb);
  k_gemm_pv<<<dim3(1, 4, 64), dim3(128), 0, stream>>>(probs, vtb, ctxf, ctxb);

  k_gemm1s<<<dim3(8, 16, 2), dim3(256), 0, stream>>>(ctxb, wt[7], op, PART, 512, 1024, 1024, 1024);
  Low3 lo_co = { {ctxb, ctxb, ctxb}, {f_oa + SEL1, f_oa + SEL1, f_oa + SEL1}, {low0, low0, low0} };
  k_lora_low<<<dim3(2048, 1, 1), dim3(256), 0, stream>>>(lo_co);
  Addb3 ab_co = { {low0, low0, low0}, {f_ob + SEL1, f_ob + SEL1, f_ob + SEL1},
                  {op, op, op}, {op + PART, op + PART, op + PART},
                  {yres, yres, yres}, {xres, xres, xres},
                  {nullptr, nullptr, nullptr} };
  k_lora_addb<<<dim3(2048, 1, 1), dim3(256), 0, stream>>>(ab_co);

  // ================= gated-gelu MLP =================
  k_rmsnorm<<<dim3(2048), dim3(256), 0, stream>>>(yres, f_ln3, xn);
  G3S g_mlp = { {xn, xn, xn}, {wi0t, wi1t, wi1t}, {h0, h1, h1},
                1024, 1024, 1024, 4096, 1, 1024, 0 };
  k_gemm3s<<<dim3(32, 16, 2), dim3(256), 0, stream>>>(g_mlp);
  k_gelumul<<<dim3(8192), dim3(256), 0, stream>>>(h0, h1, hbf);
  k_gemm1s<<<dim3(8, 16, 4), dim3(256), 0, stream>>>(hbf, wot, fp, PART, 1024, 4096, 4096, 1024);
  k_sum4<<<dim3(2048), dim3(256), 0, stream>>>(fp, PART, yres, (float*)d_out);
}

// Round 3
// 695.353 us; speedup vs baseline: 1.1796x; 1.0706x over previous
//
#include <hip/hip_runtime.h>
#include <math.h>

// ---------------------------------------------------------------------------
// LoRA T5 decoder layer on MI355X (gfx950).
// B=4, L=ENC=512, D=1024, H=16, HD=64, MLP=4096, R=32.
// bf16 MFMA 16x16x32 everywhere; m97-style global_load_lds staging.
// R2->R3: (1) flash attention (QK+softmax+PV fused, no scores/probs
// materialization); (2) fused dual-GEMM MLP with gelu epilogue writing bf16;
// (3) drop dead fp32 outputs (ctx fp32, q/k fp32).
// ---------------------------------------------------------------------------

#define DEV __device__ __forceinline__

typedef __bf16 bf16x8 __attribute__((ext_vector_type(8)));
typedef float floatx4 __attribute__((ext_vector_type(4)));

typedef __attribute__((address_space(1))) void* gas_ptr;
typedef __attribute__((address_space(3))) void* las_ptr;

DEV unsigned short f2bf(float f) {
  union { float f; unsigned int u; } v; v.f = f;
  unsigned int r = v.u + 0x7fffu + ((v.u >> 16) & 1u);
  return (unsigned short)(r >> 16);
}
DEV float bf2f(unsigned short u) {
  union { unsigned int u; float f; } v; v.u = ((unsigned int)u) << 16;
  return v.f;
}

#define GLOAD_LDS16(g, l) __builtin_amdgcn_global_load_lds((gas_ptr)(g), (las_ptr)(l), 16, 0, 0)

// Stage nrows x 64 bf16 (128 B rows) from global (row stride ldbytes) into LDS.
template<int NW>
DEV void stage_tile(const char* gbase, char* lds, int nrows, int ldbytes, int wave, int lane) {
  int nchunks = nrows >> 3;
  for (int c = wave; c < nchunks; c += NW) {
    int row  = (c << 3) + (lane >> 3);
    int colb = (lane & 7) << 4;
    GLOAD_LDS16(gbase + (size_t)row * ldbytes + colb, lds + (c << 10));
  }
}

// C = A[M,K] * Bt[N,K]^T, bf16 in / fp32 out. 128x128 tile, 4 waves.
template<int WM, int WN>
DEV void gemm_core(const unsigned short* A, const unsigned short* Bt, float* C,
                   int K, int lda, int ldb, int ldc, int m0, int n0,
                   char* ldsA, char* ldsB) {
  constexpr int NW = WM * WN;
  const int tid  = threadIdx.x;
  const int lane = tid & 63;
  const int wave = tid >> 6;
  const int wm   = wave % WM;
  const int wn   = wave / WM;
  const int quad = lane >> 4;
  const int l15  = lane & 15;

  floatx4 acc[4][4];
#pragma unroll
  for (int i = 0; i < 4; ++i)
#pragma unroll
    for (int j = 0; j < 4; ++j) acc[i][j] = (floatx4){0.f, 0.f, 0.f, 0.f};

  const char* gA = (const char*)(A + (size_t)m0 * lda);
  const char* gB = (const char*)(Bt + (size_t)n0 * ldb);

  for (int k0 = 0; k0 < K; k0 += 64) {
    stage_tile<NW>(gA + (size_t)k0 * 2, ldsA, WM * 64, lda * 2, wave, lane);
    stage_tile<NW>(gB + (size_t)k0 * 2, ldsB, WN * 64, ldb * 2, wave, lane);
    __syncthreads();
#pragma unroll
    for (int kk = 0; kk < 64; kk += 32) {
      bf16x8 af[4], bv[4];
      const char* baseA = ldsA + (size_t)(wm * 64 + l15) * 128 + (kk + quad * 8) * 2;
      const char* baseB = ldsB + (size_t)(wn * 64 + l15) * 128 + (kk + quad * 8) * 2;
#pragma unroll
      for (int mi = 0; mi < 4; ++mi) af[mi] = *(const bf16x8*)(baseA + mi * 2048);
#pragma unroll
      for (int ni = 0; ni < 4; ++ni) bv[ni] = *(const bf16x8*)(baseB + ni * 2048);
#pragma unroll
      for (int mi = 0; mi < 4; ++mi)
#pragma unroll
        for (int ni = 0; ni < 4; ++ni)
          acc[mi][ni] = __builtin_amdgcn_mfma_f32_16x16x32_bf16(af[mi], bv[ni], acc[mi][ni], 0, 0, 0);
    }
    __syncthreads();
  }

#pragma unroll
  for (int mi = 0; mi < 4; ++mi) {
#pragma unroll
    for (int r = 0; r < 4; ++r) {
      int row = m0 + wm * 64 + mi * 16 + quad * 4 + r;
#pragma unroll
      for (int ni = 0; ni < 4; ++ni) {
        int col = n0 + wn * 64 + ni * 16 + l15;
        C[(size_t)row * ldc + col] = acc[mi][ni][r];
      }
    }
  }
}

// ---------------- GEMM wrappers ----------------

struct G3S {
  const unsigned short* A[3];
  const unsigned short* B[3];
  float* C[3];
  int K, lda, ldb, ldc, S, Kchunk;
  size_t pstride;
};
__global__ __launch_bounds__(256) void k_gemm3s(G3S g) {
  __shared__ char lds[32768];
  int z = blockIdx.z;
  int gi = z / g.S, s = z - gi * g.S;
  size_t koff = (size_t)s * g.Kchunk;
  gemm_core<2, 2>(g.A[gi] + koff, g.B[gi] + koff,
                  g.C[gi] + (size_t)s * g.pstride,
                  g.Kchunk, g.lda, g.ldb, g.ldc,
                  blockIdx.y * 128, blockIdx.x * 128, lds, lds + 16384);
}

__global__ __launch_bounds__(256) void k_gemm1s(const unsigned short* A, const unsigned short* Bt,
                                                float* Cpart, size_t pstride,
                                                int Kchunk, int lda, int ldb, int ldc) {
  __shared__ char lds[32768];
  int s = blockIdx.z;
  size_t koff = (size_t)s * Kchunk;
  gemm_core<2, 2>(A + koff, Bt + koff, Cpart + (size_t)s * pstride,
                  Kchunk, lda, ldb, ldc,
                  blockIdx.y * 128, blockIdx.x * 128, lds, lds + 16384);
}

// Fused MLP: h = gelu(A@B0t^T) * (A@B1t^T), bf16 out. 128x128 tile, dual acc.
__global__ __launch_bounds__(256) void k_mlp(const unsigned short* A, const unsigned short* B0t,
                                             const unsigned short* B1t, unsigned short* hbf) {
  __shared__ char lds[49152];
  char* ldsA  = lds;
  char* ldsB0 = lds + 16384;
  char* ldsB1 = lds + 32768;
  const int m0 = blockIdx.y * 128, n0 = blockIdx.x * 128;
  const int tid  = threadIdx.x;
  const int lane = tid & 63;
  const int wave = tid >> 6;
  const int wm   = wave & 1;
  const int wn   = wave >> 1;
  const int quad = lane >> 4;
  const int l15  = lane & 15;

  floatx4 acc0[4][4], acc1[4][4];
#pragma unroll
  for (int i = 0; i < 4; ++i)
#pragma unroll
    for (int j = 0; j < 4; ++j) {
      acc0[i][j] = (floatx4){0.f, 0.f, 0.f, 0.f};
      acc1[i][j] = (floatx4){0.f, 0.f, 0.f, 0.f};
    }

  const char* gA  = (const char*)(A   + (size_t)m0 * 1024);
  const char* gB0 = (const char*)(B0t + (size_t)n0 * 1024);
  const char* gB1 = (const char*)(B1t + (size_t)n0 * 1024);

  for (int k0 = 0; k0 < 1024; k0 += 64) {
    stage_tile<4>(gA  + (size_t)k0 * 2, ldsA,  128, 2048, wave, lane);
    stage_tile<4>(gB0 + (size_t)k0 * 2, ldsB0, 128, 2048, wave, lane);
    stage_tile<4>(gB1 + (size_t)k0 * 2, ldsB1, 128, 2048, wave, lane);
    __syncthreads();
#pragma unroll
    for (int kk = 0; kk < 64; kk += 32) {
      bf16x8 af[4], b0[4], b1[4];
      const char* baseA = ldsA  + (size_t)(wm * 64 + l15) * 128 + (kk + quad * 8) * 2;
      const char* baseB = (size_t)(wn * 64 + l15) * 128 + (kk + quad * 8) * 2 + (char*)0;
#pragma unroll
      for (int mi = 0; mi < 4; ++mi) af[mi] = *(const bf16x8*)(baseA + mi * 2048);
#pragma unroll
      for (int ni = 0; ni < 4; ++ni) {
        b0[ni] = *(const bf16x8*)(ldsB0 + (size_t)baseB + ni * 2048);
        b1[ni] = *(const bf16x8*)(ldsB1 + (size_t)baseB + ni * 2048);
      }
#pragma unroll
      for (int mi = 0; mi < 4; ++mi)
#pragma unroll
        for (int ni = 0; ni < 4; ++ni) {
          acc0[mi][ni] = __builtin_amdgcn_mfma_f32_16x16x32_bf16(af[mi], b0[ni], acc0[mi][ni], 0, 0, 0);
          acc1[mi][ni] = __builtin_amdgcn_mfma_f32_16x16x32_bf16(af[mi], b1[ni], acc1[mi][ni], 0, 0, 0);
        }
    }
    __syncthreads();
  }

#pragma unroll
  for (int mi = 0; mi < 4; ++mi) {
#pragma unroll
    for (int r = 0; r < 4; ++r) {
      int row = m0 + wm * 64 + mi * 16 + quad * 4 + r;
#pragma unroll
      for (int ni = 0; ni < 4; ++ni) {
        int col = n0 + wn * 64 + ni * 16 + l15;
        float g = acc0[mi][ni][r];
        float v = 0.5f * g * (1.0f + erff(g * 0.70710678f)) * acc1[mi][ni][r];
        hbf[(size_t)row * 4096 + col] = f2bf(v);
      }
    }
  }
}

// ---------------- flash attention ----------------
// One block per (q-tile of 64 rows, z=b*16+h). 4 waves; wave owns 16 q rows.
// S and O accumulators in MFMA C-layout (row = quad*4+reg). P goes through
// LDS to become the A-operand of PV.
template<bool CAUSAL>
__global__ __launch_bounds__(256) void k_flash(const unsigned short* qmat, const unsigned short* kmat,
                                               const unsigned short* vt, const float* rb,
                                               unsigned short* ctxb) {
  __shared__ char ldsQ[8192];   // [64 q][64 d] bf16
  __shared__ char ldsK[8192];   // [64 k][64 d]
  __shared__ char ldsV[8192];   // [64 d][64 k]
  __shared__ char ldsP[8192];   // [64 q][64 k]
  __shared__ float lrb[512];

  const int z = blockIdx.y, b = z >> 4, h = z & 15;
  const int q0 = blockIdx.x * 64;
  const int tid = threadIdx.x, lane = tid & 63, wave = tid >> 6;
  const int quad = lane >> 4, l15 = lane & 15;

  const unsigned short* Q = qmat + (size_t)b * 512 * 1024 + h * 64;
  const unsigned short* K = kmat + (size_t)b * 512 * 1024 + h * 64;
  const unsigned short* V = vt + (size_t)z * 64 * 512;   // [64 d][512 k]

  stage_tile<4>((const char*)(Q + (size_t)q0 * 1024), ldsQ, 64, 2048, wave, lane);
  if (CAUSAL)
    for (int i = tid; i < 512; i += 256) lrb[i] = rb[h * 512 + i];

  float m_run[4], l_run[4];
  floatx4 oacc[4];
#pragma unroll
  for (int r = 0; r < 4; ++r) { m_run[r] = -1e30f; l_run[r] = 0.f; }
#pragma unroll
  for (int ni = 0; ni < 4; ++ni) oacc[ni] = (floatx4){0.f, 0.f, 0.f, 0.f};

  const int ktend = CAUSAL ? (blockIdx.x + 1) : 8;
  for (int kt = 0; kt < ktend; ++kt) {
    __syncthreads();  // prior iter's LDS reads done
    stage_tile<4>((const char*)(K + (size_t)kt * 64 * 1024), ldsK, 64, 2048, wave, lane);
    stage_tile<4>((const char*)(V + kt * 64), ldsV, 64, 1024, wave, lane);
    __syncthreads();  // staged data visible (vmcnt drained)

    // S = Q Kt : wave's 16 q rows x 64 k cols
    floatx4 sacc[4];
#pragma unroll
    for (int ct = 0; ct < 4; ++ct) sacc[ct] = (floatx4){0.f, 0.f, 0.f, 0.f};
    const char* aBase = ldsQ + (size_t)(wave * 16 + l15) * 128 + quad * 16;
#pragma unroll
    for (int kd = 0; kd < 2; ++kd) {
      bf16x8 af = *(const bf16x8*)(aBase + kd * 64);
#pragma unroll
      for (int ct = 0; ct < 4; ++ct) {
        bf16x8 bf = *(const bf16x8*)(ldsK + (size_t)(ct * 16 + l15) * 128 + quad * 16 + kd * 64);
        sacc[ct] = __builtin_amdgcn_mfma_f32_16x16x32_bf16(af, bf, sacc[ct], 0, 0, 0);
      }
    }

    // scale + bias + mask
    float sv[4][4];
#pragma unroll
    for (int ct = 0; ct < 4; ++ct)
#pragma unroll
      for (int r = 0; r < 4; ++r) {
        float v = sacc[ct][r] * 0.125f;
        if (CAUSAL) {
          int qq = q0 + wave * 16 + quad * 4 + r;
          int kk = kt * 64 + ct * 16 + l15;
          v = (kk <= qq) ? v + lrb[qq - kk] : -1e30f;
        }
        sv[ct][r] = v;
      }

    // row max (across 4 ct regs, then across the 16 l15 lanes within quad)
    float mx[4];
#pragma unroll
    for (int r = 0; r < 4; ++r)
      mx[r] = fmaxf(fmaxf(sv[0][r], sv[1][r]), fmaxf(sv[2][r], sv[3][r]));
#pragma unroll
    for (int o = 1; o < 16; o <<= 1)
#pragma unroll
      for (int r = 0; r < 4; ++r) mx[r] = fmaxf(mx[r], __shfl_xor(mx[r], o));

    float alpha[4], rs[4];
#pragma unroll
    for (int r = 0; r < 4; ++r) {
      float mn = fmaxf(m_run[r], mx[r]);
      alpha[r] = expf(m_run[r] - mn);
      m_run[r] = mn;
      rs[r] = 0.f;
    }
#pragma unroll
    for (int ct = 0; ct < 4; ++ct)
#pragma unroll
      for (int r = 0; r < 4; ++r) {
        float p = expf(sv[ct][r] - m_run[r]);
        sv[ct][r] = p;
        rs[r] += p;
      }
#pragma unroll
    for (int o = 1; o < 16; o <<= 1)
#pragma unroll
      for (int r = 0; r < 4; ++r) rs[r] += __shfl_xor(rs[r], o);
#pragma unroll
    for (int r = 0; r < 4; ++r) l_run[r] = l_run[r] * alpha[r] + rs[r];
#pragma unroll
    for (int ni = 0; ni < 4; ++ni)
#pragma unroll
      for (int r = 0; r < 4; ++r) oacc[ni][r] *= alpha[r];

    // P -> LDS (bf16), rows = wave's q rows
#pragma unroll
    for (int ct = 0; ct < 4; ++ct)
#pragma unroll
      for (int r = 0; r < 4; ++r)
        *(unsigned short*)(ldsP + (size_t)(wave * 16 + quad * 4 + r) * 128 + (ct * 16 + l15) * 2)
            = f2bf(sv[ct][r]);
    __syncthreads();

    // O += P Vt : A rows = wave's q rows, B rows = d
    const char* pBase = ldsP + (size_t)(wave * 16 + l15) * 128 + quad * 16;
#pragma unroll
    for (int kd = 0; kd < 2; ++kd) {
      bf16x8 pf = *(const bf16x8*)(pBase + kd * 64);
#pragma unroll
      for (int ni = 0; ni < 4; ++ni) {
        bf16x8 vf8 = *(const bf16x8*)(ldsV + (size_t)(ni * 16 + l15) * 128 + quad * 16 + kd * 64);
        oacc[ni] = __builtin_amdgcn_mfma_f32_16x16x32_bf16(pf, vf8, oacc[ni], 0, 0, 0);
      }
    }
  }

  // epilogue: O /= l, write bf16 ctx [b, q, h*64+d]
#pragma unroll
  for (int r = 0; r < 4; ++r) {
    int q = q0 + wave * 16 + quad * 4 + r;
    float inv = 1.0f / l_run[r];
    unsigned short* dst = ctxb + ((size_t)b * 512 + q) * 1024 + h * 64;
#pragma unroll
    for (int ni = 0; ni < 4; ++ni)
      dst[ni * 16 + l15] = f2bf(oacc[ni][r] * inv);
  }
}

// ---------------- small kernels ----------------

struct WtArgs {
  const float* src[11];
  unsigned short* dst[11];
  int K[11], N[11];
  int tstart[12];
};
__global__ __launch_bounds__(256) void k_wtconv(WtArgs a) {
  int bid = blockIdx.x;
  int z = 0;
  while (z < 10 && bid >= a.tstart[z + 1]) ++z;
  int tile = bid - a.tstart[z];
  int N = a.N[z], K = a.K[z];
  int ntn = N >> 5;
  int tn = tile % ntn, tk = tile / ntn;
  __shared__ float tl[32][33];
  int t = threadIdx.x, tx = t & 31, ty = t >> 5;
  const float* src = a.src[z];
  unsigned short* dst = a.dst[z];
#pragma unroll
  for (int i = 0; i < 32; i += 8)
    tl[ty + i][tx] = src[(size_t)(tk * 32 + ty + i) * N + tn * 32 + tx];
  __syncthreads();
#pragma unroll
  for (int i = 0; i < 32; i += 8)
    dst[(size_t)(tn * 32 + ty + i) * K + tk * 32 + tx] = f2bf(tl[tx][ty + i]);
}

__global__ void k_f2bf(const float* in, unsigned short* out) {
  int i = blockIdx.x * 256 + threadIdx.x;
  float4 v = ((const float4*)in)[i];
  ushort4 o;
  o.x = f2bf(v.x); o.y = f2bf(v.y); o.z = f2bf(v.z); o.w = f2bf(v.w);
  ((ushort4*)out)[i] = o;
}

__global__ void k_relbias(const float* table, float* rb) {
  int i = blockIdx.x * 256 + threadIdx.x;
  if (i >= 16 * 512) return;
  int h = i >> 9, d = i & 511;
  int bucket;
  if (d < 16) bucket = d;
  else {
    int lb = 16 + (int)(logf((float)d / 16.0f) / logf(8.0f) * 16.0f);
    bucket = lb < 31 ? lb : 31;
  }
  rb[i] = table[bucket * 16 + h];
}

__global__ __launch_bounds__(256) void k_rmsnorm(const float* x, const float* sc, unsigned short* out) {
  int row = blockIdx.x, t = threadIdx.x;
  float4 v = ((const float4*)(x + (size_t)row * 1024))[t];
  float ss = v.x * v.x + v.y * v.y + v.z * v.z + v.w * v.w;
  for (int o = 32; o; o >>= 1) ss += __shfl_down(ss, o);
  __shared__ float red[4];
  if ((t & 63) == 0) red[t >> 6] = ss;
  __syncthreads();
  float tot = red[0] + red[1] + red[2] + red[3];
  float rs = rsqrtf(tot * (1.0f / 1024.0f) + 1e-6f);
  float4 s4 = ((const float4*)sc)[t];
  ushort4 o;
  o.x = f2bf(v.x * rs * s4.x); o.y = f2bf(v.y * rs * s4.y);
  o.z = f2bf(v.z * rs * s4.z); o.w = f2bf(v.w * rs * s4.w);
  ((ushort4*)(out + (size_t)row * 1024))[t] = o;
}

__global__ __launch_bounds__(256) void k_vtrans(const float* vf, unsigned short* vt) {
  int z = blockIdx.y, b = z >> 4, h = z & 15;
  int k0 = blockIdx.x * 64;
  __shared__ float tl[64][65];
  int t = threadIdx.x;
  int d = t & 63, kr = t >> 6;
#pragma unroll
  for (int i = 0; i < 64; i += 4)
    tl[kr + i][d] = vf[(size_t)(b * 512 + k0 + kr + i) * 1024 + h * 64 + d];
  __syncthreads();
  int dw = t >> 2, kc = (t & 3) * 16;
  unsigned short* dst = vt + ((size_t)z * 64 + dw) * 512 + k0 + kc;
#pragma unroll
  for (int j = 0; j < 16; ++j) dst[j] = f2bf(tl[kc + j][dw]);
}

struct Low3 {
  const unsigned short* x[3];
  const float* a[3];
  float* low[3];
};
__global__ __launch_bounds__(256) void k_lora_low(Low3 g) {
  int z = blockIdx.z, row = blockIdx.x;
  int b = row >> 9;
  const unsigned short* x = g.x[z] + (size_t)row * 1024;
  const float* a = g.a[z] + ((size_t)b << 16);
  int t = threadIdx.x, r = t & 31, kc = t >> 5;
  float s = 0.f;
  int kbase = kc * 128;
  for (int i = 0; i < 128; ++i) {
    int k = kbase + i;
    s += bf2f(x[k]) * a[(size_t)k * 32 + r];
  }
  __shared__ float red[256];
  red[t] = s;
  __syncthreads();
  if (t < 32) {
    float tot = 0.f;
    for (int j = 0; j < 8; ++j) tot += red[j * 32 + t];
    g.low[z][(size_t)row * 32 + t] = tot;
  }
}

// gout(optional) = gin (+gin2) + low@bmat (+resid); mirror(optional) bf16
struct Addb3 {
  const float* low[3];
  const float* bm[3];
  const float* gin[3];
  const float* gin2[3];
  float* gout[3];
  const float* resid[3];
  unsigned short* mirror[3];
};
__global__ __launch_bounds__(256) void k_lora_addb(Addb3 g) {
  int z = blockIdx.z, row = blockIdx.x;
  int b = row >> 9;
  const float* bm = g.bm[z] + ((size_t)b << 16);
  int t = threadIdx.x;
  __shared__ float lsh[32];
  if (t < 32) lsh[t] = g.low[z][(size_t)row * 32 + t];
  __syncthreads();
  float ax = 0, ay = 0, az = 0, aw = 0;
  for (int r = 0; r < 32; ++r) {
    float lv = lsh[r];
    float4 b4 = ((const float4*)(bm + (size_t)r * 1024))[t];
    ax += lv * b4.x; ay += lv * b4.y; az += lv * b4.z; aw += lv * b4.w;
  }
  size_t idx = (size_t)row * 256 + t;
  float4 gv = ((const float4*)g.gin[z])[idx];
  ax += gv.x; ay += gv.y; az += gv.z; aw += gv.w;
  if (g.gin2[z]) {
    float4 g2 = ((const float4*)g.gin2[z])[idx];
    ax += g2.x; ay += g2.y; az += g2.z; aw += g2.w;
  }
  if (g.resid[z]) {
    float4 rv = ((const float4*)g.resid[z])[idx];
    ax += rv.x; ay += rv.y; az += rv.z; aw += rv.w;
  }
  if (g.gout[z]) {
    float4 o; o.x = ax; o.y = ay; o.z = az; o.w = aw;
    ((float4*)g.gout[z])[idx] = o;
  }
  if (g.mirror[z]) {
    ushort4 mo; mo.x = f2bf(ax); mo.y = f2bf(ay); mo.z = f2bf(az); mo.w = f2bf(aw);
    ((ushort4*)g.mirror[z])[idx] = mo;
  }
}

// out = p0+p1+p2+p3 + resid
__global__ void k_sum4(const float* p, size_t pstride, const float* resid, float* out) {
  int i = blockIdx.x * 256 + threadIdx.x;
  float4 a = ((const float4*)p)[i];
  float4 b = ((const float4*)(p + pstride))[i];
  float4 c = ((const float4*)(p + 2 * pstride))[i];
  float4 d = ((const float4*)(p + 3 * pstride))[i];
  float4 r = ((const float4*)resid)[i];
  float4 o;
  o.x = a.x + b.x + c.x + d.x + r.x;
  o.y = a.y + b.y + c.y + d.y + r.y;
  o.z = a.z + b.z + c.z + d.z + r.z;
  o.w = a.w + b.w + c.w + d.w + r.w;
  ((float4*)out)[i] = o;
}

// ---------------------------------------------------------------------------

extern "C" void kernel_launch(void* const* d_in, const int* in_sizes, int n_in,
                              void* d_out, int out_size, void* d_ws, size_t ws_size,
                              hipStream_t stream) {
  const float* f_inputs  = (const float*)d_in[0];
  const float* f_encoded = (const float*)d_in[1];
  const float* f_qa = (const float*)d_in[2];
  const float* f_qb = (const float*)d_in[3];
  const float* f_ka = (const float*)d_in[4];
  const float* f_kb = (const float*)d_in[5];
  const float* f_va = (const float*)d_in[6];
  const float* f_vb = (const float*)d_in[7];
  const float* f_oa = (const float*)d_in[8];
  const float* f_ob = (const float*)d_in[9];
  const float* f_table = (const float*)d_in[10];
  const float* f_ln1 = (const float*)d_in[11];
  const float* f_ln2 = (const float*)d_in[12];
  const float* f_ln3 = (const float*)d_in[13];
  const float* f_W[8] = { (const float*)d_in[14], (const float*)d_in[15],
                          (const float*)d_in[16], (const float*)d_in[17],
                          (const float*)d_in[18], (const float*)d_in[19],
                          (const float*)d_in[20], (const float*)d_in[21] };
  const float* f_wi0 = (const float*)d_in[22];
  const float* f_wi1 = (const float*)d_in[23];
  const float* f_wo  = (const float*)d_in[24];

  const size_t SEL1 = 32768;               // sel stride in lora a/b arrays
  const size_t PART = (size_t)2048 * 1024; // [2048,1024] fp32 partial (elements)

  char* w = (char*)d_ws;
  size_t off = 0;
  auto alloc = [&](size_t bytes) -> char* {
    off = (off + 255) & ~(size_t)255;
    char* p = w + off;
    off += bytes;
    return p;
  };
  unsigned short* wt[8];
  for (int i = 0; i < 8; ++i) wt[i] = (unsigned short*)alloc(1024 * 1024 * 2);
  unsigned short* wi0t = (unsigned short*)alloc(4096 * 1024 * 2);
  unsigned short* wi1t = (unsigned short*)alloc(4096 * 1024 * 2);
  unsigned short* wot  = (unsigned short*)alloc(1024 * 4096 * 2);
  unsigned short* encbf = (unsigned short*)alloc(2048 * 1024 * 2);
  float* rb = (float*)alloc(16 * 512 * 4);
  unsigned short* xn = (unsigned short*)alloc(2048 * 1024 * 2);
  float* vf = (float*)alloc(2048 * 1024 * 4);
  unsigned short* qbf = (unsigned short*)alloc(2048 * 1024 * 2);
  unsigned short* kbf = (unsigned short*)alloc(2048 * 1024 * 2);
  unsigned short* vtb = (unsigned short*)alloc((size_t)64 * 64 * 512 * 2);
  float* low0 = (float*)alloc(2048 * 32 * 4);
  float* low1 = (float*)alloc(2048 * 32 * 4);
  float* low2 = (float*)alloc(2048 * 32 * 4);
  char*  big  = alloc((size_t)64 << 20);   // 64 MB multi-use scratch
  unsigned short* ctxb = (unsigned short*)alloc(2048 * 1024 * 2);
  float* xres = (float*)alloc(2048 * 1024 * 4);
  float* yres = (float*)alloc(2048 * 1024 * 4);
  // aliases in `big` (stream-serial lifetimes):
  float* qp = (float*)big;                   // QKV partials: 6*8 MB
  float* kp = qp + 2 * PART;
  float* vp = qp + 4 * PART;
  float* op = (float*)big;                   // out-proj partials: 2*8 MB
  unsigned short* hbf = (unsigned short*)big;              // 16 MB bf16 [2048][4096]
  float* fp = (float*)(big + ((size_t)16 << 20));          // 4*8 MB final partials
  (void)ws_size; (void)in_sizes; (void)n_in; (void)out_size;

  // ---- weight convert + transpose ----
  WtArgs wa;
  int ts = 0;
  for (int i = 0; i < 8; ++i) {
    wa.src[i] = f_W[i]; wa.dst[i] = wt[i]; wa.K[i] = 1024; wa.N[i] = 1024;
    wa.tstart[i] = ts; ts += 32 * 32;
  }
  wa.src[8] = f_wi0; wa.dst[8] = wi0t; wa.K[8] = 1024; wa.N[8] = 4096; wa.tstart[8] = ts; ts += 32 * 128;
  wa.src[9] = f_wi1; wa.dst[9] = wi1t; wa.K[9] = 1024; wa.N[9] = 4096; wa.tstart[9] = ts; ts += 32 * 128;
  wa.src[10] = f_wo; wa.dst[10] = wot; wa.K[10] = 4096; wa.N[10] = 1024; wa.tstart[10] = ts; ts += 128 * 32;
  wa.tstart[11] = ts;
  k_wtconv<<<dim3(ts), dim3(256), 0, stream>>>(wa);

  k_f2bf<<<dim3(2048), dim3(256), 0, stream>>>(f_encoded, encbf);
  k_relbias<<<dim3(32), dim3(256), 0, stream>>>(f_table, rb);

  // ================= self-attention =================
  k_rmsnorm<<<dim3(2048), dim3(256), 0, stream>>>(f_inputs, f_ln1, xn);

  G3S g_qkv = { {xn, xn, xn}, {wt[0], wt[1], wt[2]}, {qp, kp, vp},
                1024, 1024, 1024, 1024, 2, 512, PART };
  k_gemm3s<<<dim3(8, 16, 6), dim3(256), 0, stream>>>(g_qkv);

  Low3 lo_s = { {xn, xn, xn}, {f_qa, f_ka, f_va}, {low0, low1, low2} };
  k_lora_low<<<dim3(2048, 1, 3), dim3(256), 0, stream>>>(lo_s);
  Addb3 ab_s = { {low0, low1, low2}, {f_qb, f_kb, f_vb},
                 {qp, kp, vp}, {qp + PART, kp + PART, vp + PART},
                 {nullptr, nullptr, vf}, {nullptr, nullptr, nullptr}, {qbf, kbf, nullptr} };
  k_lora_addb<<<dim3(2048, 1, 3), dim3(256), 0, stream>>>(ab_s);

  k_vtrans<<<dim3(8, 64), dim3(256), 0, stream>>>(vf, vtb);
  k_flash<true><<<dim3(8, 64), dim3(256), 0, stream>>>(qbf, kbf, vtb, rb, ctxb);

  k_gemm1s<<<dim3(8, 16, 2), dim3(256), 0, stream>>>(ctxb, wt[3], op, PART, 512, 1024, 1024, 1024);
  Low3 lo_o = { {ctxb, ctxb, ctxb}, {f_oa, f_oa, f_oa}, {low0, low0, low0} };
  k_lora_low<<<dim3(2048, 1, 1), dim3(256), 0, stream>>>(lo_o);
  Addb3 ab_o = { {low0, low0, low0}, {f_ob, f_ob, f_ob},
                 {op, op, op}, {op + PART, op + PART, op + PART},
                 {xres, xres, xres}, {f_inputs, f_inputs, f_inputs},
                 {nullptr, nullptr, nullptr} };
  k_lora_addb<<<dim3(2048, 1, 1), dim3(256), 0, stream>>>(ab_o);

  // ================= cross-attention =================
  k_rmsnorm<<<dim3(2048), dim3(256), 0, stream>>>(xres, f_ln2, xn);

  G3S g_cqkv = { {xn, encbf, encbf}, {wt[4], wt[5], wt[6]}, {qp, kp, vp},
                 1024, 1024, 1024, 1024, 2, 512, PART };
  k_gemm3s<<<dim3(8, 16, 6), dim3(256), 0, stream>>>(g_cqkv);

  Low3 lo_c = { {xn, encbf, encbf}, {f_qa + SEL1, f_ka + SEL1, f_va + SEL1}, {low0, low1, low2} };
  k_lora_low<<<dim3(2048, 1, 3), dim3(256), 0, stream>>>(lo_c);
  Addb3 ab_c = { {low0, low1, low2}, {f_qb + SEL1, f_kb + SEL1, f_vb + SEL1},
                 {qp, kp, vp}, {qp + PART, kp + PART, vp + PART},
                 {nullptr, nullptr, vf}, {nullptr, nullptr, nullptr}, {qbf, kbf, nullptr} };
  k_lora_addb<<<dim3(2048, 1, 3), dim3(256), 0, stream>>>(ab_c);

  k_vtrans<<<dim3(8, 64), dim3(256), 0, stream>>>(vf, vtb);
  k_flash<false><<<dim3(8, 64), dim3(256), 0, stream>>>(qbf, kbf, vtb, rb, ctxb);

  k_gemm1s<<<dim3(8, 16, 2), dim3(256), 0, stream>>>(ctxb, wt[7], op, PART, 512, 1024, 1024, 1024);
  Low3 lo_co = { {ctxb, ctxb, ctxb}, {f_oa + SEL1, f_oa + SEL1, f_oa + SEL1}, {low0, low0, low0} };
  k_lora_low<<<dim3(2048, 1, 1), dim3(256), 0, stream>>>(lo_co);
  Addb3 ab_co = { {low0, low0, low0}, {f_ob + SEL1, f_ob + SEL1, f_ob + SEL1},
                  {op, op, op}, {op + PART, op + PART, op + PART},
                  {yres, yres, yres}, {xres, xres, xres},
                  {nullptr, nullptr, nullptr} };
  k_lora_addb<<<dim3(2048, 1, 1), dim3(256), 0, stream>>>(ab_co);

  // ================= gated-gelu MLP =================
  k_rmsnorm<<<dim3(2048), dim3(256), 0, stream>>>(yres, f_ln3, xn);
  k_mlp<<<dim3(32, 16), dim3(256), 0, stream>>>(xn, wi0t, wi1t, hbf);
  k_gemm1s<<<dim3(8, 16, 4), dim3(256), 0, stream>>>(hbf, wot, fp, PART, 1024, 4096, 4096, 1024);
  k_sum4<<<dim3(2048), dim3(256), 0, stream>>>(fp, PART, yres, (float*)d_out);
}

// Round 4
// 670.640 us; speedup vs baseline: 1.2231x; 1.0368x over previous
//
#include <hip/hip_runtime.h>
#include <math.h>

// ---------------------------------------------------------------------------
// LoRA T5 decoder layer on MI355X (gfx950).
// B=4, L=ENC=512, D=1024, H=16, HD=64, MLP=4096, R=32.
// bf16 MFMA 16x16x32; m97-style global_load_lds staging.
// R3->R4: (1) k_mlp restructured: interleaved combined weight wc[8192][1024],
// 128x64 h-tiles, 4x2 dual acc, 1024 blocks (occupancy fix);
// (2) LoRA kernels process 8 rows/block (a/b matrix L2 traffic / 8);
// (3) out-proj split-K 2->4; addb takes (base, ngin, stride) partial list.
// ---------------------------------------------------------------------------

#define DEV __device__ __forceinline__

typedef __bf16 bf16x8 __attribute__((ext_vector_type(8)));
typedef float floatx4 __attribute__((ext_vector_type(4)));

typedef __attribute__((address_space(1))) void* gas_ptr;
typedef __attribute__((address_space(3))) void* las_ptr;

DEV unsigned short f2bf(float f) {
  union { float f; unsigned int u; } v; v.f = f;
  unsigned int r = v.u + 0x7fffu + ((v.u >> 16) & 1u);
  return (unsigned short)(r >> 16);
}
DEV float bf2f(unsigned short u) {
  union { unsigned int u; float f; } v; v.u = ((unsigned int)u) << 16;
  return v.f;
}

#define GLOAD_LDS16(g, l) __builtin_amdgcn_global_load_lds((gas_ptr)(g), (las_ptr)(l), 16, 0, 0)

// Stage nrows x 64 bf16 (128 B rows) from global (row stride ldbytes) into LDS.
template<int NW>
DEV void stage_tile(const char* gbase, char* lds, int nrows, int ldbytes, int wave, int lane) {
  int nchunks = nrows >> 3;
  for (int c = wave; c < nchunks; c += NW) {
    int row  = (c << 3) + (lane >> 3);
    int colb = (lane & 7) << 4;
    GLOAD_LDS16(gbase + (size_t)row * ldbytes + colb, lds + (c << 10));
  }
}

// C = A[M,K] * Bt[N,K]^T, bf16 in / fp32 out. 128x128 tile, 4 waves.
template<int WM, int WN>
DEV void gemm_core(const unsigned short* A, const unsigned short* Bt, float* C,
                   int K, int lda, int ldb, int ldc, int m0, int n0,
                   char* ldsA, char* ldsB) {
  constexpr int NW = WM * WN;
  const int tid  = threadIdx.x;
  const int lane = tid & 63;
  const int wave = tid >> 6;
  const int wm   = wave % WM;
  const int wn   = wave / WM;
  const int quad = lane >> 4;
  const int l15  = lane & 15;

  floatx4 acc[4][4];
#pragma unroll
  for (int i = 0; i < 4; ++i)
#pragma unroll
    for (int j = 0; j < 4; ++j) acc[i][j] = (floatx4){0.f, 0.f, 0.f, 0.f};

  const char* gA = (const char*)(A + (size_t)m0 * lda);
  const char* gB = (const char*)(Bt + (size_t)n0 * ldb);

  for (int k0 = 0; k0 < K; k0 += 64) {
    stage_tile<NW>(gA + (size_t)k0 * 2, ldsA, WM * 64, lda * 2, wave, lane);
    stage_tile<NW>(gB + (size_t)k0 * 2, ldsB, WN * 64, ldb * 2, wave, lane);
    __syncthreads();
#pragma unroll
    for (int kk = 0; kk < 64; kk += 32) {
      bf16x8 af[4], bv[4];
      const char* baseA = ldsA + (size_t)(wm * 64 + l15) * 128 + (kk + quad * 8) * 2;
      const char* baseB = ldsB + (size_t)(wn * 64 + l15) * 128 + (kk + quad * 8) * 2;
#pragma unroll
      for (int mi = 0; mi < 4; ++mi) af[mi] = *(const bf16x8*)(baseA + mi * 2048);
#pragma unroll
      for (int ni = 0; ni < 4; ++ni) bv[ni] = *(const bf16x8*)(baseB + ni * 2048);
#pragma unroll
      for (int mi = 0; mi < 4; ++mi)
#pragma unroll
        for (int ni = 0; ni < 4; ++ni)
          acc[mi][ni] = __builtin_amdgcn_mfma_f32_16x16x32_bf16(af[mi], bv[ni], acc[mi][ni], 0, 0, 0);
    }
    __syncthreads();
  }

#pragma unroll
  for (int mi = 0; mi < 4; ++mi) {
#pragma unroll
    for (int r = 0; r < 4; ++r) {
      int row = m0 + wm * 64 + mi * 16 + quad * 4 + r;
#pragma unroll
      for (int ni = 0; ni < 4; ++ni) {
        int col = n0 + wn * 64 + ni * 16 + l15;
        C[(size_t)row * ldc + col] = acc[mi][ni][r];
      }
    }
  }
}

// ---------------- GEMM wrappers ----------------

struct G3S {
  const unsigned short* A[3];
  const unsigned short* B[3];
  float* C[3];
  int K, lda, ldb, ldc, S, Kchunk;
  size_t pstride;
};
__global__ __launch_bounds__(256) void k_gemm3s(G3S g) {
  __shared__ char lds[32768];
  int z = blockIdx.z;
  int gi = z / g.S, s = z - gi * g.S;
  size_t koff = (size_t)s * g.Kchunk;
  gemm_core<2, 2>(g.A[gi] + koff, g.B[gi] + koff,
                  g.C[gi] + (size_t)s * g.pstride,
                  g.Kchunk, g.lda, g.ldb, g.ldc,
                  blockIdx.y * 128, blockIdx.x * 128, lds, lds + 16384);
}

__global__ __launch_bounds__(256) void k_gemm1s(const unsigned short* A, const unsigned short* Bt,
                                                float* Cpart, size_t pstride,
                                                int Kchunk, int lda, int ldb, int ldc) {
  __shared__ char lds[32768];
  int s = blockIdx.z;
  size_t koff = (size_t)s * Kchunk;
  gemm_core<2, 2>(A + koff, Bt + koff, Cpart + (size_t)s * pstride,
                  Kchunk, lda, ldb, ldc,
                  blockIdx.y * 128, blockIdx.x * 128, lds, lds + 16384);
}

// Fused MLP with interleaved combined weight Wc[8192][1024]:
// 64-row group g of h-cols maps to Wc rows g*128..g*128+63 (wi0) and +64..+127 (wi1).
// Block computes a 128x64 h-tile; wave (wm,wn) owns 64 rows x 32 cols, dual acc 4x2.
__global__ __launch_bounds__(256) void k_mlp(const unsigned short* A, const unsigned short* Wc,
                                             unsigned short* hbf) {
  __shared__ char lds[32768];
  char* ldsA = lds;          // 128 rows x 64k
  char* ldsB = lds + 16384;  // 128 rows (64 wi0 + 64 wi1) x 64k
  const int m0 = blockIdx.y * 128;
  const int n0 = blockIdx.x * 64;
  const int tid = threadIdx.x, lane = tid & 63, wave = tid >> 6;
  const int wm = wave & 1, wn = wave >> 1;
  const int quad = lane >> 4, l15 = lane & 15;

  floatx4 acc0[4][2], acc1[4][2];
#pragma unroll
  for (int i = 0; i < 4; ++i)
#pragma unroll
    for (int j = 0; j < 2; ++j) {
      acc0[i][j] = (floatx4){0.f, 0.f, 0.f, 0.f};
      acc1[i][j] = (floatx4){0.f, 0.f, 0.f, 0.f};
    }

  const char* gA = (const char*)(A + (size_t)m0 * 1024);
  const char* gB = (const char*)(Wc + (size_t)blockIdx.x * 128 * 1024);

  for (int k0 = 0; k0 < 1024; k0 += 64) {
    stage_tile<4>(gA + (size_t)k0 * 2, ldsA, 128, 2048, wave, lane);
    stage_tile<4>(gB + (size_t)k0 * 2, ldsB, 128, 2048, wave, lane);
    __syncthreads();
#pragma unroll
    for (int kk = 0; kk < 64; kk += 32) {
      bf16x8 af[4], b0[2], b1[2];
      const char* baseA = ldsA + (size_t)(wm * 64 + l15) * 128 + (kk + quad * 8) * 2;
#pragma unroll
      for (int mi = 0; mi < 4; ++mi) af[mi] = *(const bf16x8*)(baseA + mi * 2048);
#pragma unroll
      for (int ni = 0; ni < 2; ++ni) {
        b0[ni] = *(const bf16x8*)(ldsB + (size_t)(wn * 32 + ni * 16 + l15) * 128 + (kk + quad * 8) * 2);
        b1[ni] = *(const bf16x8*)(ldsB + (size_t)(64 + wn * 32 + ni * 16 + l15) * 128 + (kk + quad * 8) * 2);
      }
#pragma unroll
      for (int mi = 0; mi < 4; ++mi)
#pragma unroll
        for (int ni = 0; ni < 2; ++ni) {
          acc0[mi][ni] = __builtin_amdgcn_mfma_f32_16x16x32_bf16(af[mi], b0[ni], acc0[mi][ni], 0, 0, 0);
          acc1[mi][ni] = __builtin_amdgcn_mfma_f32_16x16x32_bf16(af[mi], b1[ni], acc1[mi][ni], 0, 0, 0);
        }
    }
    __syncthreads();
  }

#pragma unroll
  for (int mi = 0; mi < 4; ++mi) {
#pragma unroll
    for (int r = 0; r < 4; ++r) {
      int row = m0 + wm * 64 + mi * 16 + quad * 4 + r;
#pragma unroll
      for (int ni = 0; ni < 2; ++ni) {
        int col = n0 + wn * 32 + ni * 16 + l15;
        float g = acc0[mi][ni][r];
        float v = 0.5f * g * (1.0f + erff(g * 0.70710678f)) * acc1[mi][ni][r];
        hbf[(size_t)row * 4096 + col] = f2bf(v);
      }
    }
  }
}

// ---------------- flash attention ----------------
template<bool CAUSAL>
__global__ __launch_bounds__(256) void k_flash(const unsigned short* qmat, const unsigned short* kmat,
                                               const unsigned short* vt, const float* rb,
                                               unsigned short* ctxb) {
  __shared__ char ldsQ[8192];   // [64 q][64 d] bf16
  __shared__ char ldsK[8192];   // [64 k][64 d]
  __shared__ char ldsV[8192];   // [64 d][64 k]
  __shared__ char ldsP[8192];   // [64 q][64 k]
  __shared__ float lrb[512];

  const int z = blockIdx.y, b = z >> 4, h = z & 15;
  const int q0 = blockIdx.x * 64;
  const int tid = threadIdx.x, lane = tid & 63, wave = tid >> 6;
  const int quad = lane >> 4, l15 = lane & 15;

  const unsigned short* Q = qmat + (size_t)b * 512 * 1024 + h * 64;
  const unsigned short* K = kmat + (size_t)b * 512 * 1024 + h * 64;
  const unsigned short* V = vt + (size_t)z * 64 * 512;   // [64 d][512 k]

  stage_tile<4>((const char*)(Q + (size_t)q0 * 1024), ldsQ, 64, 2048, wave, lane);
  if (CAUSAL)
    for (int i = tid; i < 512; i += 256) lrb[i] = rb[h * 512 + i];

  float m_run[4], l_run[4];
  floatx4 oacc[4];
#pragma unroll
  for (int r = 0; r < 4; ++r) { m_run[r] = -1e30f; l_run[r] = 0.f; }
#pragma unroll
  for (int ni = 0; ni < 4; ++ni) oacc[ni] = (floatx4){0.f, 0.f, 0.f, 0.f};

  const int ktend = CAUSAL ? (blockIdx.x + 1) : 8;
  for (int kt = 0; kt < ktend; ++kt) {
    __syncthreads();
    stage_tile<4>((const char*)(K + (size_t)kt * 64 * 1024), ldsK, 64, 2048, wave, lane);
    stage_tile<4>((const char*)(V + kt * 64), ldsV, 64, 1024, wave, lane);
    __syncthreads();

    floatx4 sacc[4];
#pragma unroll
    for (int ct = 0; ct < 4; ++ct) sacc[ct] = (floatx4){0.f, 0.f, 0.f, 0.f};
    const char* aBase = ldsQ + (size_t)(wave * 16 + l15) * 128 + quad * 16;
#pragma unroll
    for (int kd = 0; kd < 2; ++kd) {
      bf16x8 af = *(const bf16x8*)(aBase + kd * 64);
#pragma unroll
      for (int ct = 0; ct < 4; ++ct) {
        bf16x8 bf = *(const bf16x8*)(ldsK + (size_t)(ct * 16 + l15) * 128 + quad * 16 + kd * 64);
        sacc[ct] = __builtin_amdgcn_mfma_f32_16x16x32_bf16(af, bf, sacc[ct], 0, 0, 0);
      }
    }

    float sv[4][4];
#pragma unroll
    for (int ct = 0; ct < 4; ++ct)
#pragma unroll
      for (int r = 0; r < 4; ++r) {
        float v = sacc[ct][r] * 0.125f;
        if (CAUSAL) {
          int qq = q0 + wave * 16 + quad * 4 + r;
          int kk = kt * 64 + ct * 16 + l15;
          v = (kk <= qq) ? v + lrb[qq - kk] : -1e30f;
        }
        sv[ct][r] = v;
      }

    float mx[4];
#pragma unroll
    for (int r = 0; r < 4; ++r)
      mx[r] = fmaxf(fmaxf(sv[0][r], sv[1][r]), fmaxf(sv[2][r], sv[3][r]));
#pragma unroll
    for (int o = 1; o < 16; o <<= 1)
#pragma unroll
      for (int r = 0; r < 4; ++r) mx[r] = fmaxf(mx[r], __shfl_xor(mx[r], o));

    float alpha[4], rs[4];
#pragma unroll
    for (int r = 0; r < 4; ++r) {
      float mn = fmaxf(m_run[r], mx[r]);
      alpha[r] = expf(m_run[r] - mn);
      m_run[r] = mn;
      rs[r] = 0.f;
    }
#pragma unroll
    for (int ct = 0; ct < 4; ++ct)
#pragma unroll
      for (int r = 0; r < 4; ++r) {
        float p = expf(sv[ct][r] - m_run[r]);
        sv[ct][r] = p;
        rs[r] += p;
      }
#pragma unroll
    for (int o = 1; o < 16; o <<= 1)
#pragma unroll
      for (int r = 0; r < 4; ++r) rs[r] += __shfl_xor(rs[r], o);
#pragma unroll
    for (int r = 0; r < 4; ++r) l_run[r] = l_run[r] * alpha[r] + rs[r];
#pragma unroll
    for (int ni = 0; ni < 4; ++ni)
#pragma unroll
      for (int r = 0; r < 4; ++r) oacc[ni][r] *= alpha[r];

#pragma unroll
    for (int ct = 0; ct < 4; ++ct)
#pragma unroll
      for (int r = 0; r < 4; ++r)
        *(unsigned short*)(ldsP + (size_t)(wave * 16 + quad * 4 + r) * 128 + (ct * 16 + l15) * 2)
            = f2bf(sv[ct][r]);
    __syncthreads();

    const char* pBase = ldsP + (size_t)(wave * 16 + l15) * 128 + quad * 16;
#pragma unroll
    for (int kd = 0; kd < 2; ++kd) {
      bf16x8 pf = *(const bf16x8*)(pBase + kd * 64);
#pragma unroll
      for (int ni = 0; ni < 4; ++ni) {
        bf16x8 vf8 = *(const bf16x8*)(ldsV + (size_t)(ni * 16 + l15) * 128 + quad * 16 + kd * 64);
        oacc[ni] = __builtin_amdgcn_mfma_f32_16x16x32_bf16(pf, vf8, oacc[ni], 0, 0, 0);
      }
    }
  }

#pragma unroll
  for (int r = 0; r < 4; ++r) {
    int q = q0 + wave * 16 + quad * 4 + r;
    float inv = 1.0f / l_run[r];
    unsigned short* dst = ctxb + ((size_t)b * 512 + q) * 1024 + h * 64;
#pragma unroll
    for (int ni = 0; ni < 4; ++ni)
      dst[ni * 16 + l15] = f2bf(oacc[ni][r] * inv);
  }
}

// ---------------- small kernels ----------------

// fp32 [K][N] -> bf16 [N][K]; mode 1/2: interleave 64-row groups into Wc rows
// g*128+(n&63) (mode1=wi0) / g*128+64+(n&63) (mode2=wi1).
struct WtArgs {
  const float* src[11];
  unsigned short* dst[11];
  int K[11], N[11], mode[11];
  int tstart[12];
};
__global__ __launch_bounds__(256) void k_wtconv(WtArgs a) {
  int bid = blockIdx.x;
  int z = 0;
  while (z < 10 && bid >= a.tstart[z + 1]) ++z;
  int tile = bid - a.tstart[z];
  int N = a.N[z], K = a.K[z], mode = a.mode[z];
  int ntn = N >> 5;
  int tn = tile % ntn, tk = tile / ntn;
  __shared__ float tl[32][33];
  int t = threadIdx.x, tx = t & 31, ty = t >> 5;
  const float* src = a.src[z];
  unsigned short* dst = a.dst[z];
#pragma unroll
  for (int i = 0; i < 32; i += 8)
    tl[ty + i][tx] = src[(size_t)(tk * 32 + ty + i) * N + tn * 32 + tx];
  __syncthreads();
#pragma unroll
  for (int i = 0; i < 32; i += 8) {
    int n = tn * 32 + ty + i;
    int orow = (mode == 0) ? n : ((n >> 6) * 128 + ((mode == 2) ? 64 : 0) + (n & 63));
    dst[(size_t)orow * K + tk * 32 + tx] = f2bf(tl[tx][ty + i]);
  }
}

__global__ void k_f2bf(const float* in, unsigned short* out) {
  int i = blockIdx.x * 256 + threadIdx.x;
  float4 v = ((const float4*)in)[i];
  ushort4 o;
  o.x = f2bf(v.x); o.y = f2bf(v.y); o.z = f2bf(v.z); o.w = f2bf(v.w);
  ((ushort4*)out)[i] = o;
}

__global__ void k_relbias(const float* table, float* rb) {
  int i = blockIdx.x * 256 + threadIdx.x;
  if (i >= 16 * 512) return;
  int h = i >> 9, d = i & 511;
  int bucket;
  if (d < 16) bucket = d;
  else {
    int lb = 16 + (int)(logf((float)d / 16.0f) / logf(8.0f) * 16.0f);
    bucket = lb < 31 ? lb : 31;
  }
  rb[i] = table[bucket * 16 + h];
}

__global__ __launch_bounds__(256) void k_rmsnorm(const float* x, const float* sc, unsigned short* out) {
  int row = blockIdx.x, t = threadIdx.x;
  float4 v = ((const float4*)(x + (size_t)row * 1024))[t];
  float ss = v.x * v.x + v.y * v.y + v.z * v.z + v.w * v.w;
  for (int o = 32; o; o >>= 1) ss += __shfl_down(ss, o);
  __shared__ float red[4];
  if ((t & 63) == 0) red[t >> 6] = ss;
  __syncthreads();
  float tot = red[0] + red[1] + red[2] + red[3];
  float rs = rsqrtf(tot * (1.0f / 1024.0f) + 1e-6f);
  float4 s4 = ((const float4*)sc)[t];
  ushort4 o;
  o.x = f2bf(v.x * rs * s4.x); o.y = f2bf(v.y * rs * s4.y);
  o.z = f2bf(v.z * rs * s4.z); o.w = f2bf(v.w * rs * s4.w);
  ((ushort4*)(out + (size_t)row * 1024))[t] = o;
}

__global__ __launch_bounds__(256) void k_vtrans(const float* vf, unsigned short* vt) {
  int z = blockIdx.y, b = z >> 4, h = z & 15;
  int k0 = blockIdx.x * 64;
  __shared__ float tl[64][65];
  int t = threadIdx.x;
  int d = t & 63, kr = t >> 6;
#pragma unroll
  for (int i = 0; i < 64; i += 4)
    tl[kr + i][d] = vf[(size_t)(b * 512 + k0 + kr + i) * 1024 + h * 64 + d];
  __syncthreads();
  int dw = t >> 2, kc = (t & 3) * 16;
  unsigned short* dst = vt + ((size_t)z * 64 + dw) * 512 + k0 + kc;
#pragma unroll
  for (int j = 0; j < 16; ++j) dst[j] = f2bf(tl[kc + j][dw]);
}

// low[row][r] = sum_k x[row][k] * a[b][k][r]. 8 rows/block; thread=(j,r).
// a-values broadcast across the 32 r-lanes' neighbors; reused via L1 across waves.
struct Low3 {
  const unsigned short* x[3];
  const float* a[3];
  float* low[3];
};
__global__ __launch_bounds__(256) void k_lora_low(Low3 g) {
  int z = blockIdx.z;
  int row0 = blockIdx.x * 8;
  int b = row0 >> 9;
  int t = threadIdx.x, r = t & 31, j = t >> 5;
  const bf16x8* xv = (const bf16x8*)(g.x[z] + (size_t)(row0 + j) * 1024);
  const float* a = g.a[z] + ((size_t)b << 16);
  float s = 0.f;
  for (int kb = 0; kb < 128; ++kb) {
    bf16x8 v = xv[kb];
#pragma unroll
    for (int u = 0; u < 8; ++u)
      s += (float)v[u] * a[(size_t)(kb * 8 + u) * 32 + r];
  }
  g.low[z][(size_t)(row0 + j) * 32 + r] = s;
}

// gout = sum_{p<ngin} gin[z]+p*gstride (+resid) + low@bm; 8 rows/block.
struct Addb3 {
  const float* low[3];
  const float* bm[3];
  const float* gin[3];
  float* gout[3];
  const float* resid[3];
  unsigned short* mirror[3];
  int ngin;
  size_t gstride;
};
__global__ __launch_bounds__(256) void k_lora_addb(Addb3 g) {
  int z = blockIdx.z;
  int row0 = blockIdx.x * 8;
  int b = row0 >> 9;
  const float* bm = g.bm[z] + ((size_t)b << 16);
  int t = threadIdx.x;
  __shared__ float lsh[8][32];
  lsh[t >> 5][t & 31] = g.low[z][(size_t)row0 * 32 + t];
  __syncthreads();
  float4 acc[8];
#pragma unroll
  for (int j = 0; j < 8; ++j) acc[j] = (float4){0.f, 0.f, 0.f, 0.f};
  for (int r = 0; r < 32; ++r) {
    float4 b4 = ((const float4*)(bm + (size_t)r * 1024))[t];
#pragma unroll
    for (int j = 0; j < 8; ++j) {
      float lv = lsh[j][r];
      acc[j].x += lv * b4.x; acc[j].y += lv * b4.y;
      acc[j].z += lv * b4.z; acc[j].w += lv * b4.w;
    }
  }
#pragma unroll
  for (int j = 0; j < 8; ++j) {
    size_t idx = (size_t)(row0 + j) * 256 + t;
    float4 s = acc[j];
    for (int p = 0; p < g.ngin; ++p) {
      float4 gv = ((const float4*)(g.gin[z] + (size_t)p * g.gstride))[idx];
      s.x += gv.x; s.y += gv.y; s.z += gv.z; s.w += gv.w;
    }
    if (g.resid[z]) {
      float4 rv = ((const float4*)g.resid[z])[idx];
      s.x += rv.x; s.y += rv.y; s.z += rv.z; s.w += rv.w;
    }
    if (g.gout[z]) ((float4*)g.gout[z])[idx] = s;
    if (g.mirror[z]) {
      ushort4 mo; mo.x = f2bf(s.x); mo.y = f2bf(s.y); mo.z = f2bf(s.z); mo.w = f2bf(s.w);
      ((ushort4*)g.mirror[z])[idx] = mo;
    }
  }
}

// out = p0+p1+p2+p3 + resid
__global__ void k_sum4(const float* p, size_t pstride, const float* resid, float* out) {
  int i = blockIdx.x * 256 + threadIdx.x;
  float4 a = ((const float4*)p)[i];
  float4 b = ((const float4*)(p + pstride))[i];
  float4 c = ((const float4*)(p + 2 * pstride))[i];
  float4 d = ((const float4*)(p + 3 * pstride))[i];
  float4 r = ((const float4*)resid)[i];
  float4 o;
  o.x = a.x + b.x + c.x + d.x + r.x;
  o.y = a.y + b.y + c.y + d.y + r.y;
  o.z = a.z + b.z + c.z + d.z + r.z;
  o.w = a.w + b.w + c.w + d.w + r.w;
  ((float4*)out)[i] = o;
}

// ---------------------------------------------------------------------------

extern "C" void kernel_launch(void* const* d_in, const int* in_sizes, int n_in,
                              void* d_out, int out_size, void* d_ws, size_t ws_size,
                              hipStream_t stream) {
  const float* f_inputs  = (const float*)d_in[0];
  const float* f_encoded = (const float*)d_in[1];
  const float* f_qa = (const float*)d_in[2];
  const float* f_qb = (const float*)d_in[3];
  const float* f_ka = (const float*)d_in[4];
  const float* f_kb = (const float*)d_in[5];
  const float* f_va = (const float*)d_in[6];
  const float* f_vb = (const float*)d_in[7];
  const float* f_oa = (const float*)d_in[8];
  const float* f_ob = (const float*)d_in[9];
  const float* f_table = (const float*)d_in[10];
  const float* f_ln1 = (const float*)d_in[11];
  const float* f_ln2 = (const float*)d_in[12];
  const float* f_ln3 = (const float*)d_in[13];
  const float* f_W[8] = { (const float*)d_in[14], (const float*)d_in[15],
                          (const float*)d_in[16], (const float*)d_in[17],
                          (const float*)d_in[18], (const float*)d_in[19],
                          (const float*)d_in[20], (const float*)d_in[21] };
  const float* f_wi0 = (const float*)d_in[22];
  const float* f_wi1 = (const float*)d_in[23];
  const float* f_wo  = (const float*)d_in[24];

  const size_t SEL1 = 32768;               // sel stride in lora a/b arrays
  const size_t PART = (size_t)2048 * 1024; // [2048,1024] fp32 partial (elements)

  char* w = (char*)d_ws;
  size_t off = 0;
  auto alloc = [&](size_t bytes) -> char* {
    off = (off + 255) & ~(size_t)255;
    char* p = w + off;
    off += bytes;
    return p;
  };
  unsigned short* wt[8];
  for (int i = 0; i < 8; ++i) wt[i] = (unsigned short*)alloc(1024 * 1024 * 2);
  unsigned short* wc  = (unsigned short*)alloc((size_t)8192 * 1024 * 2);  // interleaved wi0/wi1
  unsigned short* wot = (unsigned short*)alloc(1024 * 4096 * 2);
  unsigned short* encbf = (unsigned short*)alloc(2048 * 1024 * 2);
  float* rb = (float*)alloc(16 * 512 * 4);
  unsigned short* xn = (unsigned short*)alloc(2048 * 1024 * 2);
  float* vf = (float*)alloc(2048 * 1024 * 4);
  unsigned short* qbf = (unsigned short*)alloc(2048 * 1024 * 2);
  unsigned short* kbf = (unsigned short*)alloc(2048 * 1024 * 2);
  unsigned short* vtb = (unsigned short*)alloc((size_t)64 * 64 * 512 * 2);
  float* low0 = (float*)alloc(2048 * 32 * 4);
  float* low1 = (float*)alloc(2048 * 32 * 4);
  float* low2 = (float*)alloc(2048 * 32 * 4);
  char*  big  = alloc((size_t)64 << 20);   // 64 MB multi-use scratch
  unsigned short* ctxb = (unsigned short*)alloc(2048 * 1024 * 2);
  float* xres = (float*)alloc(2048 * 1024 * 4);
  float* yres = (float*)alloc(2048 * 1024 * 4);
  // aliases in `big` (stream-serial lifetimes):
  float* qp = (float*)big;                   // QKV partials: 6*8 MB
  float* kp = qp + 2 * PART;
  float* vp = qp + 4 * PART;
  float* op = (float*)big;                   // out-proj partials: 4*8 MB
  unsigned short* hbf = (unsigned short*)big;              // 16 MB bf16 [2048][4096]
  float* fp = (float*)(big + ((size_t)16 << 20));          // 4*8 MB final partials
  (void)ws_size; (void)in_sizes; (void)n_in; (void)out_size;

  // ---- weight convert + transpose ----
  WtArgs wa;
  int ts = 0;
  for (int i = 0; i < 8; ++i) {
    wa.src[i] = f_W[i]; wa.dst[i] = wt[i]; wa.K[i] = 1024; wa.N[i] = 1024;
    wa.mode[i] = 0; wa.tstart[i] = ts; ts += 32 * 32;
  }
  wa.src[8] = f_wi0; wa.dst[8] = wc; wa.K[8] = 1024; wa.N[8] = 4096; wa.mode[8] = 1;
  wa.tstart[8] = ts; ts += 32 * 128;
  wa.src[9] = f_wi1; wa.dst[9] = wc; wa.K[9] = 1024; wa.N[9] = 4096; wa.mode[9] = 2;
  wa.tstart[9] = ts; ts += 32 * 128;
  wa.src[10] = f_wo; wa.dst[10] = wot; wa.K[10] = 4096; wa.N[10] = 1024; wa.mode[10] = 0;
  wa.tstart[10] = ts; ts += 128 * 32;
  wa.tstart[11] = ts;
  k_wtconv<<<dim3(ts), dim3(256), 0, stream>>>(wa);

  k_f2bf<<<dim3(2048), dim3(256), 0, stream>>>(f_encoded, encbf);
  k_relbias<<<dim3(32), dim3(256), 0, stream>>>(f_table, rb);

  // ================= self-attention =================
  k_rmsnorm<<<dim3(2048), dim3(256), 0, stream>>>(f_inputs, f_ln1, xn);

  G3S g_qkv = { {xn, xn, xn}, {wt[0], wt[1], wt[2]}, {qp, kp, vp},
                1024, 1024, 1024, 1024, 2, 512, PART };
  k_gemm3s<<<dim3(8, 16, 6), dim3(256), 0, stream>>>(g_qkv);

  Low3 lo_s = { {xn, xn, xn}, {f_qa, f_ka, f_va}, {low0, low1, low2} };
  k_lora_low<<<dim3(256, 1, 3), dim3(256), 0, stream>>>(lo_s);
  Addb3 ab_s = { {low0, low1, low2}, {f_qb, f_kb, f_vb}, {qp, kp, vp},
                 {nullptr, nullptr, vf}, {nullptr, nullptr, nullptr},
                 {qbf, kbf, nullptr}, 2, PART };
  k_lora_addb<<<dim3(256, 1, 3), dim3(256), 0, stream>>>(ab_s);

  k_vtrans<<<dim3(8, 64), dim3(256), 0, stream>>>(vf, vtb);
  k_flash<true><<<dim3(8, 64), dim3(256), 0, stream>>>(qbf, kbf, vtb, rb, ctxb);

  k_gemm1s<<<dim3(8, 16, 4), dim3(256), 0, stream>>>(ctxb, wt[3], op, PART, 256, 1024, 1024, 1024);
  Low3 lo_o = { {ctxb, ctxb, ctxb}, {f_oa, f_oa, f_oa}, {low0, low0, low0} };
  k_lora_low<<<dim3(256, 1, 1), dim3(256), 0, stream>>>(lo_o);
  Addb3 ab_o = { {low0, low0, low0}, {f_ob, f_ob, f_ob}, {op, op, op},
                 {xres, xres, xres}, {f_inputs, f_inputs, f_inputs},
                 {nullptr, nullptr, nullptr}, 4, PART };
  k_lora_addb<<<dim3(256, 1, 1), dim3(256), 0, stream>>>(ab_o);

  // ================= cross-attention =================
  k_rmsnorm<<<dim3(2048), dim3(256), 0, stream>>>(xres, f_ln2, xn);

  G3S g_cqkv = { {xn, encbf, encbf}, {wt[4], wt[5], wt[6]}, {qp, kp, vp},
                 1024, 1024, 1024, 1024, 2, 512, PART };
  k_gemm3s<<<dim3(8, 16, 6), dim3(256), 0, stream>>>(g_cqkv);

  Low3 lo_c = { {xn, encbf, encbf}, {f_qa + SEL1, f_ka + SEL1, f_va + SEL1}, {low0, low1, low2} };
  k_lora_low<<<dim3(256, 1, 3), dim3(256), 0, stream>>>(lo_c);
  Addb3 ab_c = { {low0, low1, low2}, {f_qb + SEL1, f_kb + SEL1, f_vb + SEL1}, {qp, kp, vp},
                 {nullptr, nullptr, vf}, {nullptr, nullptr, nullptr},
                 {qbf, kbf, nullptr}, 2, PART };
  k_lora_addb<<<dim3(256, 1, 3), dim3(256), 0, stream>>>(ab_c);

  k_vtrans<<<dim3(8, 64), dim3(256), 0, stream>>>(vf, vtb);
  k_flash<false><<<dim3(8, 64), dim3(256), 0, stream>>>(qbf, kbf, vtb, rb, ctxb);

  k_gemm1s<<<dim3(8, 16, 4), dim3(256), 0, stream>>>(ctxb, wt[7], op, PART, 256, 1024, 1024, 1024);
  Low3 lo_co = { {ctxb, ctxb, ctxb}, {f_oa + SEL1, f_oa + SEL1, f_oa + SEL1}, {low0, low0, low0} };
  k_lora_low<<<dim3(256, 1, 1), dim3(256), 0, stream>>>(lo_co);
  Addb3 ab_co = { {low0, low0, low0}, {f_ob + SEL1, f_ob + SEL1, f_ob + SEL1}, {op, op, op},
                  {yres, yres, yres}, {xres, xres, xres},
                  {nullptr, nullptr, nullptr}, 4, PART };
  k_lora_addb<<<dim3(256, 1, 1), dim3(256), 0, stream>>>(ab_co);

  // ================= gated-gelu MLP =================
  k_rmsnorm<<<dim3(2048), dim3(256), 0, stream>>>(yres, f_ln3, xn);
  k_mlp<<<dim3(64, 16), dim3(256), 0, stream>>>(xn, wc, hbf);
  k_gemm1s<<<dim3(8, 16, 4), dim3(256), 0, stream>>>(hbf, wot, fp, PART, 1024, 4096, 4096, 1024);
  k_sum4<<<dim3(2048), dim3(256), 0, stream>>>(fp, PART, yres, (float*)d_out);
}

// Round 5
// 653.668 us; speedup vs baseline: 1.2549x; 1.0260x over previous
//
#include <hip/hip_runtime.h>
#include <math.h>

// ---------------------------------------------------------------------------
// LoRA T5 decoder layer on MI355X (gfx950).
// B=4, L=ENC=512, D=1024, H=16, HD=64, MLP=4096, R=32.
// bf16 MFMA 16x16x32; m97-style global_load_lds staging.
// R4->R5: (1) k_mlp: 8-wave split-half design — waves 0-3 compute wi0-half,
// waves 4-7 wi1-half of the same 128x128 h-tile at full gemm_core MFMA
// density; h1 exchanged via LDS for the gelu product (weight interleave now
// 256-row groups). (2) flash: 128-k tiles (half the barriers/staging).
// (3) f2bf + relbias folded into the prep kernel.
// ---------------------------------------------------------------------------

#define DEV __device__ __forceinline__

typedef __bf16 bf16x8 __attribute__((ext_vector_type(8)));
typedef float floatx4 __attribute__((ext_vector_type(4)));

typedef __attribute__((address_space(1))) void* gas_ptr;
typedef __attribute__((address_space(3))) void* las_ptr;

DEV unsigned short f2bf(float f) {
  union { float f; unsigned int u; } v; v.f = f;
  unsigned int r = v.u + 0x7fffu + ((v.u >> 16) & 1u);
  return (unsigned short)(r >> 16);
}
DEV float bf2f(unsigned short u) {
  union { unsigned int u; float f; } v; v.u = ((unsigned int)u) << 16;
  return v.f;
}

#define GLOAD_LDS16(g, l) __builtin_amdgcn_global_load_lds((gas_ptr)(g), (las_ptr)(l), 16, 0, 0)

// Stage nrows x 64 bf16 (128 B rows) from global (row stride ldbytes) into LDS.
template<int NW>
DEV void stage_tile(const char* gbase, char* lds, int nrows, int ldbytes, int wave, int lane) {
  int nchunks = nrows >> 3;
  for (int c = wave; c < nchunks; c += NW) {
    int row  = (c << 3) + (lane >> 3);
    int colb = (lane & 7) << 4;
    GLOAD_LDS16(gbase + (size_t)row * ldbytes + colb, lds + (c << 10));
  }
}

// Stage nrows x 128 bf16 (256 B rows) from global (row stride ldbytes) into LDS.
template<int NW>
DEV void stage_tile256(const char* gbase, char* lds, int nrows, int ldbytes, int wave, int lane) {
  int nchunks = nrows >> 2;               // 4 rows per 1 KiB chunk
  for (int c = wave; c < nchunks; c += NW) {
    int row  = (c << 2) + (lane >> 4);
    int colb = (lane & 15) << 4;
    GLOAD_LDS16(gbase + (size_t)row * ldbytes + colb, lds + (c << 10));
  }
}

// C = A[M,K] * Bt[N,K]^T, bf16 in / fp32 out. 128x128 tile, 4 waves.
template<int WM, int WN>
DEV void gemm_core(const unsigned short* A, const unsigned short* Bt, float* C,
                   int K, int lda, int ldb, int ldc, int m0, int n0,
                   char* ldsA, char* ldsB) {
  constexpr int NW = WM * WN;
  const int tid  = threadIdx.x;
  const int lane = tid & 63;
  const int wave = tid >> 6;
  const int wm   = wave % WM;
  const int wn   = wave / WM;
  const int quad = lane >> 4;
  const int l15  = lane & 15;

  floatx4 acc[4][4];
#pragma unroll
  for (int i = 0; i < 4; ++i)
#pragma unroll
    for (int j = 0; j < 4; ++j) acc[i][j] = (floatx4){0.f, 0.f, 0.f, 0.f};

  const char* gA = (const char*)(A + (size_t)m0 * lda);
  const char* gB = (const char*)(Bt + (size_t)n0 * ldb);

  for (int k0 = 0; k0 < K; k0 += 64) {
    stage_tile<NW>(gA + (size_t)k0 * 2, ldsA, WM * 64, lda * 2, wave, lane);
    stage_tile<NW>(gB + (size_t)k0 * 2, ldsB, WN * 64, ldb * 2, wave, lane);
    __syncthreads();
#pragma unroll
    for (int kk = 0; kk < 64; kk += 32) {
      bf16x8 af[4], bv[4];
      const char* baseA = ldsA + (size_t)(wm * 64 + l15) * 128 + (kk + quad * 8) * 2;
      const char* baseB = ldsB + (size_t)(wn * 64 + l15) * 128 + (kk + quad * 8) * 2;
#pragma unroll
      for (int mi = 0; mi < 4; ++mi) af[mi] = *(const bf16x8*)(baseA + mi * 2048);
#pragma unroll
      for (int ni = 0; ni < 4; ++ni) bv[ni] = *(const bf16x8*)(baseB + ni * 2048);
#pragma unroll
      for (int mi = 0; mi < 4; ++mi)
#pragma unroll
        for (int ni = 0; ni < 4; ++ni)
          acc[mi][ni] = __builtin_amdgcn_mfma_f32_16x16x32_bf16(af[mi], bv[ni], acc[mi][ni], 0, 0, 0);
    }
    __syncthreads();
  }

#pragma unroll
  for (int mi = 0; mi < 4; ++mi) {
#pragma unroll
    for (int r = 0; r < 4; ++r) {
      int row = m0 + wm * 64 + mi * 16 + quad * 4 + r;
#pragma unroll
      for (int ni = 0; ni < 4; ++ni) {
        int col = n0 + wn * 64 + ni * 16 + l15;
        C[(size_t)row * ldc + col] = acc[mi][ni][r];
      }
    }
  }
}

// ---------------- GEMM wrappers ----------------

struct G3S {
  const unsigned short* A[3];
  const unsigned short* B[3];
  float* C[3];
  int K, lda, ldb, ldc, S, Kchunk;
  size_t pstride;
};
__global__ __launch_bounds__(256) void k_gemm3s(G3S g) {
  __shared__ char lds[32768];
  int z = blockIdx.z;
  int gi = z / g.S, s = z - gi * g.S;
  size_t koff = (size_t)s * g.Kchunk;
  gemm_core<2, 2>(g.A[gi] + koff, g.B[gi] + koff,
                  g.C[gi] + (size_t)s * g.pstride,
                  g.Kchunk, g.lda, g.ldb, g.ldc,
                  blockIdx.y * 128, blockIdx.x * 128, lds, lds + 16384);
}

__global__ __launch_bounds__(256) void k_gemm1s(const unsigned short* A, const unsigned short* Bt,
                                                float* Cpart, size_t pstride,
                                                int Kchunk, int lda, int ldb, int ldc) {
  __shared__ char lds[32768];
  int s = blockIdx.z;
  size_t koff = (size_t)s * Kchunk;
  gemm_core<2, 2>(A + koff, Bt + koff, Cpart + (size_t)s * pstride,
                  Kchunk, lda, ldb, ldc,
                  blockIdx.y * 128, blockIdx.x * 128, lds, lds + 16384);
}

// Fused MLP, combined weight Wc[8192][1024] interleaved in 256-row groups:
// Wc rows g*256..+127 = wi0 cols g*128..+127; +128..+255 = wi1 same cols.
// 512 threads / 8 waves: waves 0-3 (half=0) compute wi0 64x64 subtiles,
// waves 4-7 (half=1) wi1. h1 crosses via LDS (bf16) for the gelu product.
__global__ __launch_bounds__(512) void k_mlp(const unsigned short* A, const unsigned short* Wc,
                                             unsigned short* hbf) {
  __shared__ char lds[49152];
  char* ldsA = lds;          // 128 rows x 128 B = 16 KB
  char* ldsB = lds + 16384;  // 256 rows x 128 B = 32 KB
  const int m0 = blockIdx.y * 128;
  const int n0 = blockIdx.x * 128;
  const int tid = threadIdx.x, lane = tid & 63, wave = tid >> 6;
  const int half = wave >> 2, wl = wave & 3;
  const int wm = wl & 1, wn = wl >> 1;
  const int quad = lane >> 4, l15 = lane & 15;

  floatx4 acc[4][4];
#pragma unroll
  for (int i = 0; i < 4; ++i)
#pragma unroll
    for (int j = 0; j < 4; ++j) acc[i][j] = (floatx4){0.f, 0.f, 0.f, 0.f};

  const char* gA = (const char*)(A + (size_t)m0 * 1024);
  const char* gB = (const char*)(Wc + (size_t)blockIdx.x * 256 * 1024);

  for (int k0 = 0; k0 < 1024; k0 += 64) {
    stage_tile<8>(gA + (size_t)k0 * 2, ldsA, 128, 2048, wave, lane);
    stage_tile<8>(gB + (size_t)k0 * 2, ldsB, 256, 2048, wave, lane);
    __syncthreads();
#pragma unroll
    for (int kk = 0; kk < 64; kk += 32) {
      bf16x8 af[4], bv[4];
      const char* baseA = ldsA + (size_t)(wm * 64 + l15) * 128 + (kk + quad * 8) * 2;
      const char* baseB = ldsB + (size_t)(half * 128 + wn * 64 + l15) * 128 + (kk + quad * 8) * 2;
#pragma unroll
      for (int mi = 0; mi < 4; ++mi) af[mi] = *(const bf16x8*)(baseA + mi * 2048);
#pragma unroll
      for (int ni = 0; ni < 4; ++ni) bv[ni] = *(const bf16x8*)(baseB + ni * 2048);
#pragma unroll
      for (int mi = 0; mi < 4; ++mi)
#pragma unroll
        for (int ni = 0; ni < 4; ++ni)
          acc[mi][ni] = __builtin_amdgcn_mfma_f32_16x16x32_bf16(af[mi], bv[ni], acc[mi][ni], 0, 0, 0);
    }
    __syncthreads();
  }

  // h1 (half==1) -> LDS exchange (bf16, reuse ldsB: 128 rows x 256 B = 32 KB)
  if (half == 1) {
#pragma unroll
    for (int mi = 0; mi < 4; ++mi)
#pragma unroll
      for (int r = 0; r < 4; ++r) {
        int row = wm * 64 + mi * 16 + quad * 4 + r;
#pragma unroll
        for (int ni = 0; ni < 4; ++ni) {
          int col = wn * 64 + ni * 16 + l15;
          *(unsigned short*)(ldsB + (size_t)row * 256 + col * 2) = f2bf(acc[mi][ni][r]);
        }
      }
  }
  __syncthreads();
  if (half == 0) {
#pragma unroll
    for (int mi = 0; mi < 4; ++mi)
#pragma unroll
      for (int r = 0; r < 4; ++r) {
        int row = wm * 64 + mi * 16 + quad * 4 + r;
#pragma unroll
        for (int ni = 0; ni < 4; ++ni) {
          int col = wn * 64 + ni * 16 + l15;
          float h1 = bf2f(*(const unsigned short*)(ldsB + (size_t)row * 256 + col * 2));
          float g = acc[mi][ni][r];
          float v = 0.5f * g * (1.0f + erff(g * 0.70710678f)) * h1;
          hbf[(size_t)(m0 + row) * 4096 + n0 + col] = f2bf(v);
        }
      }
  }
}

// ---------------- flash attention ----------------
// One block per (64 q rows, z=b*16+h); 128-k tiles per iteration.
template<bool CAUSAL>
__global__ __launch_bounds__(256) void k_flash(const unsigned short* qmat, const unsigned short* kmat,
                                               const unsigned short* vt, const float* rb,
                                               unsigned short* ctxb) {
  __shared__ char ldsQ[8192];    // [64 q][64 d]
  __shared__ char ldsK[16384];   // [128 k][64 d]
  __shared__ char ldsV[16384];   // [64 d][128 k]
  __shared__ char ldsP[16384];   // [64 q][128 k]
  __shared__ float lrb[512];

  const int z = blockIdx.y, b = z >> 4, h = z & 15;
  const int q0 = blockIdx.x * 64;
  const int tid = threadIdx.x, lane = tid & 63, wave = tid >> 6;
  const int quad = lane >> 4, l15 = lane & 15;

  const unsigned short* Q = qmat + (size_t)b * 512 * 1024 + h * 64;
  const unsigned short* K = kmat + (size_t)b * 512 * 1024 + h * 64;
  const unsigned short* V = vt + (size_t)z * 64 * 512;   // [64 d][512 k]

  stage_tile<4>((const char*)(Q + (size_t)q0 * 1024), ldsQ, 64, 2048, wave, lane);
  if (CAUSAL)
    for (int i = tid; i < 512; i += 256) lrb[i] = rb[h * 512 + i];

  float m_run[4], l_run[4];
  floatx4 oacc[4];
#pragma unroll
  for (int r = 0; r < 4; ++r) { m_run[r] = -1e30f; l_run[r] = 0.f; }
#pragma unroll
  for (int ni = 0; ni < 4; ++ni) oacc[ni] = (floatx4){0.f, 0.f, 0.f, 0.f};

  const int ktend = CAUSAL ? (blockIdx.x / 2 + 1) : 4;
  for (int kt = 0; kt < ktend; ++kt) {
    __syncthreads();
    stage_tile<4>((const char*)(K + (size_t)kt * 128 * 1024), ldsK, 128, 2048, wave, lane);
    stage_tile256<4>((const char*)(V + kt * 128), ldsV, 64, 1024, wave, lane);
    __syncthreads();

    // S = Q Kt : wave's 16 q rows x 128 k cols (8 ct)
    floatx4 sacc[8];
#pragma unroll
    for (int ct = 0; ct < 8; ++ct) sacc[ct] = (floatx4){0.f, 0.f, 0.f, 0.f};
    const char* aBase = ldsQ + (size_t)(wave * 16 + l15) * 128 + quad * 16;
#pragma unroll
    for (int kd = 0; kd < 2; ++kd) {
      bf16x8 af = *(const bf16x8*)(aBase + kd * 64);
#pragma unroll
      for (int ct = 0; ct < 8; ++ct) {
        bf16x8 bf = *(const bf16x8*)(ldsK + (size_t)(ct * 16 + l15) * 128 + quad * 16 + kd * 64);
        sacc[ct] = __builtin_amdgcn_mfma_f32_16x16x32_bf16(af, bf, sacc[ct], 0, 0, 0);
      }
    }

    float sv[8][4];
#pragma unroll
    for (int ct = 0; ct < 8; ++ct)
#pragma unroll
      for (int r = 0; r < 4; ++r) {
        float v = sacc[ct][r] * 0.125f;
        if (CAUSAL) {
          int qq = q0 + wave * 16 + quad * 4 + r;
          int kk = kt * 128 + ct * 16 + l15;
          v = (kk <= qq) ? v + lrb[qq - kk] : -1e30f;
        }
        sv[ct][r] = v;
      }

    float mx[4];
#pragma unroll
    for (int r = 0; r < 4; ++r) {
      mx[r] = sv[0][r];
#pragma unroll
      for (int ct = 1; ct < 8; ++ct) mx[r] = fmaxf(mx[r], sv[ct][r]);
    }
#pragma unroll
    for (int o = 1; o < 16; o <<= 1)
#pragma unroll
      for (int r = 0; r < 4; ++r) mx[r] = fmaxf(mx[r], __shfl_xor(mx[r], o));

    float alpha[4], rs[4];
#pragma unroll
    for (int r = 0; r < 4; ++r) {
      float mn = fmaxf(m_run[r], mx[r]);
      alpha[r] = __expf(m_run[r] - mn);
      m_run[r] = mn;
      rs[r] = 0.f;
    }
#pragma unroll
    for (int ct = 0; ct < 8; ++ct)
#pragma unroll
      for (int r = 0; r < 4; ++r) {
        float p = __expf(sv[ct][r] - m_run[r]);
        sv[ct][r] = p;
        rs[r] += p;
      }
#pragma unroll
    for (int o = 1; o < 16; o <<= 1)
#pragma unroll
      for (int r = 0; r < 4; ++r) rs[r] += __shfl_xor(rs[r], o);
#pragma unroll
    for (int r = 0; r < 4; ++r) l_run[r] = l_run[r] * alpha[r] + rs[r];
#pragma unroll
    for (int ni = 0; ni < 4; ++ni)
#pragma unroll
      for (int r = 0; r < 4; ++r) oacc[ni][r] *= alpha[r];

    // P -> LDS [64 q][128 k] bf16
#pragma unroll
    for (int ct = 0; ct < 8; ++ct)
#pragma unroll
      for (int r = 0; r < 4; ++r)
        *(unsigned short*)(ldsP + (size_t)(wave * 16 + quad * 4 + r) * 256 + (ct * 16 + l15) * 2)
            = f2bf(sv[ct][r]);
    __syncthreads();

    // O += P Vt over 128 k (4 kk steps)
    const char* pBase = ldsP + (size_t)(wave * 16 + l15) * 256 + quad * 16;
#pragma unroll
    for (int kk = 0; kk < 4; ++kk) {
      bf16x8 pf = *(const bf16x8*)(pBase + kk * 64);
#pragma unroll
      for (int ni = 0; ni < 4; ++ni) {
        bf16x8 vf8 = *(const bf16x8*)(ldsV + (size_t)(ni * 16 + l15) * 256 + quad * 16 + kk * 64);
        oacc[ni] = __builtin_amdgcn_mfma_f32_16x16x32_bf16(pf, vf8, oacc[ni], 0, 0, 0);
      }
    }
  }

#pragma unroll
  for (int r = 0; r < 4; ++r) {
    int q = q0 + wave * 16 + quad * 4 + r;
    float inv = 1.0f / l_run[r];
    unsigned short* dst = ctxb + ((size_t)b * 512 + q) * 1024 + h * 64;
#pragma unroll
    for (int ni = 0; ni < 4; ++ni)
      dst[ni * 16 + l15] = f2bf(oacc[ni][r] * inv);
  }
}

// ---------------- prep kernel (weights + encoder cast + rel bias) ----------

// modes: 0 = [K][N]->[N][K]; 1/2 = wi0/wi1 interleave into 256-row groups:
// orow = (n>>7)*256 + (mode==2)*128 + (n&127).
struct PrepArgs {
  const float* src[11];
  unsigned short* dst[11];
  int K[11], N[11], mode[11];
  int tstart[12];
  const float* encoded;         // 2048x1024 fp32
  unsigned short* encbf;
  const float* table;           // [32][16]
  float* rb;                    // [16][512]
  int nwt, nf2bf;               // block-range boundaries
};
__global__ __launch_bounds__(256) void k_prep(PrepArgs a) {
  int bid = blockIdx.x;
  int t = threadIdx.x;
  if (bid < a.nwt) {
    int z = 0;
    while (z < 10 && bid >= a.tstart[z + 1]) ++z;
    int tile = bid - a.tstart[z];
    int N = a.N[z], K = a.K[z], mode = a.mode[z];
    int ntn = N >> 5;
    int tn = tile % ntn, tk = tile / ntn;
    __shared__ float tl[32][33];
    int tx = t & 31, ty = t >> 5;
    const float* src = a.src[z];
    unsigned short* dst = a.dst[z];
#pragma unroll
    for (int i = 0; i < 32; i += 8)
      tl[ty + i][tx] = src[(size_t)(tk * 32 + ty + i) * N + tn * 32 + tx];
    __syncthreads();
#pragma unroll
    for (int i = 0; i < 32; i += 8) {
      int n = tn * 32 + ty + i;
      int orow = (mode == 0) ? n : ((n >> 7) * 256 + ((mode == 2) ? 128 : 0) + (n & 127));
      dst[(size_t)orow * K + tk * 32 + tx] = f2bf(tl[tx][ty + i]);
    }
  } else if (bid < a.nwt + a.nf2bf) {
    int i = (bid - a.nwt) * 256 + t;
    float4 v = ((const float4*)a.encoded)[i];
    ushort4 o;
    o.x = f2bf(v.x); o.y = f2bf(v.y); o.z = f2bf(v.z); o.w = f2bf(v.w);
    ((ushort4*)a.encbf)[i] = o;
  } else {
    int i = (bid - a.nwt - a.nf2bf) * 256 + t;
    if (i < 16 * 512) {
      int h = i >> 9, d = i & 511;
      int bucket;
      if (d < 16) bucket = d;
      else {
        int lb = 16 + (int)(logf((float)d / 16.0f) / logf(8.0f) * 16.0f);
        bucket = lb < 31 ? lb : 31;
      }
      a.rb[i] = a.table[bucket * 16 + h];
    }
  }
}

// ---------------- small kernels ----------------

__global__ __launch_bounds__(256) void k_rmsnorm(const float* x, const float* sc, unsigned short* out) {
  int row = blockIdx.x, t = threadIdx.x;
  float4 v = ((const float4*)(x + (size_t)row * 1024))[t];
  float ss = v.x * v.x + v.y * v.y + v.z * v.z + v.w * v.w;
  for (int o = 32; o; o >>= 1) ss += __shfl_down(ss, o);
  __shared__ float red[4];
  if ((t & 63) == 0) red[t >> 6] = ss;
  __syncthreads();
  float tot = red[0] + red[1] + red[2] + red[3];
  float rs = rsqrtf(tot * (1.0f / 1024.0f) + 1e-6f);
  float4 s4 = ((const float4*)sc)[t];
  ushort4 o;
  o.x = f2bf(v.x * rs * s4.x); o.y = f2bf(v.y * rs * s4.y);
  o.z = f2bf(v.z * rs * s4.z); o.w = f2bf(v.w * rs * s4.w);
  ((ushort4*)(out + (size_t)row * 1024))[t] = o;
}

__global__ __launch_bounds__(256) void k_vtrans(const float* vf, unsigned short* vt) {
  int z = blockIdx.y, b = z >> 4, h = z & 15;
  int k0 = blockIdx.x * 64;
  __shared__ float tl[64][65];
  int t = threadIdx.x;
  int d = t & 63, kr = t >> 6;
#pragma unroll
  for (int i = 0; i < 64; i += 4)
    tl[kr + i][d] = vf[(size_t)(b * 512 + k0 + kr + i) * 1024 + h * 64 + d];
  __syncthreads();
  int dw = t >> 2, kc = (t & 3) * 16;
  unsigned short* dst = vt + ((size_t)z * 64 + dw) * 512 + k0 + kc;
#pragma unroll
  for (int j = 0; j < 16; ++j) dst[j] = f2bf(tl[kc + j][dw]);
}

struct Low3 {
  const unsigned short* x[3];
  const float* a[3];
  float* low[3];
};
__global__ __launch_bounds__(256) void k_lora_low(Low3 g) {
  int z = blockIdx.z;
  int row0 = blockIdx.x * 8;
  int b = row0 >> 9;
  int t = threadIdx.x, r = t & 31, j = t >> 5;
  const bf16x8* xv = (const bf16x8*)(g.x[z] + (size_t)(row0 + j) * 1024);
  const float* a = g.a[z] + ((size_t)b << 16);
  float s = 0.f;
  for (int kb = 0; kb < 128; ++kb) {
    bf16x8 v = xv[kb];
#pragma unroll
    for (int u = 0; u < 8; ++u)
      s += (float)v[u] * a[(size_t)(kb * 8 + u) * 32 + r];
  }
  g.low[z][(size_t)(row0 + j) * 32 + r] = s;
}

struct Addb3 {
  const float* low[3];
  const float* bm[3];
  const float* gin[3];
  float* gout[3];
  const float* resid[3];
  unsigned short* mirror[3];
  int ngin;
  size_t gstride;
};
__global__ __launch_bounds__(256) void k_lora_addb(Addb3 g) {
  int z = blockIdx.z;
  int row0 = blockIdx.x * 8;
  int b = row0 >> 9;
  const float* bm = g.bm[z] + ((size_t)b << 16);
  int t = threadIdx.x;
  __shared__ float lsh[8][32];
  lsh[t >> 5][t & 31] = g.low[z][(size_t)row0 * 32 + t];
  __syncthreads();
  float4 acc[8];
#pragma unroll
  for (int j = 0; j < 8; ++j) acc[j] = (float4){0.f, 0.f, 0.f, 0.f};
  for (int r = 0; r < 32; ++r) {
    float4 b4 = ((const float4*)(bm + (size_t)r * 1024))[t];
#pragma unroll
    for (int j = 0; j < 8; ++j) {
      float lv = lsh[j][r];
      acc[j].x += lv * b4.x; acc[j].y += lv * b4.y;
      acc[j].z += lv * b4.z; acc[j].w += lv * b4.w;
    }
  }
#pragma unroll
  for (int j = 0; j < 8; ++j) {
    size_t idx = (size_t)(row0 + j) * 256 + t;
    float4 s = acc[j];
    for (int p = 0; p < g.ngin; ++p) {
      float4 gv = ((const float4*)(g.gin[z] + (size_t)p * g.gstride))[idx];
      s.x += gv.x; s.y += gv.y; s.z += gv.z; s.w += gv.w;
    }
    if (g.resid[z]) {
      float4 rv = ((const float4*)g.resid[z])[idx];
      s.x += rv.x; s.y += rv.y; s.z += rv.z; s.w += rv.w;
    }
    if (g.gout[z]) ((float4*)g.gout[z])[idx] = s;
    if (g.mirror[z]) {
      ushort4 mo; mo.x = f2bf(s.x); mo.y = f2bf(s.y); mo.z = f2bf(s.z); mo.w = f2bf(s.w);
      ((ushort4*)g.mirror[z])[idx] = mo;
    }
  }
}

__global__ void k_sum4(const float* p, size_t pstride, const float* resid, float* out) {
  int i = blockIdx.x * 256 + threadIdx.x;
  float4 a = ((const float4*)p)[i];
  float4 b = ((const float4*)(p + pstride))[i];
  float4 c = ((const float4*)(p + 2 * pstride))[i];
  float4 d = ((const float4*)(p + 3 * pstride))[i];
  float4 r = ((const float4*)resid)[i];
  float4 o;
  o.x = a.x + b.x + c.x + d.x + r.x;
  o.y = a.y + b.y + c.y + d.y + r.y;
  o.z = a.z + b.z + c.z + d.z + r.z;
  o.w = a.w + b.w + c.w + d.w + r.w;
  ((float4*)out)[i] = o;
}

// ---------------------------------------------------------------------------

extern "C" void kernel_launch(void* const* d_in, const int* in_sizes, int n_in,
                              void* d_out, int out_size, void* d_ws, size_t ws_size,
                              hipStream_t stream) {
  const float* f_inputs  = (const float*)d_in[0];
  const float* f_encoded = (const float*)d_in[1];
  const float* f_qa = (const float*)d_in[2];
  const float* f_qb = (const float*)d_in[3];
  const float* f_ka = (const float*)d_in[4];
  const float* f_kb = (const float*)d_in[5];
  const float* f_va = (const float*)d_in[6];
  const float* f_vb = (const float*)d_in[7];
  const float* f_oa = (const float*)d_in[8];
  const float* f_ob = (const float*)d_in[9];
  const float* f_table = (const float*)d_in[10];
  const float* f_ln1 = (const float*)d_in[11];
  const float* f_ln2 = (const float*)d_in[12];
  const float* f_ln3 = (const float*)d_in[13];
  const float* f_W[8] = { (const float*)d_in[14], (const float*)d_in[15],
                          (const float*)d_in[16], (const float*)d_in[17],
                          (const float*)d_in[18], (const float*)d_in[19],
                          (const float*)d_in[20], (const float*)d_in[21] };
  const float* f_wi0 = (const float*)d_in[22];
  const float* f_wi1 = (const float*)d_in[23];
  const float* f_wo  = (const float*)d_in[24];

  const size_t SEL1 = 32768;               // sel stride in lora a/b arrays
  const size_t PART = (size_t)2048 * 1024; // [2048,1024] fp32 partial (elements)

  char* w = (char*)d_ws;
  size_t off = 0;
  auto alloc = [&](size_t bytes) -> char* {
    off = (off + 255) & ~(size_t)255;
    char* p = w + off;
    off += bytes;
    return p;
  };
  unsigned short* wt[8];
  for (int i = 0; i < 8; ++i) wt[i] = (unsigned short*)alloc(1024 * 1024 * 2);
  unsigned short* wc  = (unsigned short*)alloc((size_t)8192 * 1024 * 2);  // interleaved wi0/wi1
  unsigned short* wot = (unsigned short*)alloc(1024 * 4096 * 2);
  unsigned short* encbf = (unsigned short*)alloc(2048 * 1024 * 2);
  float* rb = (float*)alloc(16 * 512 * 4);
  unsigned short* xn = (unsigned short*)alloc(2048 * 1024 * 2);
  float* vf = (float*)alloc(2048 * 1024 * 4);
  unsigned short* qbf = (unsigned short*)alloc(2048 * 1024 * 2);
  unsigned short* kbf = (unsigned short*)alloc(2048 * 1024 * 2);
  unsigned short* vtb = (unsigned short*)alloc((size_t)64 * 64 * 512 * 2);
  float* low0 = (float*)alloc(2048 * 32 * 4);
  float* low1 = (float*)alloc(2048 * 32 * 4);
  float* low2 = (float*)alloc(2048 * 32 * 4);
  char*  big  = alloc((size_t)64 << 20);   // 64 MB multi-use scratch
  unsigned short* ctxb = (unsigned short*)alloc(2048 * 1024 * 2);
  float* xres = (float*)alloc(2048 * 1024 * 4);
  float* yres = (float*)alloc(2048 * 1024 * 4);
  // aliases in `big` (stream-serial lifetimes):
  float* qp = (float*)big;                   // QKV partials: 6*8 MB
  float* kp = qp + 2 * PART;
  float* vp = qp + 4 * PART;
  float* op = (float*)big;                   // out-proj partials: 4*8 MB
  unsigned short* hbf = (unsigned short*)big;              // 16 MB bf16 [2048][4096]
  float* fp = (float*)(big + ((size_t)16 << 20));          // 4*8 MB final partials
  (void)ws_size; (void)in_sizes; (void)n_in; (void)out_size;

  // ---- prep: weight convert/transpose + encoder cast + rel bias ----
  PrepArgs pa;
  int ts = 0;
  for (int i = 0; i < 8; ++i) {
    pa.src[i] = f_W[i]; pa.dst[i] = wt[i]; pa.K[i] = 1024; pa.N[i] = 1024;
    pa.mode[i] = 0; pa.tstart[i] = ts; ts += 32 * 32;
  }
  pa.src[8] = f_wi0; pa.dst[8] = wc; pa.K[8] = 1024; pa.N[8] = 4096; pa.mode[8] = 1;
  pa.tstart[8] = ts; ts += 32 * 128;
  pa.src[9] = f_wi1; pa.dst[9] = wc; pa.K[9] = 1024; pa.N[9] = 4096; pa.mode[9] = 2;
  pa.tstart[9] = ts; ts += 32 * 128;
  pa.src[10] = f_wo; pa.dst[10] = wot; pa.K[10] = 4096; pa.N[10] = 1024; pa.mode[10] = 0;
  pa.tstart[10] = ts; ts += 128 * 32;
  pa.tstart[11] = ts;
  pa.encoded = f_encoded; pa.encbf = encbf;
  pa.table = f_table; pa.rb = rb;
  pa.nwt = ts; pa.nf2bf = 2048;
  k_prep<<<dim3(ts + 2048 + 32), dim3(256), 0, stream>>>(pa);

  // ================= self-attention =================
  k_rmsnorm<<<dim3(2048), dim3(256), 0, stream>>>(f_inputs, f_ln1, xn);

  G3S g_qkv = { {xn, xn, xn}, {wt[0], wt[1], wt[2]}, {qp, kp, vp},
                1024, 1024, 1024, 1024, 2, 512, PART };
  k_gemm3s<<<dim3(8, 16, 6), dim3(256), 0, stream>>>(g_qkv);

  Low3 lo_s = { {xn, xn, xn}, {f_qa, f_ka, f_va}, {low0, low1, low2} };
  k_lora_low<<<dim3(256, 1, 3), dim3(256), 0, stream>>>(lo_s);
  Addb3 ab_s = { {low0, low1, low2}, {f_qb, f_kb, f_vb}, {qp, kp, vp},
                 {nullptr, nullptr, vf}, {nullptr, nullptr, nullptr},
                 {qbf, kbf, nullptr}, 2, PART };
  k_lora_addb<<<dim3(256, 1, 3), dim3(256), 0, stream>>>(ab_s);

  k_vtrans<<<dim3(8, 64), dim3(256), 0, stream>>>(vf, vtb);
  k_flash<true><<<dim3(8, 64), dim3(256), 0, stream>>>(qbf, kbf, vtb, rb, ctxb);

  k_gemm1s<<<dim3(8, 16, 4), dim3(256), 0, stream>>>(ctxb, wt[3], op, PART, 256, 1024, 1024, 1024);
  Low3 lo_o = { {ctxb, ctxb, ctxb}, {f_oa, f_oa, f_oa}, {low0, low0, low0} };
  k_lora_low<<<dim3(256, 1, 1), dim3(256), 0, stream>>>(lo_o);
  Addb3 ab_o = { {low0, low0, low0}, {f_ob, f_ob, f_ob}, {op, op, op},
                 {xres, xres, xres}, {f_inputs, f_inputs, f_inputs},
                 {nullptr, nullptr, nullptr}, 4, PART };
  k_lora_addb<<<dim3(256, 1, 1), dim3(256), 0, stream>>>(ab_o);

  // ================= cross-attention =================
  k_rmsnorm<<<dim3(2048), dim3(256), 0, stream>>>(xres, f_ln2, xn);

  G3S g_cqkv = { {xn, encbf, encbf}, {wt[4], wt[5], wt[6]}, {qp, kp, vp},
                 1024, 1024, 1024, 1024, 2, 512, PART };
  k_gemm3s<<<dim3(8, 16, 6), dim3(256), 0, stream>>>(g_cqkv);

  Low3 lo_c = { {xn, encbf, encbf}, {f_qa + SEL1, f_ka + SEL1, f_va + SEL1}, {low0, low1, low2} };
  k_lora_low<<<dim3(256, 1, 3), dim3(256), 0, stream>>>(lo_c);
  Addb3 ab_c = { {low0, low1, low2}, {f_qb + SEL1, f_kb + SEL1, f_vb + SEL1}, {qp, kp, vp},
                 {nullptr, nullptr, vf}, {nullptr, nullptr, nullptr},
                 {qbf, kbf, nullptr}, 2, PART };
  k_lora_addb<<<dim3(256, 1, 3), dim3(256), 0, stream>>>(ab_c);

  k_vtrans<<<dim3(8, 64), dim3(256), 0, stream>>>(vf, vtb);
  k_flash<false><<<dim3(8, 64), dim3(256), 0, stream>>>(qbf, kbf, vtb, rb, ctxb);

  k_gemm1s<<<dim3(8, 16, 4), dim3(256), 0, stream>>>(ctxb, wt[7], op, PART, 256, 1024, 1024, 1024);
  Low3 lo_co = { {ctxb, ctxb, ctxb}, {f_oa + SEL1, f_oa + SEL1, f_oa + SEL1}, {low0, low0, low0} };
  k_lora_low<<<dim3(256, 1, 1), dim3(256), 0, stream>>>(lo_co);
  Addb3 ab_co = { {low0, low0, low0}, {f_ob + SEL1, f_ob + SEL1, f_ob + SEL1}, {op, op, op},
                  {yres, yres, yres}, {xres, xres, xres},
                  {nullptr, nullptr, nullptr}, 4, PART };
  k_lora_addb<<<dim3(256, 1, 1), dim3(256), 0, stream>>>(ab_co);

  // ================= gated-gelu MLP =================
  k_rmsnorm<<<dim3(2048), dim3(256), 0, stream>>>(yres, f_ln3, xn);
  k_mlp<<<dim3(32, 16), dim3(512), 0, stream>>>(xn, wc, hbf);
  k_gemm1s<<<dim3(8, 16, 4), dim3(256), 0, stream>>>(hbf, wot, fp, PART, 1024, 4096, 4096, 1024);
  k_sum4<<<dim3(2048), dim3(256), 0, stream>>>(fp, PART, yres, (float*)d_out);
}

// Round 7
// 652.482 us; speedup vs baseline: 1.2571x; 1.0018x over previous
//
#include <hip/hip_runtime.h>
#include <math.h>

// ---------------------------------------------------------------------------
// LoRA T5 decoder layer on MI355X (gfx950).
// B=4, L=ENC=512, D=1024, H=16, HD=64, MLP=4096, R=32.
// R6->R7: fix bmext column indexing (b-matrix source col must be the
// within-section global output column (n0&1023)+n, not the local row n).
// Structure unchanged from R6: LoRA folded into GEMMs via K-extension,
// single big QKV+crossKV dispatch, fused epilogue chains.
// ---------------------------------------------------------------------------

#define DEV __device__ __forceinline__

typedef __bf16 bf16x8 __attribute__((ext_vector_type(8)));
typedef float floatx4 __attribute__((ext_vector_type(4)));

typedef __attribute__((address_space(1))) void* gas_ptr;
typedef __attribute__((address_space(3))) void* las_ptr;

DEV unsigned short f2bf(float f) {
  union { float f; unsigned int u; } v; v.f = f;
  unsigned int r = v.u + 0x7fffu + ((v.u >> 16) & 1u);
  return (unsigned short)(r >> 16);
}
DEV float bf2f(unsigned short u) {
  union { unsigned int u; float f; } v; v.u = ((unsigned int)u) << 16;
  return v.f;
}

#define GLOAD_LDS16(g, l) __builtin_amdgcn_global_load_lds((gas_ptr)(g), (las_ptr)(l), 16, 0, 0)

// Stage nrows x 64 bf16 (128 B rows) from global (row stride ldbytes) into LDS.
template<int NW>
DEV void stage_tile(const char* gbase, char* lds, int nrows, int ldbytes, int wave, int lane) {
  int nchunks = nrows >> 3;
  for (int c = wave; c < nchunks; c += NW) {
    int row  = (c << 3) + (lane >> 3);
    int colb = (lane & 7) << 4;
    GLOAD_LDS16(gbase + (size_t)row * ldbytes + colb, lds + (c << 10));
  }
}

// Stage nrows x 128 bf16 (256 B rows) from global (row stride ldbytes) into LDS.
template<int NW>
DEV void stage_tile256(const char* gbase, char* lds, int nrows, int ldbytes, int wave, int lane) {
  int nchunks = nrows >> 2;
  for (int c = wave; c < nchunks; c += NW) {
    int row  = (c << 2) + (lane >> 4);
    int colb = (lane & 15) << 4;
    GLOAD_LDS16(gbase + (size_t)row * ldbytes + colb, lds + (c << 10));
  }
}

// ---------------- generic bf16 GEMM core (fp32 out), 128x128 tile ----------
template<int WM, int WN>
DEV void gemm_core(const unsigned short* A, const unsigned short* Bt, float* C,
                   int K, int lda, int ldb, int ldc, int m0, int n0,
                   char* ldsA, char* ldsB) {
  constexpr int NW = WM * WN;
  const int tid  = threadIdx.x;
  const int lane = tid & 63;
  const int wave = tid >> 6;
  const int wm   = wave % WM;
  const int wn   = wave / WM;
  const int quad = lane >> 4;
  const int l15  = lane & 15;

  floatx4 acc[4][4];
#pragma unroll
  for (int i = 0; i < 4; ++i)
#pragma unroll
    for (int j = 0; j < 4; ++j) acc[i][j] = (floatx4){0.f, 0.f, 0.f, 0.f};

  const char* gA = (const char*)(A + (size_t)m0 * lda);
  const char* gB = (const char*)(Bt + (size_t)n0 * ldb);

  for (int k0 = 0; k0 < K; k0 += 64) {
    stage_tile<NW>(gA + (size_t)k0 * 2, ldsA, WM * 64, lda * 2, wave, lane);
    stage_tile<NW>(gB + (size_t)k0 * 2, ldsB, WN * 64, ldb * 2, wave, lane);
    __syncthreads();
#pragma unroll
    for (int kk = 0; kk < 64; kk += 32) {
      bf16x8 af[4], bv[4];
      const char* baseA = ldsA + (size_t)(wm * 64 + l15) * 128 + (kk + quad * 8) * 2;
      const char* baseB = ldsB + (size_t)(wn * 64 + l15) * 128 + (kk + quad * 8) * 2;
#pragma unroll
      for (int mi = 0; mi < 4; ++mi) af[mi] = *(const bf16x8*)(baseA + mi * 2048);
#pragma unroll
      for (int ni = 0; ni < 4; ++ni) bv[ni] = *(const bf16x8*)(baseB + ni * 2048);
#pragma unroll
      for (int mi = 0; mi < 4; ++mi)
#pragma unroll
        for (int ni = 0; ni < 4; ++ni)
          acc[mi][ni] = __builtin_amdgcn_mfma_f32_16x16x32_bf16(af[mi], bv[ni], acc[mi][ni], 0, 0, 0);
    }
    __syncthreads();
  }

#pragma unroll
  for (int mi = 0; mi < 4; ++mi) {
#pragma unroll
    for (int r = 0; r < 4; ++r) {
      int row = m0 + wm * 64 + mi * 16 + quad * 4 + r;
#pragma unroll
      for (int ni = 0; ni < 4; ++ni) {
        int col = n0 + wn * 64 + ni * 16 + l15;
        C[(size_t)row * ldc + col] = acc[mi][ni][r];
      }
    }
  }
}

__global__ __launch_bounds__(256) void k_gemm1s(const unsigned short* A, const unsigned short* Bt,
                                                float* Cpart, size_t pstride,
                                                int Kchunk, int lda, int ldb, int ldc) {
  __shared__ char lds[32768];
  int s = blockIdx.z;
  size_t koff = (size_t)s * Kchunk;
  gemm_core<2, 2>(A + koff, Bt + koff, Cpart + (size_t)s * pstride,
                  Kchunk, lda, ldb, ldc,
                  blockIdx.y * 128, blockIdx.x * 128, lds, lds + 16384);
}

// ---------------- K-extended GEMM: C = [A0|Aext] @ [B0|Bext(b)]^T ----------
// A0 [2048][1024] bf16, Aext [2048][128] bf16; B0 [N][1024]; Bext [4][N][128].
// 18 total k-iters (16 W + 2 ext); slice covers iters [it0, it1).
struct GXSlice {
  const unsigned short* A0;
  const unsigned short* Aext;
  const unsigned short* B0;
  const unsigned short* Bext;
  float* C;
  size_t bextb;            // per-b element stride of Bext (= N*128)
  int ldc, nxa, it0, it1;
};
struct GX { GXSlice s[4]; };

__global__ __launch_bounds__(256) void k_gemmx(GX g) {
  __shared__ char lds[32768];
  char* ldsA = lds;
  char* ldsB = lds + 16384;
  GXSlice sl = g.s[blockIdx.z];
  if ((int)blockIdx.x >= sl.nxa) return;
  const int m0 = blockIdx.y * 128, n0 = blockIdx.x * 128;
  const int b = m0 >> 9;
  const int tid = threadIdx.x, lane = tid & 63, wave = tid >> 6;
  const int wm = wave & 1, wn = wave >> 1;
  const int quad = lane >> 4, l15 = lane & 15;

  floatx4 acc[4][4];
#pragma unroll
  for (int i = 0; i < 4; ++i)
#pragma unroll
    for (int j = 0; j < 4; ++j) acc[i][j] = (floatx4){0.f, 0.f, 0.f, 0.f};

  for (int it = sl.it0; it < sl.it1; ++it) {
    if (it < 16) {
      stage_tile<4>((const char*)sl.A0 + (size_t)m0 * 2048 + it * 128, ldsA, 128, 2048, wave, lane);
      stage_tile<4>((const char*)sl.B0 + (size_t)n0 * 2048 + it * 128, ldsB, 128, 2048, wave, lane);
    } else {
      int eb = (it - 16) * 128;   // byte offset into the 256 B ext rows
      stage_tile<4>((const char*)sl.Aext + (size_t)m0 * 256 + eb, ldsA, 128, 256, wave, lane);
      stage_tile<4>((const char*)(sl.Bext + (size_t)b * sl.bextb) + (size_t)n0 * 256 + eb,
                    ldsB, 128, 256, wave, lane);
    }
    __syncthreads();
#pragma unroll
    for (int kk = 0; kk < 64; kk += 32) {
      bf16x8 af[4], bv[4];
      const char* baseA = ldsA + (size_t)(wm * 64 + l15) * 128 + (kk + quad * 8) * 2;
      const char* baseB = ldsB + (size_t)(wn * 64 + l15) * 128 + (kk + quad * 8) * 2;
#pragma unroll
      for (int mi = 0; mi < 4; ++mi) af[mi] = *(const bf16x8*)(baseA + mi * 2048);
#pragma unroll
      for (int ni = 0; ni < 4; ++ni) bv[ni] = *(const bf16x8*)(baseB + ni * 2048);
#pragma unroll
      for (int mi = 0; mi < 4; ++mi)
#pragma unroll
        for (int ni = 0; ni < 4; ++ni)
          acc[mi][ni] = __builtin_amdgcn_mfma_f32_16x16x32_bf16(af[mi], bv[ni], acc[mi][ni], 0, 0, 0);
    }
    __syncthreads();
  }

#pragma unroll
  for (int mi = 0; mi < 4; ++mi) {
#pragma unroll
    for (int r = 0; r < 4; ++r) {
      int row = m0 + wm * 64 + mi * 16 + quad * 4 + r;
#pragma unroll
      for (int ni = 0; ni < 4; ++ni) {
        int col = n0 + wn * 64 + ni * 16 + l15;
        sl.C[(size_t)row * sl.ldc + col] = acc[mi][ni][r];
      }
    }
  }
}

// ---------------- QKV sum: splitK(2) sum + bf16 cast + V transpose --------
// z=0: self [2048][3072] -> qbf,kbf flat; v -> vtb [z64][d][k] scatter.
// z=1: cross [2048][2048] -> kbf2 flat; v -> vtb2 scatter.
__global__ __launch_bounds__(256) void k_qkvsum(const float* bqs, const float* bqc,
                                                unsigned short* qbf, unsigned short* kbf,
                                                unsigned short* vtb, unsigned short* kbf2,
                                                unsigned short* vtb2) {
  const size_t PS = (size_t)2048 * 3072, PC = (size_t)2048 * 2048;
  int t = threadIdx.x;
  int row0 = blockIdx.x * 8;
  int zc = blockIdx.y;
  for (int j = 0; j < 8; ++j) {
    int row = row0 + j;
    int b = row >> 9, kpos = row & 511;
    int nsec = zc ? 2 : 3;
    for (int sec = 0; sec < nsec; ++sec) {
      const float* base = zc ? (bqc + (size_t)row * 2048 + sec * 1024)
                             : (bqs + (size_t)row * 3072 + sec * 1024);
      float4 a = ((const float4*)base)[t];
      float4 c = ((const float4*)(base + (zc ? PC : PS)))[t];
      float4 s; s.x = a.x + c.x; s.y = a.y + c.y; s.z = a.z + c.z; s.w = a.w + c.w;
      ushort4 o; o.x = f2bf(s.x); o.y = f2bf(s.y); o.z = f2bf(s.z); o.w = f2bf(s.w);
      int vsec = zc ? (sec == 1) : (sec == 2);
      if (!vsec) {
        unsigned short* dst = zc ? kbf2 : (sec == 0 ? qbf : kbf);
        ((ushort4*)(dst + (size_t)row * 1024))[t] = o;
      } else {
        unsigned short* dst = zc ? vtb2 : vtb;
        int h = t >> 4, dbase = (t & 15) * 4;
        size_t base2 = ((size_t)(b * 16 + h) * 64 + dbase) * 512 + kpos;
        dst[base2] = o.x; dst[base2 + 512] = o.y;
        dst[base2 + 1024] = o.z; dst[base2 + 1536] = o.w;
      }
    }
  }
}

// ---------------- flash attention ----------------
template<bool CAUSAL, bool QSUM>
__global__ __launch_bounds__(256) void k_flash(const unsigned short* qmat, const float* qparts,
                                               const unsigned short* kmat, const unsigned short* vt,
                                               const float* rb, unsigned short* ctxb) {
  __shared__ char ldsQ[8192];    // [64 q][64 d]
  __shared__ char ldsK[16384];   // [128 k][64 d]
  __shared__ char ldsV[16384];   // [64 d][128 k]
  __shared__ char ldsP[16384];   // [64 q][128 k]
  __shared__ float lrb[512];

  const size_t PART = (size_t)2048 * 1024;
  const int z = blockIdx.y, b = z >> 4, h = z & 15;
  const int q0 = blockIdx.x * 64;
  const int tid = threadIdx.x, lane = tid & 63, wave = tid >> 6;
  const int quad = lane >> 4, l15 = lane & 15;

  const unsigned short* K = kmat + (size_t)b * 512 * 1024 + h * 64;
  const unsigned short* V = vt + (size_t)z * 64 * 512;

  if (QSUM) {
    // Q tile from 4 fp32 split-K partials
#pragma unroll
    for (int rr = 0; rr < 4; ++rr) {
      int row = rr * 16 + (tid >> 4);
      int c4 = tid & 15;
      const float* src = qparts + (size_t)(q0 + row) * 1024 + h * 64 + c4 * 4;
      float4 s0 = *(const float4*)src;
      float4 s1 = *(const float4*)(src + PART);
      float4 s2 = *(const float4*)(src + 2 * PART);
      float4 s3 = *(const float4*)(src + 3 * PART);
      ushort4 o;
      o.x = f2bf(s0.x + s1.x + s2.x + s3.x);
      o.y = f2bf(s0.y + s1.y + s2.y + s3.y);
      o.z = f2bf(s0.z + s1.z + s2.z + s3.z);
      o.w = f2bf(s0.w + s1.w + s2.w + s3.w);
      *(ushort4*)(ldsQ + (size_t)row * 128 + c4 * 8) = o;
    }
  } else {
    const unsigned short* Q = qmat + (size_t)b * 512 * 1024 + h * 64;
    stage_tile<4>((const char*)(Q + (size_t)q0 * 1024), ldsQ, 64, 2048, wave, lane);
  }
  if (CAUSAL)
    for (int i = tid; i < 512; i += 256) lrb[i] = rb[h * 512 + i];

  float m_run[4], l_run[4];
  floatx4 oacc[4];
#pragma unroll
  for (int r = 0; r < 4; ++r) { m_run[r] = -1e30f; l_run[r] = 0.f; }
#pragma unroll
  for (int ni = 0; ni < 4; ++ni) oacc[ni] = (floatx4){0.f, 0.f, 0.f, 0.f};

  const int ktend = CAUSAL ? (blockIdx.x / 2 + 1) : 4;
  for (int kt = 0; kt < ktend; ++kt) {
    __syncthreads();
    stage_tile<4>((const char*)(K + (size_t)kt * 128 * 1024), ldsK, 128, 2048, wave, lane);
    stage_tile256<4>((const char*)(V + kt * 128), ldsV, 64, 1024, wave, lane);
    __syncthreads();

    floatx4 sacc[8];
#pragma unroll
    for (int ct = 0; ct < 8; ++ct) sacc[ct] = (floatx4){0.f, 0.f, 0.f, 0.f};
    const char* aBase = ldsQ + (size_t)(wave * 16 + l15) * 128 + quad * 16;
#pragma unroll
    for (int kd = 0; kd < 2; ++kd) {
      bf16x8 af = *(const bf16x8*)(aBase + kd * 64);
#pragma unroll
      for (int ct = 0; ct < 8; ++ct) {
        bf16x8 bf = *(const bf16x8*)(ldsK + (size_t)(ct * 16 + l15) * 128 + quad * 16 + kd * 64);
        sacc[ct] = __builtin_amdgcn_mfma_f32_16x16x32_bf16(af, bf, sacc[ct], 0, 0, 0);
      }
    }

    float sv[8][4];
#pragma unroll
    for (int ct = 0; ct < 8; ++ct)
#pragma unroll
      for (int r = 0; r < 4; ++r) {
        float v = sacc[ct][r] * 0.125f;
        if (CAUSAL) {
          int qq = q0 + wave * 16 + quad * 4 + r;
          int kk = kt * 128 + ct * 16 + l15;
          v = (kk <= qq) ? v + lrb[qq - kk] : -1e30f;
        }
        sv[ct][r] = v;
      }

    float mx[4];
#pragma unroll
    for (int r = 0; r < 4; ++r) {
      mx[r] = sv[0][r];
#pragma unroll
      for (int ct = 1; ct < 8; ++ct) mx[r] = fmaxf(mx[r], sv[ct][r]);
    }
#pragma unroll
    for (int o = 1; o < 16; o <<= 1)
#pragma unroll
      for (int r = 0; r < 4; ++r) mx[r] = fmaxf(mx[r], __shfl_xor(mx[r], o));

    float alpha[4], rs[4];
#pragma unroll
    for (int r = 0; r < 4; ++r) {
      float mn = fmaxf(m_run[r], mx[r]);
      alpha[r] = __expf(m_run[r] - mn);
      m_run[r] = mn;
      rs[r] = 0.f;
    }
#pragma unroll
    for (int ct = 0; ct < 8; ++ct)
#pragma unroll
      for (int r = 0; r < 4; ++r) {
        float p = __expf(sv[ct][r] - m_run[r]);
        sv[ct][r] = p;
        rs[r] += p;
      }
#pragma unroll
    for (int o = 1; o < 16; o <<= 1)
#pragma unroll
      for (int r = 0; r < 4; ++r) rs[r] += __shfl_xor(rs[r], o);
#pragma unroll
    for (int r = 0; r < 4; ++r) l_run[r] = l_run[r] * alpha[r] + rs[r];
#pragma unroll
    for (int ni = 0; ni < 4; ++ni)
#pragma unroll
      for (int r = 0; r < 4; ++r) oacc[ni][r] *= alpha[r];

#pragma unroll
    for (int ct = 0; ct < 8; ++ct)
#pragma unroll
      for (int r = 0; r < 4; ++r)
        *(unsigned short*)(ldsP + (size_t)(wave * 16 + quad * 4 + r) * 256 + (ct * 16 + l15) * 2)
            = f2bf(sv[ct][r]);
    __syncthreads();

    const char* pBase = ldsP + (size_t)(wave * 16 + l15) * 256 + quad * 16;
#pragma unroll
    for (int kk = 0; kk < 4; ++kk) {
      bf16x8 pf = *(const bf16x8*)(pBase + kk * 64);
#pragma unroll
      for (int ni = 0; ni < 4; ++ni) {
        bf16x8 vf8 = *(const bf16x8*)(ldsV + (size_t)(ni * 16 + l15) * 256 + quad * 16 + kk * 64);
        oacc[ni] = __builtin_amdgcn_mfma_f32_16x16x32_bf16(pf, vf8, oacc[ni], 0, 0, 0);
      }
    }
  }

#pragma unroll
  for (int r = 0; r < 4; ++r) {
    int q = q0 + wave * 16 + quad * 4 + r;
    float inv = 1.0f / l_run[r];
    unsigned short* dst = ctxb + ((size_t)b * 512 + q) * 1024 + h * 64;
#pragma unroll
    for (int ni = 0; ni < 4; ++ni)
      dst[ni * 16 + l15] = f2bf(oacc[ni][r] * inv);
  }
}

// ---------------- fused MLP ----------------
__global__ __launch_bounds__(512) void k_mlp(const unsigned short* A, const unsigned short* Wc,
                                             unsigned short* hbf) {
  __shared__ char lds[49152];
  char* ldsA = lds;
  char* ldsB = lds + 16384;
  const int m0 = blockIdx.y * 128;
  const int n0 = blockIdx.x * 128;
  const int tid = threadIdx.x, lane = tid & 63, wave = tid >> 6;
  const int half = wave >> 2, wl = wave & 3;
  const int wm = wl & 1, wn = wl >> 1;
  const int quad = lane >> 4, l15 = lane & 15;

  floatx4 acc[4][4];
#pragma unroll
  for (int i = 0; i < 4; ++i)
#pragma unroll
    for (int j = 0; j < 4; ++j) acc[i][j] = (floatx4){0.f, 0.f, 0.f, 0.f};

  const char* gA = (const char*)(A + (size_t)m0 * 1024);
  const char* gB = (const char*)(Wc + (size_t)blockIdx.x * 256 * 1024);

  for (int k0 = 0; k0 < 1024; k0 += 64) {
    stage_tile<8>(gA + (size_t)k0 * 2, ldsA, 128, 2048, wave, lane);
    stage_tile<8>(gB + (size_t)k0 * 2, ldsB, 256, 2048, wave, lane);
    __syncthreads();
#pragma unroll
    for (int kk = 0; kk < 64; kk += 32) {
      bf16x8 af[4], bv[4];
      const char* baseA = ldsA + (size_t)(wm * 64 + l15) * 128 + (kk + quad * 8) * 2;
      const char* baseB = ldsB + (size_t)(half * 128 + wn * 64 + l15) * 128 + (kk + quad * 8) * 2;
#pragma unroll
      for (int mi = 0; mi < 4; ++mi) af[mi] = *(const bf16x8*)(baseA + mi * 2048);
#pragma unroll
      for (int ni = 0; ni < 4; ++ni) bv[ni] = *(const bf16x8*)(baseB + ni * 2048);
#pragma unroll
      for (int mi = 0; mi < 4; ++mi)
#pragma unroll
        for (int ni = 0; ni < 4; ++ni)
          acc[mi][ni] = __builtin_amdgcn_mfma_f32_16x16x32_bf16(af[mi], bv[ni], acc[mi][ni], 0, 0, 0);
    }
    __syncthreads();
  }

  if (half == 1) {
#pragma unroll
    for (int mi = 0; mi < 4; ++mi)
#pragma unroll
      for (int r = 0; r < 4; ++r) {
        int row = wm * 64 + mi * 16 + quad * 4 + r;
#pragma unroll
        for (int ni = 0; ni < 4; ++ni) {
          int col = wn * 64 + ni * 16 + l15;
          *(unsigned short*)(ldsB + (size_t)row * 256 + col * 2) = f2bf(acc[mi][ni][r]);
        }
      }
  }
  __syncthreads();
  if (half == 0) {
#pragma unroll
    for (int mi = 0; mi < 4; ++mi)
#pragma unroll
      for (int r = 0; r < 4; ++r) {
        int row = wm * 64 + mi * 16 + quad * 4 + r;
#pragma unroll
        for (int ni = 0; ni < 4; ++ni) {
          int col = wn * 64 + ni * 16 + l15;
          float h1 = bf2f(*(const unsigned short*)(ldsB + (size_t)row * 256 + col * 2));
          float g = acc[mi][ni][r];
          float v = 0.5f * g * (1.0f + erff(g * 0.70710678f)) * h1;
          hbf[(size_t)(m0 + row) * 4096 + n0 + col] = f2bf(v);
        }
      }
  }
}

// ---------------- prep: weights + encbf + relbias + bmext + cross-kv lows --
struct PrepArgs {
  const float* src[11];
  unsigned short* dst[11];
  int K[11], N[11], mode[11];
  int tstart[12];
  const float* encoded;
  unsigned short* encbf;
  const float* table;
  float* rb;
  // bmext: 5 matrices
  unsigned short* bmdst[5];
  const float* bmsrc[5][3];
  int bmnrg[5];
  int bmstart[6];      // cumulative block starts (x4 batches)
  const float* lca[2]; // ka_sel1, va_sel1 bases (elements)
  unsigned short* lowc;
  int nwt, nf2bf, nbm;
};
__global__ __launch_bounds__(256) void k_prep(PrepArgs a) {
  __shared__ char shm[49152];
  int bid = blockIdx.x;
  int t = threadIdx.x;
  if (bid < a.nwt) {
    // fp32 [K][N] -> bf16 [N][K] (mode1/2: wi interleave in 256-row groups)
    int z = 0;
    while (z < 10 && bid >= a.tstart[z + 1]) ++z;
    int tile = bid - a.tstart[z];
    int N = a.N[z], K = a.K[z], mode = a.mode[z];
    int ntn = N >> 5;
    int tn = tile % ntn, tk = tile / ntn;
    float (*tl)[33] = (float(*)[33])shm;
    int tx = t & 31, ty = t >> 5;
    const float* src = a.src[z];
    unsigned short* dst = a.dst[z];
#pragma unroll
    for (int i = 0; i < 32; i += 8)
      tl[ty + i][tx] = src[(size_t)(tk * 32 + ty + i) * N + tn * 32 + tx];
    __syncthreads();
#pragma unroll
    for (int i = 0; i < 32; i += 8) {
      int n = tn * 32 + ty + i;
      int orow = (mode == 0) ? n : ((n >> 7) * 256 + ((mode == 2) ? 128 : 0) + (n & 127));
      dst[(size_t)orow * K + tk * 32 + tx] = f2bf(tl[tx][ty + i]);
    }
    return;
  }
  bid -= a.nwt;
  if (bid < a.nf2bf) {
    int i = bid * 256 + t;
    float4 v = ((const float4*)a.encoded)[i];
    ushort4 o;
    o.x = f2bf(v.x); o.y = f2bf(v.y); o.z = f2bf(v.z); o.w = f2bf(v.w);
    ((ushort4*)a.encbf)[i] = o;
    return;
  }
  bid -= a.nf2bf;
  if (bid < 32) {
    int i = bid * 256 + t;
    if (i < 16 * 512) {
      int h = i >> 9, d = i & 511;
      int bucket;
      if (d < 16) bucket = d;
      else {
        int lb = 16 + (int)(logf((float)d / 16.0f) / logf(8.0f) * 16.0f);
        bucket = lb < 31 ? lb : 31;
      }
      a.rb[i] = a.table[bucket * 16 + h];
    }
    return;
  }
  bid -= 32;
  if (bid < a.nbm) {
    // bmext fill: matrix m, batch b, rowgroup rg of 128 rows x 128 cols.
    // Bext[b][row=n0+n][c] = (c>>5==sec) ? b_sec[b][c&31][(n0&1023)+n] : 0
    int m = 0;
    while (m < 4 && bid >= a.bmstart[m + 1]) ++m;
    int idx = bid - a.bmstart[m];
    int nrg = a.bmnrg[m];
    int b = idx / nrg, rg = idx % nrg;
    int n0 = rg * 128;
    int sec = n0 >> 10;
    const float* src = a.bmsrc[m][sec] + (size_t)b * 65536;
    unsigned short* dst = a.bmdst[m] + ((size_t)b * nrg * 128 + n0) * 128;
    int n = t & 127, coff = (t >> 7) * 64;
    int ncol = (n0 & 1023) + n;          // FIX: within-section global output col
    unsigned short* drow = dst + (size_t)n * 128 + coff;
    for (int c4 = 0; c4 < 16; ++c4) {
      ushort4 o;
#pragma unroll
      for (int e = 0; e < 4; ++e) {
        int c = coff + c4 * 4 + e;
        float v = ((c >> 5) == sec) ? src[(size_t)(c & 31) * 1024 + ncol] : 0.f;
        ((unsigned short*)&o)[e] = f2bf(v);
      }
      *(ushort4*)(drow + c4 * 4) = o;
    }
    return;
  }
  bid -= a.nbm;
  {
    // cross-KV lows from fp32 encoded: 8 rows/block
    int row0 = bid * 8;
    int b = row0 >> 9;
    float* rowsF = (float*)shm;                       // [8][1024] = 32 KB
    float* pacc = (float*)(shm + 32768);              // [2][8][8][32] = 16 KB
    for (int j = 0; j < 8; ++j)
      ((float4*)(rowsF + j * 1024))[t] = ((const float4*)(a.encoded + (size_t)(row0 + j) * 1024))[t];
    __syncthreads();
    int r = t & 31, g = t >> 5;
    float acc[2][8];
#pragma unroll
    for (int p = 0; p < 2; ++p)
#pragma unroll
      for (int j = 0; j < 8; ++j) acc[p][j] = 0.f;
    const float* a0 = a.lca[0] + (size_t)b * 65536;
    const float* a1 = a.lca[1] + (size_t)b * 65536;
    for (int i = 0; i < 128; ++i) {
      int k = g * 128 + i;
      float ak = a0[(size_t)k * 32 + r];
      float av = a1[(size_t)k * 32 + r];
#pragma unroll
      for (int j = 0; j < 8; ++j) {
        float x = rowsF[j * 1024 + k];
        acc[0][j] += x * ak;
        acc[1][j] += x * av;
      }
    }
#pragma unroll
    for (int p = 0; p < 2; ++p)
#pragma unroll
      for (int j = 0; j < 8; ++j)
        pacc[((p * 8 + j) * 8 + g) * 32 + r] = acc[p][j];
    __syncthreads();
    for (int j = 0; j < 8; ++j) {
      if (t < 64) {
        int p = t >> 5, r2 = t & 31;
        float s = 0.f;
        for (int gg = 0; gg < 8; ++gg) s += pacc[((p * 8 + j) * 8 + gg) * 32 + r2];
        a.lowc[(size_t)(row0 + j) * 128 + p * 32 + r2] = f2bf(s);
      } else if (t < 128) {
        a.lowc[(size_t)(row0 + j) * 128 + t] = 0;
      }
    }
  }
}

// ---------------- k_start: rmsnorm + self q/k/v lows ----------------------
__global__ __launch_bounds__(256) void k_start(const float* x, const float* sc,
                                               const float* qa, const float* ka, const float* va,
                                               unsigned short* xn, unsigned short* lowext) {
  __shared__ unsigned short lrows[8][1024];   // 16 KB
  __shared__ float pacc[3 * 8 * 8 * 32];      // 24 KB
  __shared__ float red[4];
  int t = threadIdx.x;
  int row0 = blockIdx.x * 8;
  int b = row0 >> 9;
  float4 s4 = ((const float4*)sc)[t];
  for (int j = 0; j < 8; ++j) {
    int row = row0 + j;
    float4 v = ((const float4*)(x + (size_t)row * 1024))[t];
    float ss = v.x * v.x + v.y * v.y + v.z * v.z + v.w * v.w;
    for (int o = 32; o; o >>= 1) ss += __shfl_down(ss, o);
    if ((t & 63) == 0) red[t >> 6] = ss;
    __syncthreads();
    float tot = red[0] + red[1] + red[2] + red[3];
    float rs = rsqrtf(tot * (1.0f / 1024.0f) + 1e-6f);
    ushort4 o;
    o.x = f2bf(v.x * rs * s4.x); o.y = f2bf(v.y * rs * s4.y);
    o.z = f2bf(v.z * rs * s4.z); o.w = f2bf(v.w * rs * s4.w);
    ((ushort4*)(xn + (size_t)row * 1024))[t] = o;
    *(ushort4*)(&lrows[j][t * 4]) = o;
    __syncthreads();
  }
  int r = t & 31, g = t >> 5;
  float acc[3][8];
#pragma unroll
  for (int p = 0; p < 3; ++p)
#pragma unroll
    for (int j = 0; j < 8; ++j) acc[p][j] = 0.f;
  const float* aq = qa + (size_t)b * 65536;
  const float* ak = ka + (size_t)b * 65536;
  const float* av = va + (size_t)b * 65536;
  for (int i = 0; i < 128; ++i) {
    int k = g * 128 + i;
    float a0 = aq[(size_t)k * 32 + r];
    float a1 = ak[(size_t)k * 32 + r];
    float a2 = av[(size_t)k * 32 + r];
#pragma unroll
    for (int j = 0; j < 8; ++j) {
      float xv = bf2f(lrows[j][k]);
      acc[0][j] += xv * a0;
      acc[1][j] += xv * a1;
      acc[2][j] += xv * a2;
    }
  }
#pragma unroll
  for (int p = 0; p < 3; ++p)
#pragma unroll
    for (int j = 0; j < 8; ++j)
      pacc[((p * 8 + j) * 8 + g) * 32 + r] = acc[p][j];
  __syncthreads();
  for (int j = 0; j < 8; ++j) {
    if (t < 96) {
      int p = t >> 5, r2 = t & 31;
      float s = 0.f;
      for (int gg = 0; gg < 8; ++gg) s += pacc[((p * 8 + j) * 8 + gg) * 32 + r2];
      lowext[(size_t)(row0 + j) * 128 + p * 32 + r2] = f2bf(s);
    } else if (t < 128) {
      lowext[(size_t)(row0 + j) * 128 + t] = 0;
    }
  }
}

// ---------------- k_addbrms: 4-partial sum + resid + rms (+ next low) -----
template<bool LOW>
__global__ __launch_bounds__(256) void k_addbrms(const float* parts, const float* resid,
                                                 const float* sc, float* resout,
                                                 unsigned short* xn,
                                                 const float* aP, unsigned short* lowext) {
  __shared__ unsigned short lrows[8][1024];
  __shared__ float pacc[8 * 8 * 32];
  __shared__ float red[4];
  const size_t PART = (size_t)2048 * 1024;
  int t = threadIdx.x;
  int row0 = blockIdx.x * 8;
  int b = row0 >> 9;
  float4 s4 = ((const float4*)sc)[t];
  for (int j = 0; j < 8; ++j) {
    int row = row0 + j;
    const float* p0 = parts + (size_t)row * 1024;
    float4 v = ((const float4*)p0)[t];
    float4 v1 = ((const float4*)(p0 + PART))[t];
    float4 v2 = ((const float4*)(p0 + 2 * PART))[t];
    float4 v3 = ((const float4*)(p0 + 3 * PART))[t];
    float4 rv = ((const float4*)(resid + (size_t)row * 1024))[t];
    float4 s;
    s.x = v.x + v1.x + v2.x + v3.x + rv.x;
    s.y = v.y + v1.y + v2.y + v3.y + rv.y;
    s.z = v.z + v1.z + v2.z + v3.z + rv.z;
    s.w = v.w + v1.w + v2.w + v3.w + rv.w;
    ((float4*)(resout + (size_t)row * 1024))[t] = s;
    float ss = s.x * s.x + s.y * s.y + s.z * s.z + s.w * s.w;
    for (int o = 32; o; o >>= 1) ss += __shfl_down(ss, o);
    if ((t & 63) == 0) red[t >> 6] = ss;
    __syncthreads();
    float tot = red[0] + red[1] + red[2] + red[3];
    float rs = rsqrtf(tot * (1.0f / 1024.0f) + 1e-6f);
    ushort4 o;
    o.x = f2bf(s.x * rs * s4.x); o.y = f2bf(s.y * rs * s4.y);
    o.z = f2bf(s.z * rs * s4.z); o.w = f2bf(s.w * rs * s4.w);
    ((ushort4*)(xn + (size_t)row * 1024))[t] = o;
    if (LOW) *(ushort4*)(&lrows[j][t * 4]) = o;
    __syncthreads();
  }
  if (LOW) {
    int r = t & 31, g = t >> 5;
    float acc[8];
#pragma unroll
    for (int j = 0; j < 8; ++j) acc[j] = 0.f;
    const float* ap = aP + (size_t)b * 65536;
    for (int i = 0; i < 128; ++i) {
      int k = g * 128 + i;
      float a0 = ap[(size_t)k * 32 + r];
#pragma unroll
      for (int j = 0; j < 8; ++j) acc[j] += bf2f(lrows[j][k]) * a0;
    }
#pragma unroll
    for (int j = 0; j < 8; ++j) pacc[(j * 8 + g) * 32 + r] = acc[j];
    __syncthreads();
    for (int j = 0; j < 8; ++j) {
      if (t < 32) {
        float s = 0.f;
        for (int gg = 0; gg < 8; ++gg) s += pacc[(j * 8 + gg) * 32 + t];
        lowext[(size_t)(row0 + j) * 128 + t] = f2bf(s);
      } else if (t < 128) {
        lowext[(size_t)(row0 + j) * 128 + t] = 0;
      }
    }
  }
}

// ---------------- low for out-proj (ctx bf16 -> lowext bf16) --------------
__global__ __launch_bounds__(256) void k_lowbf(const unsigned short* x, const float* a,
                                               unsigned short* lowext) {
  int row0 = blockIdx.x * 8;
  int b = row0 >> 9;
  int t = threadIdx.x, r = t & 31, j = t >> 5;
  int row = row0 + j;
  const bf16x8* xv = (const bf16x8*)(x + (size_t)row * 1024);
  const float* ap = a + (size_t)b * 65536;
  float s = 0.f;
  for (int kb = 0; kb < 128; ++kb) {
    bf16x8 v = xv[kb];
#pragma unroll
    for (int u = 0; u < 8; ++u)
      s += (float)v[u] * ap[(size_t)(kb * 8 + u) * 32 + r];
  }
  lowext[(size_t)row * 128 + r] = f2bf(s);
  lowext[(size_t)row * 128 + 32 + r] = 0;
  lowext[(size_t)row * 128 + 64 + r] = 0;
  lowext[(size_t)row * 128 + 96 + r] = 0;
}

// ---------------- final sum ----------------
__global__ void k_sum4(const float* p, size_t pstride, const float* resid, float* out) {
  int i = blockIdx.x * 256 + threadIdx.x;
  float4 a = ((const float4*)p)[i];
  float4 b = ((const float4*)(p + pstride))[i];
  float4 c = ((const float4*)(p + 2 * pstride))[i];
  float4 d = ((const float4*)(p + 3 * pstride))[i];
  float4 r = ((const float4*)resid)[i];
  float4 o;
  o.x = a.x + b.x + c.x + d.x + r.x;
  o.y = a.y + b.y + c.y + d.y + r.y;
  o.z = a.z + b.z + c.z + d.z + r.z;
  o.w = a.w + b.w + c.w + d.w + r.w;
  ((float4*)out)[i] = o;
}

// ---------------------------------------------------------------------------

extern "C" void kernel_launch(void* const* d_in, const int* in_sizes, int n_in,
                              void* d_out, int out_size, void* d_ws, size_t ws_size,
                              hipStream_t stream) {
  const float* f_inputs  = (const float*)d_in[0];
  const float* f_encoded = (const float*)d_in[1];
  const float* f_qa = (const float*)d_in[2];
  const float* f_qb = (const float*)d_in[3];
  const float* f_ka = (const float*)d_in[4];
  const float* f_kb = (const float*)d_in[5];
  const float* f_va = (const float*)d_in[6];
  const float* f_vb = (const float*)d_in[7];
  const float* f_oa = (const float*)d_in[8];
  const float* f_ob = (const float*)d_in[9];
  const float* f_table = (const float*)d_in[10];
  const float* f_ln1 = (const float*)d_in[11];
  const float* f_ln2 = (const float*)d_in[12];
  const float* f_ln3 = (const float*)d_in[13];
  const float* f_W[8] = { (const float*)d_in[14], (const float*)d_in[15],
                          (const float*)d_in[16], (const float*)d_in[17],
                          (const float*)d_in[18], (const float*)d_in[19],
                          (const float*)d_in[20], (const float*)d_in[21] };
  const float* f_wi0 = (const float*)d_in[22];
  const float* f_wi1 = (const float*)d_in[23];
  const float* f_wo  = (const float*)d_in[24];

  const size_t SEL1 = 32768;
  const size_t PART = (size_t)2048 * 1024;

  char* w = (char*)d_ws;
  size_t off = 0;
  auto alloc = [&](size_t bytes) -> char* {
    off = (off + 255) & ~(size_t)255;
    char* p = w + off;
    off += bytes;
    return p;
  };
  unsigned short* wt  = (unsigned short*)alloc((size_t)8192 * 1024 * 2); // q,k,v,o,cq,ck,cv,co
  unsigned short* wc  = (unsigned short*)alloc((size_t)8192 * 1024 * 2); // interleaved wi0/wi1
  unsigned short* wot = (unsigned short*)alloc((size_t)1024 * 4096 * 2);
  unsigned short* encbf = (unsigned short*)alloc(2048 * 1024 * 2);
  float* rb = (float*)alloc(16 * 512 * 4);
  unsigned short* xn  = (unsigned short*)alloc(2048 * 1024 * 2);
  unsigned short* qbf = (unsigned short*)alloc(2048 * 1024 * 2);
  unsigned short* kbf = (unsigned short*)alloc(2048 * 1024 * 2);
  unsigned short* vtb = (unsigned short*)alloc((size_t)64 * 64 * 512 * 2);
  unsigned short* kbf2 = (unsigned short*)alloc(2048 * 1024 * 2);
  unsigned short* vtb2 = (unsigned short*)alloc((size_t)64 * 64 * 512 * 2);
  unsigned short* lowext_s = (unsigned short*)alloc(2048 * 128 * 2);
  unsigned short* lowext_c = (unsigned short*)alloc(2048 * 128 * 2);
  unsigned short* lowext_q = (unsigned short*)alloc(2048 * 128 * 2);
  unsigned short* lowext_o = (unsigned short*)alloc(2048 * 128 * 2);
  unsigned short* bmext_s  = (unsigned short*)alloc((size_t)4 * 3072 * 128 * 2);
  unsigned short* bmext_c  = (unsigned short*)alloc((size_t)4 * 2048 * 128 * 2);
  unsigned short* bmext_q  = (unsigned short*)alloc((size_t)4 * 1024 * 128 * 2);
  unsigned short* bmext_o  = (unsigned short*)alloc((size_t)4 * 1024 * 128 * 2);
  unsigned short* bmext_o2 = (unsigned short*)alloc((size_t)4 * 1024 * 128 * 2);
  unsigned short* ctxb = (unsigned short*)alloc(2048 * 1024 * 2);
  float* xres = (float*)alloc(2048 * 1024 * 4);
  float* yres = (float*)alloc(2048 * 1024 * 4);
  char*  big  = alloc((size_t)84 << 20);
  // big aliases (stream-serial lifetimes):
  float* bqs  = (float*)big;                           // self QKV partials 2x[2048][3072] = 48 MB
  float* bqc  = (float*)(big + ((size_t)48 << 20));    // cross KV partials 2x[2048][2048] = 32 MB
  float* op_s = (float*)big;                           // self out-proj partials 4x8 MB
  float* qp_c = (float*)(big + ((size_t)32 << 20));    // cross-Q partials 4x8 MB
  float* op_c = (float*)big;                           // cross out-proj partials 4x8 MB
  unsigned short* hbf = (unsigned short*)big;          // 16 MB
  float* fp   = (float*)(big + ((size_t)16 << 20));    // final partials 4x8 MB
  (void)ws_size; (void)in_sizes; (void)n_in; (void)out_size;

  // ---- prep ----
  PrepArgs pa;
  int ts = 0;
  for (int i = 0; i < 8; ++i) {
    pa.src[i] = f_W[i]; pa.dst[i] = wt + (size_t)i * 1024 * 1024;
    pa.K[i] = 1024; pa.N[i] = 1024; pa.mode[i] = 0;
    pa.tstart[i] = ts; ts += 1024;
  }
  pa.src[8] = f_wi0; pa.dst[8] = wc; pa.K[8] = 1024; pa.N[8] = 4096; pa.mode[8] = 1;
  pa.tstart[8] = ts; ts += 4096;
  pa.src[9] = f_wi1; pa.dst[9] = wc; pa.K[9] = 1024; pa.N[9] = 4096; pa.mode[9] = 2;
  pa.tstart[9] = ts; ts += 4096;
  pa.src[10] = f_wo; pa.dst[10] = wot; pa.K[10] = 4096; pa.N[10] = 1024; pa.mode[10] = 0;
  pa.tstart[10] = ts; ts += 4096;
  pa.tstart[11] = ts;
  pa.nwt = ts;
  pa.encoded = f_encoded; pa.encbf = encbf;
  pa.table = f_table; pa.rb = rb;
  pa.nf2bf = 2048;
  // bmext: {self(q,k,v sel0), crossKV(k,v sel1), crossQ(q sel1), o(sel0), o2(sel1)}
  pa.bmdst[0] = bmext_s;  pa.bmnrg[0] = 24;
  pa.bmsrc[0][0] = f_qb; pa.bmsrc[0][1] = f_kb; pa.bmsrc[0][2] = f_vb;
  pa.bmdst[1] = bmext_c;  pa.bmnrg[1] = 16;
  pa.bmsrc[1][0] = f_kb + SEL1; pa.bmsrc[1][1] = f_vb + SEL1; pa.bmsrc[1][2] = nullptr;
  pa.bmdst[2] = bmext_q;  pa.bmnrg[2] = 8;
  pa.bmsrc[2][0] = f_qb + SEL1; pa.bmsrc[2][1] = nullptr; pa.bmsrc[2][2] = nullptr;
  pa.bmdst[3] = bmext_o;  pa.bmnrg[3] = 8;
  pa.bmsrc[3][0] = f_ob; pa.bmsrc[3][1] = nullptr; pa.bmsrc[3][2] = nullptr;
  pa.bmdst[4] = bmext_o2; pa.bmnrg[4] = 8;
  pa.bmsrc[4][0] = f_ob + SEL1; pa.bmsrc[4][1] = nullptr; pa.bmsrc[4][2] = nullptr;
  int bs = 0;
  for (int m = 0; m < 5; ++m) { pa.bmstart[m] = bs; bs += pa.bmnrg[m] * 4; }
  pa.bmstart[5] = bs;
  pa.nbm = bs;                                  // 256
  pa.lca[0] = f_ka + SEL1; pa.lca[1] = f_va + SEL1;
  pa.lowc = lowext_c;
  int totblk = pa.nwt + pa.nf2bf + 32 + pa.nbm + 256;
  k_prep<<<dim3(totblk), dim3(256), 0, stream>>>(pa);

  // ---- self rms + lows ----
  k_start<<<dim3(256), dim3(256), 0, stream>>>(f_inputs, f_ln1, f_qa, f_ka, f_va, xn, lowext_s);

  // ---- big QKV: self (N=3072, S2) + crossKV (N=2048, S2) ----
  {
    GX g;
    const size_t PS = (size_t)2048 * 3072, PC = (size_t)2048 * 2048;
    g.s[0] = { xn, lowext_s, wt, bmext_s, bqs,            (size_t)3072 * 128, 3072, 24, 0, 9 };
    g.s[1] = { xn, lowext_s, wt, bmext_s, bqs + PS,       (size_t)3072 * 128, 3072, 24, 9, 18 };
    g.s[2] = { encbf, lowext_c, wt + (size_t)5120 * 1024, bmext_c, bqc,      (size_t)2048 * 128, 2048, 16, 0, 9 };
    g.s[3] = { encbf, lowext_c, wt + (size_t)5120 * 1024, bmext_c, bqc + PC, (size_t)2048 * 128, 2048, 16, 9, 18 };
    k_gemmx<<<dim3(24, 16, 4), dim3(256), 0, stream>>>(g);
  }
  k_qkvsum<<<dim3(256, 2), dim3(256), 0, stream>>>(bqs, bqc, qbf, kbf, vtb, kbf2, vtb2);

  k_flash<true, false><<<dim3(8, 64), dim3(256), 0, stream>>>(qbf, nullptr, kbf, vtb, rb, ctxb);

  // ---- self out-proj (K-ext lora_o, S4) ----
  k_lowbf<<<dim3(256), dim3(256), 0, stream>>>(ctxb, f_oa, lowext_o);
  {
    GX g;
    for (int s = 0; s < 4; ++s)
      g.s[s] = { ctxb, lowext_o, wt + (size_t)3072 * 1024, bmext_o, op_s + (size_t)s * PART,
                 (size_t)1024 * 128, 1024, 8, s * 18 / 4, (s + 1) * 18 / 4 };
    k_gemmx<<<dim3(8, 16, 4), dim3(256), 0, stream>>>(g);
  }
  k_addbrms<true><<<dim3(256), dim3(256), 0, stream>>>(op_s, f_inputs, f_ln2, xres, xn,
                                                       f_qa + SEL1, lowext_q);

  // ---- cross-Q (K-ext, S4) ----
  {
    GX g;
    for (int s = 0; s < 4; ++s)
      g.s[s] = { xn, lowext_q, wt + (size_t)4096 * 1024, bmext_q, qp_c + (size_t)s * PART,
                 (size_t)1024 * 128, 1024, 8, s * 18 / 4, (s + 1) * 18 / 4 };
    k_gemmx<<<dim3(8, 16, 4), dim3(256), 0, stream>>>(g);
  }
  k_flash<false, true><<<dim3(8, 64), dim3(256), 0, stream>>>(nullptr, qp_c, kbf2, vtb2, rb, ctxb);

  // ---- cross out-proj (K-ext lora_o sel1, S4) ----
  k_lowbf<<<dim3(256), dim3(256), 0, stream>>>(ctxb, f_oa + SEL1, lowext_o);
  {
    GX g;
    for (int s = 0; s < 4; ++s)
      g.s[s] = { ctxb, lowext_o, wt + (size_t)7168 * 1024, bmext_o2, op_c + (size_t)s * PART,
                 (size_t)1024 * 128, 1024, 8, s * 18 / 4, (s + 1) * 18 / 4 };
    k_gemmx<<<dim3(8, 16, 4), dim3(256), 0, stream>>>(g);
  }
  k_addbrms<false><<<dim3(256), dim3(256), 0, stream>>>(op_c, xres, f_ln3, yres, xn,
                                                        nullptr, nullptr);

  // ---- MLP ----
  k_mlp<<<dim3(32, 16), dim3(512), 0, stream>>>(xn, wc, hbf);
  k_gemm1s<<<dim3(8, 16, 4), dim3(256), 0, stream>>>(hbf, wot, fp, PART, 1024, 4096, 4096, 1024);
  k_sum4<<<dim3(2048), dim3(256), 0, stream>>>(fp, PART, yres, (float*)d_out);
}

// Round 9
// 634.278 us; speedup vs baseline: 1.2932x; 1.0287x over previous
//
#include <hip/hip_runtime.h>
#include <math.h>

// ---------------------------------------------------------------------------
// LoRA T5 decoder layer on MI355X (gfx950).
// B=4, L=ENC=512, D=1024, H=16, HD=64, MLP=4096, R=32.
// R8->R9: replay-divergence bisect. KEEP the fast 64x64 k_prep transpose
// (pure function, launch-1-verified). REVERT to R7-proven forms: big QKV
// split-K S=2 (qkvsum sums 2 partials), lowc in k_prep tail, k_start 256
// blocks. If divergence persists, the transpose is implicated.
// ---------------------------------------------------------------------------

#define DEV __device__ __forceinline__

typedef __bf16 bf16x8 __attribute__((ext_vector_type(8)));
typedef float floatx4 __attribute__((ext_vector_type(4)));

typedef __attribute__((address_space(1))) void* gas_ptr;
typedef __attribute__((address_space(3))) void* las_ptr;

DEV unsigned short f2bf(float f) {
  union { float f; unsigned int u; } v; v.f = f;
  unsigned int r = v.u + 0x7fffu + ((v.u >> 16) & 1u);
  return (unsigned short)(r >> 16);
}
DEV float bf2f(unsigned short u) {
  union { unsigned int u; float f; } v; v.u = ((unsigned int)u) << 16;
  return v.f;
}

#define GLOAD_LDS16(g, l) __builtin_amdgcn_global_load_lds((gas_ptr)(g), (las_ptr)(l), 16, 0, 0)

// Stage nrows x 64 bf16 (128 B rows) from global (row stride ldbytes) into LDS.
template<int NW>
DEV void stage_tile(const char* gbase, char* lds, int nrows, int ldbytes, int wave, int lane) {
  int nchunks = nrows >> 3;
  for (int c = wave; c < nchunks; c += NW) {
    int row  = (c << 3) + (lane >> 3);
    int colb = (lane & 7) << 4;
    GLOAD_LDS16(gbase + (size_t)row * ldbytes + colb, lds + (c << 10));
  }
}

// Stage nrows x 128 bf16 (256 B rows) from global (row stride ldbytes) into LDS.
template<int NW>
DEV void stage_tile256(const char* gbase, char* lds, int nrows, int ldbytes, int wave, int lane) {
  int nchunks = nrows >> 2;
  for (int c = wave; c < nchunks; c += NW) {
    int row  = (c << 2) + (lane >> 4);
    int colb = (lane & 15) << 4;
    GLOAD_LDS16(gbase + (size_t)row * ldbytes + colb, lds + (c << 10));
  }
}

// ---------------- generic bf16 GEMM core (fp32 out), 128x128 tile ----------
template<int WM, int WN>
DEV void gemm_core(const unsigned short* A, const unsigned short* Bt, float* C,
                   int K, int lda, int ldb, int ldc, int m0, int n0,
                   char* ldsA, char* ldsB) {
  constexpr int NW = WM * WN;
  const int tid  = threadIdx.x;
  const int lane = tid & 63;
  const int wave = tid >> 6;
  const int wm   = wave % WM;
  const int wn   = wave / WM;
  const int quad = lane >> 4;
  const int l15  = lane & 15;

  floatx4 acc[4][4];
#pragma unroll
  for (int i = 0; i < 4; ++i)
#pragma unroll
    for (int j = 0; j < 4; ++j) acc[i][j] = (floatx4){0.f, 0.f, 0.f, 0.f};

  const char* gA = (const char*)(A + (size_t)m0 * lda);
  const char* gB = (const char*)(Bt + (size_t)n0 * ldb);

  for (int k0 = 0; k0 < K; k0 += 64) {
    stage_tile<NW>(gA + (size_t)k0 * 2, ldsA, WM * 64, lda * 2, wave, lane);
    stage_tile<NW>(gB + (size_t)k0 * 2, ldsB, WN * 64, ldb * 2, wave, lane);
    __syncthreads();
#pragma unroll
    for (int kk = 0; kk < 64; kk += 32) {
      bf16x8 af[4], bv[4];
      const char* baseA = ldsA + (size_t)(wm * 64 + l15) * 128 + (kk + quad * 8) * 2;
      const char* baseB = ldsB + (size_t)(wn * 64 + l15) * 128 + (kk + quad * 8) * 2;
#pragma unroll
      for (int mi = 0; mi < 4; ++mi) af[mi] = *(const bf16x8*)(baseA + mi * 2048);
#pragma unroll
      for (int ni = 0; ni < 4; ++ni) bv[ni] = *(const bf16x8*)(baseB + ni * 2048);
#pragma unroll
      for (int mi = 0; mi < 4; ++mi)
#pragma unroll
        for (int ni = 0; ni < 4; ++ni)
          acc[mi][ni] = __builtin_amdgcn_mfma_f32_16x16x32_bf16(af[mi], bv[ni], acc[mi][ni], 0, 0, 0);
    }
    __syncthreads();
  }

#pragma unroll
  for (int mi = 0; mi < 4; ++mi) {
#pragma unroll
    for (int r = 0; r < 4; ++r) {
      int row = m0 + wm * 64 + mi * 16 + quad * 4 + r;
#pragma unroll
      for (int ni = 0; ni < 4; ++ni) {
        int col = n0 + wn * 64 + ni * 16 + l15;
        C[(size_t)row * ldc + col] = acc[mi][ni][r];
      }
    }
  }
}

__global__ __launch_bounds__(256) void k_gemm1s(const unsigned short* A, const unsigned short* Bt,
                                                float* Cpart, size_t pstride,
                                                int Kchunk, int lda, int ldb, int ldc) {
  __shared__ char lds[32768];
  int s = blockIdx.z;
  size_t koff = (size_t)s * Kchunk;
  gemm_core<2, 2>(A + koff, Bt + koff, Cpart + (size_t)s * pstride,
                  Kchunk, lda, ldb, ldc,
                  blockIdx.y * 128, blockIdx.x * 128, lds, lds + 16384);
}

// ---------------- K-extended GEMM: C = [A0|Aext] @ [B0|Bext(b)]^T ----------
// A0 [2048][1024] bf16, Aext [2048][128] bf16; B0 [N][1024]; Bext [4][N][128].
// 18 total k-iters (16 W + 2 ext); slice covers iters [it0, it1).
struct GXSlice {
  const unsigned short* A0;
  const unsigned short* Aext;
  const unsigned short* B0;
  const unsigned short* Bext;
  float* C;
  size_t bextb;            // per-b element stride of Bext (= N*128)
  int ldc, nxa, it0, it1;
};
struct GX { GXSlice s[4]; };

__global__ __launch_bounds__(256) void k_gemmx(GX g) {
  __shared__ char lds[32768];
  char* ldsA = lds;
  char* ldsB = lds + 16384;
  GXSlice sl = g.s[blockIdx.z];
  if ((int)blockIdx.x >= sl.nxa) return;
  const int m0 = blockIdx.y * 128, n0 = blockIdx.x * 128;
  const int b = m0 >> 9;
  const int tid = threadIdx.x, lane = tid & 63, wave = tid >> 6;
  const int wm = wave & 1, wn = wave >> 1;
  const int quad = lane >> 4, l15 = lane & 15;

  floatx4 acc[4][4];
#pragma unroll
  for (int i = 0; i < 4; ++i)
#pragma unroll
    for (int j = 0; j < 4; ++j) acc[i][j] = (floatx4){0.f, 0.f, 0.f, 0.f};

  for (int it = sl.it0; it < sl.it1; ++it) {
    if (it < 16) {
      stage_tile<4>((const char*)sl.A0 + (size_t)m0 * 2048 + it * 128, ldsA, 128, 2048, wave, lane);
      stage_tile<4>((const char*)sl.B0 + (size_t)n0 * 2048 + it * 128, ldsB, 128, 2048, wave, lane);
    } else {
      int eb = (it - 16) * 128;
      stage_tile<4>((const char*)sl.Aext + (size_t)m0 * 256 + eb, ldsA, 128, 256, wave, lane);
      stage_tile<4>((const char*)(sl.Bext + (size_t)b * sl.bextb) + (size_t)n0 * 256 + eb,
                    ldsB, 128, 256, wave, lane);
    }
    __syncthreads();
#pragma unroll
    for (int kk = 0; kk < 64; kk += 32) {
      bf16x8 af[4], bv[4];
      const char* baseA = ldsA + (size_t)(wm * 64 + l15) * 128 + (kk + quad * 8) * 2;
      const char* baseB = ldsB + (size_t)(wn * 64 + l15) * 128 + (kk + quad * 8) * 2;
#pragma unroll
      for (int mi = 0; mi < 4; ++mi) af[mi] = *(const bf16x8*)(baseA + mi * 2048);
#pragma unroll
      for (int ni = 0; ni < 4; ++ni) bv[ni] = *(const bf16x8*)(baseB + ni * 2048);
#pragma unroll
      for (int mi = 0; mi < 4; ++mi)
#pragma unroll
        for (int ni = 0; ni < 4; ++ni)
          acc[mi][ni] = __builtin_amdgcn_mfma_f32_16x16x32_bf16(af[mi], bv[ni], acc[mi][ni], 0, 0, 0);
    }
    __syncthreads();
  }

#pragma unroll
  for (int mi = 0; mi < 4; ++mi) {
#pragma unroll
    for (int r = 0; r < 4; ++r) {
      int row = m0 + wm * 64 + mi * 16 + quad * 4 + r;
#pragma unroll
      for (int ni = 0; ni < 4; ++ni) {
        int col = n0 + wn * 64 + ni * 16 + l15;
        sl.C[(size_t)row * sl.ldc + col] = acc[mi][ni][r];
      }
    }
  }
}

// ---------------- QKV sum: splitK(2) sum + bf16 cast + V transpose --------
__global__ __launch_bounds__(256) void k_qkvsum(const float* bqs, const float* bqc,
                                                unsigned short* qbf, unsigned short* kbf,
                                                unsigned short* vtb, unsigned short* kbf2,
                                                unsigned short* vtb2) {
  const size_t PS = (size_t)2048 * 3072, PC = (size_t)2048 * 2048;
  int t = threadIdx.x;
  int row0 = blockIdx.x * 8;
  int zc = blockIdx.y;
  for (int j = 0; j < 8; ++j) {
    int row = row0 + j;
    int b = row >> 9, kpos = row & 511;
    int nsec = zc ? 2 : 3;
    for (int sec = 0; sec < nsec; ++sec) {
      const float* base = zc ? (bqc + (size_t)row * 2048 + sec * 1024)
                             : (bqs + (size_t)row * 3072 + sec * 1024);
      float4 a = ((const float4*)base)[t];
      float4 c = ((const float4*)(base + (zc ? PC : PS)))[t];
      float4 s; s.x = a.x + c.x; s.y = a.y + c.y; s.z = a.z + c.z; s.w = a.w + c.w;
      ushort4 o; o.x = f2bf(s.x); o.y = f2bf(s.y); o.z = f2bf(s.z); o.w = f2bf(s.w);
      int vsec = zc ? (sec == 1) : (sec == 2);
      if (!vsec) {
        unsigned short* dst = zc ? kbf2 : (sec == 0 ? qbf : kbf);
        ((ushort4*)(dst + (size_t)row * 1024))[t] = o;
      } else {
        unsigned short* dst = zc ? vtb2 : vtb;
        int h = t >> 4, dbase = (t & 15) * 4;
        size_t base2 = ((size_t)(b * 16 + h) * 64 + dbase) * 512 + kpos;
        dst[base2] = o.x; dst[base2 + 512] = o.y;
        dst[base2 + 1024] = o.z; dst[base2 + 1536] = o.w;
      }
    }
  }
}

// ---------------- flash attention ----------------
template<bool CAUSAL, bool QSUM>
__global__ __launch_bounds__(256) void k_flash(const unsigned short* qmat, const float* qparts,
                                               const unsigned short* kmat, const unsigned short* vt,
                                               const float* rb, unsigned short* ctxb) {
  __shared__ char ldsQ[8192];    // [64 q][64 d]
  __shared__ char ldsK[16384];   // [128 k][64 d]
  __shared__ char ldsV[16384];   // [64 d][128 k]
  __shared__ char ldsP[16384];   // [64 q][128 k]
  __shared__ float lrb[512];

  const size_t PART = (size_t)2048 * 1024;
  const int z = blockIdx.y, b = z >> 4, h = z & 15;
  const int q0 = blockIdx.x * 64;
  const int tid = threadIdx.x, lane = tid & 63, wave = tid >> 6;
  const int quad = lane >> 4, l15 = lane & 15;

  const unsigned short* K = kmat + (size_t)b * 512 * 1024 + h * 64;
  const unsigned short* V = vt + (size_t)z * 64 * 512;

  if (QSUM) {
#pragma unroll
    for (int rr = 0; rr < 4; ++rr) {
      int row = rr * 16 + (tid >> 4);
      int c4 = tid & 15;
      const float* src = qparts + (size_t)(q0 + row) * 1024 + h * 64 + c4 * 4;
      float4 s0 = *(const float4*)src;
      float4 s1 = *(const float4*)(src + PART);
      float4 s2 = *(const float4*)(src + 2 * PART);
      float4 s3 = *(const float4*)(src + 3 * PART);
      ushort4 o;
      o.x = f2bf(s0.x + s1.x + s2.x + s3.x);
      o.y = f2bf(s0.y + s1.y + s2.y + s3.y);
      o.z = f2bf(s0.z + s1.z + s2.z + s3.z);
      o.w = f2bf(s0.w + s1.w + s2.w + s3.w);
      *(ushort4*)(ldsQ + (size_t)row * 128 + c4 * 8) = o;
    }
  } else {
    const unsigned short* Q = qmat + (size_t)b * 512 * 1024 + h * 64;
    stage_tile<4>((const char*)(Q + (size_t)q0 * 1024), ldsQ, 64, 2048, wave, lane);
  }
  if (CAUSAL)
    for (int i = tid; i < 512; i += 256) lrb[i] = rb[h * 512 + i];

  float m_run[4], l_run[4];
  floatx4 oacc[4];
#pragma unroll
  for (int r = 0; r < 4; ++r) { m_run[r] = -1e30f; l_run[r] = 0.f; }
#pragma unroll
  for (int ni = 0; ni < 4; ++ni) oacc[ni] = (floatx4){0.f, 0.f, 0.f, 0.f};

  const int ktend = CAUSAL ? (blockIdx.x / 2 + 1) : 4;
  for (int kt = 0; kt < ktend; ++kt) {
    __syncthreads();
    stage_tile<4>((const char*)(K + (size_t)kt * 128 * 1024), ldsK, 128, 2048, wave, lane);
    stage_tile256<4>((const char*)(V + kt * 128), ldsV, 64, 1024, wave, lane);
    __syncthreads();

    floatx4 sacc[8];
#pragma unroll
    for (int ct = 0; ct < 8; ++ct) sacc[ct] = (floatx4){0.f, 0.f, 0.f, 0.f};
    const char* aBase = ldsQ + (size_t)(wave * 16 + l15) * 128 + quad * 16;
#pragma unroll
    for (int kd = 0; kd < 2; ++kd) {
      bf16x8 af = *(const bf16x8*)(aBase + kd * 64);
#pragma unroll
      for (int ct = 0; ct < 8; ++ct) {
        bf16x8 bf = *(const bf16x8*)(ldsK + (size_t)(ct * 16 + l15) * 128 + quad * 16 + kd * 64);
        sacc[ct] = __builtin_amdgcn_mfma_f32_16x16x32_bf16(af, bf, sacc[ct], 0, 0, 0);
      }
    }

    float sv[8][4];
#pragma unroll
    for (int ct = 0; ct < 8; ++ct)
#pragma unroll
      for (int r = 0; r < 4; ++r) {
        float v = sacc[ct][r] * 0.125f;
        if (CAUSAL) {
          int qq = q0 + wave * 16 + quad * 4 + r;
          int kk = kt * 128 + ct * 16 + l15;
          v = (kk <= qq) ? v + lrb[qq - kk] : -1e30f;
        }
        sv[ct][r] = v;
      }

    float mx[4];
#pragma unroll
    for (int r = 0; r < 4; ++r) {
      mx[r] = sv[0][r];
#pragma unroll
      for (int ct = 1; ct < 8; ++ct) mx[r] = fmaxf(mx[r], sv[ct][r]);
    }
#pragma unroll
    for (int o = 1; o < 16; o <<= 1)
#pragma unroll
      for (int r = 0; r < 4; ++r) mx[r] = fmaxf(mx[r], __shfl_xor(mx[r], o));

    float alpha[4], rs[4];
#pragma unroll
    for (int r = 0; r < 4; ++r) {
      float mn = fmaxf(m_run[r], mx[r]);
      alpha[r] = __expf(m_run[r] - mn);
      m_run[r] = mn;
      rs[r] = 0.f;
    }
#pragma unroll
    for (int ct = 0; ct < 8; ++ct)
#pragma unroll
      for (int r = 0; r < 4; ++r) {
        float p = __expf(sv[ct][r] - m_run[r]);
        sv[ct][r] = p;
        rs[r] += p;
      }
#pragma unroll
    for (int o = 1; o < 16; o <<= 1)
#pragma unroll
      for (int r = 0; r < 4; ++r) rs[r] += __shfl_xor(rs[r], o);
#pragma unroll
    for (int r = 0; r < 4; ++r) l_run[r] = l_run[r] * alpha[r] + rs[r];
#pragma unroll
    for (int ni = 0; ni < 4; ++ni)
#pragma unroll
      for (int r = 0; r < 4; ++r) oacc[ni][r] *= alpha[r];

#pragma unroll
    for (int ct = 0; ct < 8; ++ct)
#pragma unroll
      for (int r = 0; r < 4; ++r)
        *(unsigned short*)(ldsP + (size_t)(wave * 16 + quad * 4 + r) * 256 + (ct * 16 + l15) * 2)
            = f2bf(sv[ct][r]);
    __syncthreads();

    const char* pBase = ldsP + (size_t)(wave * 16 + l15) * 256 + quad * 16;
#pragma unroll
    for (int kk = 0; kk < 4; ++kk) {
      bf16x8 pf = *(const bf16x8*)(pBase + kk * 64);
#pragma unroll
      for (int ni = 0; ni < 4; ++ni) {
        bf16x8 vf8 = *(const bf16x8*)(ldsV + (size_t)(ni * 16 + l15) * 256 + quad * 16 + kk * 64);
        oacc[ni] = __builtin_amdgcn_mfma_f32_16x16x32_bf16(pf, vf8, oacc[ni], 0, 0, 0);
      }
    }
  }

#pragma unroll
  for (int r = 0; r < 4; ++r) {
    int q = q0 + wave * 16 + quad * 4 + r;
    float inv = 1.0f / l_run[r];
    unsigned short* dst = ctxb + ((size_t)b * 512 + q) * 1024 + h * 64;
#pragma unroll
    for (int ni = 0; ni < 4; ++ni)
      dst[ni * 16 + l15] = f2bf(oacc[ni][r] * inv);
  }
}

// ---------------- fused MLP ----------------
__global__ __launch_bounds__(512) void k_mlp(const unsigned short* A, const unsigned short* Wc,
                                             unsigned short* hbf) {
  __shared__ char lds[49152];
  char* ldsA = lds;
  char* ldsB = lds + 16384;
  const int m0 = blockIdx.y * 128;
  const int n0 = blockIdx.x * 128;
  const int tid = threadIdx.x, lane = tid & 63, wave = tid >> 6;
  const int half = wave >> 2, wl = wave & 3;
  const int wm = wl & 1, wn = wl >> 1;
  const int quad = lane >> 4, l15 = lane & 15;

  floatx4 acc[4][4];
#pragma unroll
  for (int i = 0; i < 4; ++i)
#pragma unroll
    for (int j = 0; j < 4; ++j) acc[i][j] = (floatx4){0.f, 0.f, 0.f, 0.f};

  const char* gA = (const char*)(A + (size_t)m0 * 1024);
  const char* gB = (const char*)(Wc + (size_t)blockIdx.x * 256 * 1024);

  for (int k0 = 0; k0 < 1024; k0 += 64) {
    stage_tile<8>(gA + (size_t)k0 * 2, ldsA, 128, 2048, wave, lane);
    stage_tile<8>(gB + (size_t)k0 * 2, ldsB, 256, 2048, wave, lane);
    __syncthreads();
#pragma unroll
    for (int kk = 0; kk < 64; kk += 32) {
      bf16x8 af[4], bv[4];
      const char* baseA = ldsA + (size_t)(wm * 64 + l15) * 128 + (kk + quad * 8) * 2;
      const char* baseB = ldsB + (size_t)(half * 128 + wn * 64 + l15) * 128 + (kk + quad * 8) * 2;
#pragma unroll
      for (int mi = 0; mi < 4; ++mi) af[mi] = *(const bf16x8*)(baseA + mi * 2048);
#pragma unroll
      for (int ni = 0; ni < 4; ++ni) bv[ni] = *(const bf16x8*)(baseB + ni * 2048);
#pragma unroll
      for (int mi = 0; mi < 4; ++mi)
#pragma unroll
        for (int ni = 0; ni < 4; ++ni)
          acc[mi][ni] = __builtin_amdgcn_mfma_f32_16x16x32_bf16(af[mi], bv[ni], acc[mi][ni], 0, 0, 0);
    }
    __syncthreads();
  }

  if (half == 1) {
#pragma unroll
    for (int mi = 0; mi < 4; ++mi)
#pragma unroll
      for (int r = 0; r < 4; ++r) {
        int row = wm * 64 + mi * 16 + quad * 4 + r;
#pragma unroll
        for (int ni = 0; ni < 4; ++ni) {
          int col = wn * 64 + ni * 16 + l15;
          *(unsigned short*)(ldsB + (size_t)row * 256 + col * 2) = f2bf(acc[mi][ni][r]);
        }
      }
  }
  __syncthreads();
  if (half == 0) {
#pragma unroll
    for (int mi = 0; mi < 4; ++mi)
#pragma unroll
      for (int r = 0; r < 4; ++r) {
        int row = wm * 64 + mi * 16 + quad * 4 + r;
#pragma unroll
        for (int ni = 0; ni < 4; ++ni) {
          int col = wn * 64 + ni * 16 + l15;
          float h1 = bf2f(*(const unsigned short*)(ldsB + (size_t)row * 256 + col * 2));
          float g = acc[mi][ni][r];
          float v = 0.5f * g * (1.0f + erff(g * 0.70710678f)) * h1;
          hbf[(size_t)(m0 + row) * 4096 + n0 + col] = f2bf(v);
        }
      }
  }
}

// ---------------- prep: fast transpose + encbf + relbias + bmext + lowc ---
struct PrepArgs {
  const float* src[11];
  unsigned short* dst[11];
  int K[11], N[11], mode[11];
  int tstart[12];
  const float* encoded;
  unsigned short* encbf;
  const float* table;
  float* rb;
  unsigned short* bmdst[5];
  const float* bmsrc[5][3];
  int bmnrg[5];
  int bmstart[6];
  const float* lca[2];
  unsigned short* lowc;
  int nwt, nf2bf, nbm;
};
__global__ __launch_bounds__(256) void k_prep(PrepArgs a) {
  __shared__ char shm[49152];
  int bid = blockIdx.x;
  int t = threadIdx.x;
  if (bid < a.nwt) {
    // fp32 [K][N] -> bf16 [N][K] in 64x64 tiles; full-line loads & stores.
    float (*tl)[65] = (float(*)[65])shm;   // 16.6 KB
    int z = 0;
    while (z < 10 && bid >= a.tstart[z + 1]) ++z;
    int tile = bid - a.tstart[z];
    int N = a.N[z], K = a.K[z], mode = a.mode[z];
    int ntn = N >> 6;
    int tn = tile % ntn, tk = tile / ntn;
    const float* src = a.src[z] + (size_t)(tk * 64) * N + tn * 64;
    unsigned short* dst = a.dst[z];
    {
      int rq = t >> 4, c4 = (t & 15) * 4;
#pragma unroll
      for (int i = 0; i < 4; ++i) {
        int r = rq + i * 16;
        float4 v = *(const float4*)(src + (size_t)r * N + c4);
        tl[r][c4] = v.x; tl[r][c4 + 1] = v.y; tl[r][c4 + 2] = v.z; tl[r][c4 + 3] = v.w;
      }
    }
    __syncthreads();
    {
      int nl = t >> 2, kseg = (t & 3) * 16;
      int n = tn * 64 + nl;
      int orow = (mode == 0) ? n : ((n >> 7) * 256 + ((mode == 2) ? 128 : 0) + (n & 127));
      union { unsigned short us[16]; uint4 q[2]; } pk;
#pragma unroll
      for (int j = 0; j < 16; ++j) pk.us[j] = f2bf(tl[kseg + j][nl]);
      uint4* dp = (uint4*)(dst + (size_t)orow * K + tk * 64 + kseg);
      dp[0] = pk.q[0]; dp[1] = pk.q[1];
    }
    return;
  }
  bid -= a.nwt;
  if (bid < a.nf2bf) {
    int i = bid * 256 + t;
    float4 v = ((const float4*)a.encoded)[i];
    ushort4 o;
    o.x = f2bf(v.x); o.y = f2bf(v.y); o.z = f2bf(v.z); o.w = f2bf(v.w);
    ((ushort4*)a.encbf)[i] = o;
    return;
  }
  bid -= a.nf2bf;
  if (bid < 32) {
    int i = bid * 256 + t;
    if (i < 16 * 512) {
      int h = i >> 9, d = i & 511;
      int bucket;
      if (d < 16) bucket = d;
      else {
        int lb = 16 + (int)(logf((float)d / 16.0f) / logf(8.0f) * 16.0f);
        bucket = lb < 31 ? lb : 31;
      }
      a.rb[i] = a.table[bucket * 16 + h];
    }
    return;
  }
  bid -= 32;
  if (bid < a.nbm) {
    // bmext fill: Bext[b][row=n0+n][c] = (c>>5==sec) ? b_sec[b][c&31][(n0&1023)+n] : 0
    int m = 0;
    while (m < 4 && bid >= a.bmstart[m + 1]) ++m;
    int idx = bid - a.bmstart[m];
    int nrg = a.bmnrg[m];
    int b = idx / nrg, rg = idx % nrg;
    int n0 = rg * 128;
    int sec = n0 >> 10;
    const float* src = a.bmsrc[m][sec] + (size_t)b * 65536;
    unsigned short* dst = a.bmdst[m] + ((size_t)b * nrg * 128 + n0) * 128;
    int n = t & 127, coff = (t >> 7) * 64;
    int ncol = (n0 & 1023) + n;
    unsigned short* drow = dst + (size_t)n * 128 + coff;
    for (int c4 = 0; c4 < 16; ++c4) {
      ushort4 o;
#pragma unroll
      for (int e = 0; e < 4; ++e) {
        int c = coff + c4 * 4 + e;
        float v = ((c >> 5) == sec) ? src[(size_t)(c & 31) * 1024 + ncol] : 0.f;
        ((unsigned short*)&o)[e] = f2bf(v);
      }
      *(ushort4*)(drow + c4 * 4) = o;
    }
    return;
  }
  bid -= a.nbm;
  {
    // cross-KV lows from fp32 encoded: 8 rows/block (R7-proven)
    float* rowsF = (float*)shm;                       // [8][1024] = 32 KB
    float* pacc = (float*)(shm + 32768);              // [2][8][8][32] = 16 KB
    int row0 = bid * 8;
    int b = row0 >> 9;
    for (int j = 0; j < 8; ++j)
      ((float4*)(rowsF + j * 1024))[t] = ((const float4*)(a.encoded + (size_t)(row0 + j) * 1024))[t];
    __syncthreads();
    int r = t & 31, g = t >> 5;
    float acc[2][8];
#pragma unroll
    for (int p = 0; p < 2; ++p)
#pragma unroll
      for (int j = 0; j < 8; ++j) acc[p][j] = 0.f;
    const float* a0 = a.lca[0] + (size_t)b * 65536;
    const float* a1 = a.lca[1] + (size_t)b * 65536;
    for (int i = 0; i < 128; ++i) {
      int k = g * 128 + i;
      float ak = a0[(size_t)k * 32 + r];
      float av = a1[(size_t)k * 32 + r];
#pragma unroll
      for (int j = 0; j < 8; ++j) {
        float x = rowsF[j * 1024 + k];
        acc[0][j] += x * ak;
        acc[1][j] += x * av;
      }
    }
#pragma unroll
    for (int p = 0; p < 2; ++p)
#pragma unroll
      for (int j = 0; j < 8; ++j)
        pacc[((p * 8 + j) * 8 + g) * 32 + r] = acc[p][j];
    __syncthreads();
    for (int j = 0; j < 8; ++j) {
      if (t < 64) {
        int p = t >> 5, r2 = t & 31;
        float s = 0.f;
        for (int gg = 0; gg < 8; ++gg) s += pacc[((p * 8 + j) * 8 + gg) * 32 + r2];
        a.lowc[(size_t)(row0 + j) * 128 + p * 32 + r2] = f2bf(s);
      } else if (t < 128) {
        a.lowc[(size_t)(row0 + j) * 128 + t] = 0;
      }
    }
  }
}

// ---------------- k_start: rmsnorm + self q/k/v lows (R7-proven) ----------
__global__ __launch_bounds__(256) void k_start(const float* x, const float* sc,
                                               const float* qa, const float* ka, const float* va,
                                               unsigned short* xn, unsigned short* lowext) {
  __shared__ unsigned short lrows[8][1024];   // 16 KB
  __shared__ float pacc[3 * 8 * 8 * 32];      // 24 KB
  __shared__ float red[4];
  int t = threadIdx.x;
  int row0 = blockIdx.x * 8;
  int b = row0 >> 9;
  float4 s4 = ((const float4*)sc)[t];
  for (int j = 0; j < 8; ++j) {
    int row = row0 + j;
    float4 v = ((const float4*)(x + (size_t)row * 1024))[t];
    float ss = v.x * v.x + v.y * v.y + v.z * v.z + v.w * v.w;
    for (int o = 32; o; o >>= 1) ss += __shfl_down(ss, o);
    if ((t & 63) == 0) red[t >> 6] = ss;
    __syncthreads();
    float tot = red[0] + red[1] + red[2] + red[3];
    float rs = rsqrtf(tot * (1.0f / 1024.0f) + 1e-6f);
    ushort4 o;
    o.x = f2bf(v.x * rs * s4.x); o.y = f2bf(v.y * rs * s4.y);
    o.z = f2bf(v.z * rs * s4.z); o.w = f2bf(v.w * rs * s4.w);
    ((ushort4*)(xn + (size_t)row * 1024))[t] = o;
    *(ushort4*)(&lrows[j][t * 4]) = o;
    __syncthreads();
  }
  int r = t & 31, g = t >> 5;
  float acc[3][8];
#pragma unroll
  for (int p = 0; p < 3; ++p)
#pragma unroll
    for (int j = 0; j < 8; ++j) acc[p][j] = 0.f;
  const float* aq = qa + (size_t)b * 65536;
  const float* ak = ka + (size_t)b * 65536;
  const float* av = va + (size_t)b * 65536;
  for (int i = 0; i < 128; ++i) {
    int k = g * 128 + i;
    float a0 = aq[(size_t)k * 32 + r];
    float a1 = ak[(size_t)k * 32 + r];
    float a2 = av[(size_t)k * 32 + r];
#pragma unroll
    for (int j = 0; j < 8; ++j) {
      float xv = bf2f(lrows[j][k]);
      acc[0][j] += xv * a0;
      acc[1][j] += xv * a1;
      acc[2][j] += xv * a2;
    }
  }
#pragma unroll
  for (int p = 0; p < 3; ++p)
#pragma unroll
    for (int j = 0; j < 8; ++j)
      pacc[((p * 8 + j) * 8 + g) * 32 + r] = acc[p][j];
  __syncthreads();
  for (int j = 0; j < 8; ++j) {
    if (t < 96) {
      int p = t >> 5, r2 = t & 31;
      float s = 0.f;
      for (int gg = 0; gg < 8; ++gg) s += pacc[((p * 8 + j) * 8 + gg) * 32 + r2];
      lowext[(size_t)(row0 + j) * 128 + p * 32 + r2] = f2bf(s);
    } else if (t < 128) {
      lowext[(size_t)(row0 + j) * 128 + t] = 0;
    }
  }
}

// ---------------- k_addbrms: 4-partial sum + resid + rms (+ next low) -----
template<bool LOW>
__global__ __launch_bounds__(256) void k_addbrms(const float* parts, const float* resid,
                                                 const float* sc, float* resout,
                                                 unsigned short* xn,
                                                 const float* aP, unsigned short* lowext) {
  __shared__ unsigned short lrows[8][1024];
  __shared__ float pacc[8 * 8 * 32];
  __shared__ float red[4];
  const size_t PART = (size_t)2048 * 1024;
  int t = threadIdx.x;
  int row0 = blockIdx.x * 8;
  int b = row0 >> 9;
  float4 s4 = ((const float4*)sc)[t];
  for (int j = 0; j < 8; ++j) {
    int row = row0 + j;
    const float* p0 = parts + (size_t)row * 1024;
    float4 v = ((const float4*)p0)[t];
    float4 v1 = ((const float4*)(p0 + PART))[t];
    float4 v2 = ((const float4*)(p0 + 2 * PART))[t];
    float4 v3 = ((const float4*)(p0 + 3 * PART))[t];
    float4 rv = ((const float4*)(resid + (size_t)row * 1024))[t];
    float4 s;
    s.x = v.x + v1.x + v2.x + v3.x + rv.x;
    s.y = v.y + v1.y + v2.y + v3.y + rv.y;
    s.z = v.z + v1.z + v2.z + v3.z + rv.z;
    s.w = v.w + v1.w + v2.w + v3.w + rv.w;
    ((float4*)(resout + (size_t)row * 1024))[t] = s;
    float ss = s.x * s.x + s.y * s.y + s.z * s.z + s.w * s.w;
    for (int o = 32; o; o >>= 1) ss += __shfl_down(ss, o);
    if ((t & 63) == 0) red[t >> 6] = ss;
    __syncthreads();
    float tot = red[0] + red[1] + red[2] + red[3];
    float rs = rsqrtf(tot * (1.0f / 1024.0f) + 1e-6f);
    ushort4 o;
    o.x = f2bf(s.x * rs * s4.x); o.y = f2bf(s.y * rs * s4.y);
    o.z = f2bf(s.z * rs * s4.z); o.w = f2bf(s.w * rs * s4.w);
    ((ushort4*)(xn + (size_t)row * 1024))[t] = o;
    if (LOW) *(ushort4*)(&lrows[j][t * 4]) = o;
    __syncthreads();
  }
  if (LOW) {
    int r = t & 31, g = t >> 5;
    float acc[8];
#pragma unroll
    for (int j = 0; j < 8; ++j) acc[j] = 0.f;
    const float* ap = aP + (size_t)b * 65536;
    for (int i = 0; i < 128; ++i) {
      int k = g * 128 + i;
      float a0 = ap[(size_t)k * 32 + r];
#pragma unroll
      for (int j = 0; j < 8; ++j) acc[j] += bf2f(lrows[j][k]) * a0;
    }
#pragma unroll
    for (int j = 0; j < 8; ++j) pacc[(j * 8 + g) * 32 + r] = acc[j];
    __syncthreads();
    for (int j = 0; j < 8; ++j) {
      if (t < 32) {
        float s = 0.f;
        for (int gg = 0; gg < 8; ++gg) s += pacc[(j * 8 + gg) * 32 + t];
        lowext[(size_t)(row0 + j) * 128 + t] = f2bf(s);
      } else if (t < 128) {
        lowext[(size_t)(row0 + j) * 128 + t] = 0;
      }
    }
  }
}

// ---------------- low for out-proj (ctx bf16 -> lowext bf16) --------------
__global__ __launch_bounds__(256) void k_lowbf(const unsigned short* x, const float* a,
                                               unsigned short* lowext) {
  int row0 = blockIdx.x * 8;
  int b = row0 >> 9;
  int t = threadIdx.x, r = t & 31, j = t >> 5;
  int row = row0 + j;
  const bf16x8* xv = (const bf16x8*)(x + (size_t)row * 1024);
  const float* ap = a + (size_t)b * 65536;
  float s = 0.f;
  for (int kb = 0; kb < 128; ++kb) {
    bf16x8 v = xv[kb];
#pragma unroll
    for (int u = 0; u < 8; ++u)
      s += (float)v[u] * ap[(size_t)(kb * 8 + u) * 32 + r];
  }
  lowext[(size_t)row * 128 + r] = f2bf(s);
  lowext[(size_t)row * 128 + 32 + r] = 0;
  lowext[(size_t)row * 128 + 64 + r] = 0;
  lowext[(size_t)row * 128 + 96 + r] = 0;
}

// ---------------- final sum ----------------
__global__ void k_sum4(const float* p, size_t pstride, const float* resid, float* out) {
  int i = blockIdx.x * 256 + threadIdx.x;
  float4 a = ((const float4*)p)[i];
  float4 b = ((const float4*)(p + pstride))[i];
  float4 c = ((const float4*)(p + 2 * pstride))[i];
  float4 d = ((const float4*)(p + 3 * pstride))[i];
  float4 r = ((const float4*)resid)[i];
  float4 o;
  o.x = a.x + b.x + c.x + d.x + r.x;
  o.y = a.y + b.y + c.y + d.y + r.y;
  o.z = a.z + b.z + c.z + d.z + r.z;
  o.w = a.w + b.w + c.w + d.w + r.w;
  ((float4*)out)[i] = o;
}

// ---------------------------------------------------------------------------

extern "C" void kernel_launch(void* const* d_in, const int* in_sizes, int n_in,
                              void* d_out, int out_size, void* d_ws, size_t ws_size,
                              hipStream_t stream) {
  const float* f_inputs  = (const float*)d_in[0];
  const float* f_encoded = (const float*)d_in[1];
  const float* f_qa = (const float*)d_in[2];
  const float* f_qb = (const float*)d_in[3];
  const float* f_ka = (const float*)d_in[4];
  const float* f_kb = (const float*)d_in[5];
  const float* f_va = (const float*)d_in[6];
  const float* f_vb = (const float*)d_in[7];
  const float* f_oa = (const float*)d_in[8];
  const float* f_ob = (const float*)d_in[9];
  const float* f_table = (const float*)d_in[10];
  const float* f_ln1 = (const float*)d_in[11];
  const float* f_ln2 = (const float*)d_in[12];
  const float* f_ln3 = (const float*)d_in[13];
  const float* f_W[8] = { (const float*)d_in[14], (const float*)d_in[15],
                          (const float*)d_in[16], (const float*)d_in[17],
                          (const float*)d_in[18], (const float*)d_in[19],
                          (const float*)d_in[20], (const float*)d_in[21] };
  const float* f_wi0 = (const float*)d_in[22];
  const float* f_wi1 = (const float*)d_in[23];
  const float* f_wo  = (const float*)d_in[24];

  const size_t SEL1 = 32768;
  const size_t PART = (size_t)2048 * 1024;

  char* w = (char*)d_ws;
  size_t off = 0;
  auto alloc = [&](size_t bytes) -> char* {
    off = (off + 255) & ~(size_t)255;
    char* p = w + off;
    off += bytes;
    return p;
  };
  unsigned short* wt  = (unsigned short*)alloc((size_t)8192 * 1024 * 2); // q,k,v,o,cq,ck,cv,co
  unsigned short* wc  = (unsigned short*)alloc((size_t)8192 * 1024 * 2); // interleaved wi0/wi1
  unsigned short* wot = (unsigned short*)alloc((size_t)1024 * 4096 * 2);
  unsigned short* encbf = (unsigned short*)alloc(2048 * 1024 * 2);
  float* rb = (float*)alloc(16 * 512 * 4);
  unsigned short* xn  = (unsigned short*)alloc(2048 * 1024 * 2);
  unsigned short* qbf = (unsigned short*)alloc(2048 * 1024 * 2);
  unsigned short* kbf = (unsigned short*)alloc(2048 * 1024 * 2);
  unsigned short* vtb = (unsigned short*)alloc((size_t)64 * 64 * 512 * 2);
  unsigned short* kbf2 = (unsigned short*)alloc(2048 * 1024 * 2);
  unsigned short* vtb2 = (unsigned short*)alloc((size_t)64 * 64 * 512 * 2);
  unsigned short* lowext_s = (unsigned short*)alloc(2048 * 128 * 2);
  unsigned short* lowext_c = (unsigned short*)alloc(2048 * 128 * 2);
  unsigned short* lowext_q = (unsigned short*)alloc(2048 * 128 * 2);
  unsigned short* lowext_o = (unsigned short*)alloc(2048 * 128 * 2);
  unsigned short* bmext_s  = (unsigned short*)alloc((size_t)4 * 3072 * 128 * 2);
  unsigned short* bmext_c  = (unsigned short*)alloc((size_t)4 * 2048 * 128 * 2);
  unsigned short* bmext_q  = (unsigned short*)alloc((size_t)4 * 1024 * 128 * 2);
  unsigned short* bmext_o  = (unsigned short*)alloc((size_t)4 * 1024 * 128 * 2);
  unsigned short* bmext_o2 = (unsigned short*)alloc((size_t)4 * 1024 * 128 * 2);
  unsigned short* ctxb = (unsigned short*)alloc(2048 * 1024 * 2);
  float* xres = (float*)alloc(2048 * 1024 * 4);
  float* yres = (float*)alloc(2048 * 1024 * 4);
  char*  big  = alloc((size_t)84 << 20);
  // big aliases (stream-serial lifetimes):
  float* bqs  = (float*)big;                           // self QKV partials 2x[2048][3072] = 48 MB
  float* bqc  = (float*)(big + ((size_t)48 << 20));    // cross KV partials 2x[2048][2048] = 32 MB
  float* op_s = (float*)big;                           // self out-proj partials 4x8 MB
  float* qp_c = (float*)(big + ((size_t)32 << 20));    // cross-Q partials 4x8 MB
  float* op_c = (float*)big;                           // cross out-proj partials 4x8 MB
  unsigned short* hbf = (unsigned short*)big;          // 16 MB
  float* fp   = (float*)(big + ((size_t)16 << 20));    // final partials 4x8 MB
  (void)ws_size; (void)in_sizes; (void)n_in; (void)out_size;

  // ---- prep ----
  PrepArgs pa;
  int ts = 0;
  for (int i = 0; i < 8; ++i) {
    pa.src[i] = f_W[i]; pa.dst[i] = wt + (size_t)i * 1024 * 1024;
    pa.K[i] = 1024; pa.N[i] = 1024; pa.mode[i] = 0;
    pa.tstart[i] = ts; ts += 256;                     // (1024/64)^2
  }
  pa.src[8] = f_wi0; pa.dst[8] = wc; pa.K[8] = 1024; pa.N[8] = 4096; pa.mode[8] = 1;
  pa.tstart[8] = ts; ts += 1024;                      // 16 x 64
  pa.src[9] = f_wi1; pa.dst[9] = wc; pa.K[9] = 1024; pa.N[9] = 4096; pa.mode[9] = 2;
  pa.tstart[9] = ts; ts += 1024;
  pa.src[10] = f_wo; pa.dst[10] = wot; pa.K[10] = 4096; pa.N[10] = 1024; pa.mode[10] = 0;
  pa.tstart[10] = ts; ts += 1024;                     // 64 x 16
  pa.tstart[11] = ts;
  pa.nwt = ts;
  pa.encoded = f_encoded; pa.encbf = encbf;
  pa.table = f_table; pa.rb = rb;
  pa.nf2bf = 2048;
  pa.bmdst[0] = bmext_s;  pa.bmnrg[0] = 24;
  pa.bmsrc[0][0] = f_qb; pa.bmsrc[0][1] = f_kb; pa.bmsrc[0][2] = f_vb;
  pa.bmdst[1] = bmext_c;  pa.bmnrg[1] = 16;
  pa.bmsrc[1][0] = f_kb + SEL1; pa.bmsrc[1][1] = f_vb + SEL1; pa.bmsrc[1][2] = nullptr;
  pa.bmdst[2] = bmext_q;  pa.bmnrg[2] = 8;
  pa.bmsrc[2][0] = f_qb + SEL1; pa.bmsrc[2][1] = nullptr; pa.bmsrc[2][2] = nullptr;
  pa.bmdst[3] = bmext_o;  pa.bmnrg[3] = 8;
  pa.bmsrc[3][0] = f_ob; pa.bmsrc[3][1] = nullptr; pa.bmsrc[3][2] = nullptr;
  pa.bmdst[4] = bmext_o2; pa.bmnrg[4] = 8;
  pa.bmsrc[4][0] = f_ob + SEL1; pa.bmsrc[4][1] = nullptr; pa.bmsrc[4][2] = nullptr;
  int bs = 0;
  for (int m = 0; m < 5; ++m) { pa.bmstart[m] = bs; bs += pa.bmnrg[m] * 4; }
  pa.bmstart[5] = bs;
  pa.nbm = bs;
  pa.lca[0] = f_ka + SEL1; pa.lca[1] = f_va + SEL1;
  pa.lowc = lowext_c;
  int totblk = pa.nwt + pa.nf2bf + 32 + pa.nbm + 256;
  k_prep<<<dim3(totblk), dim3(256), 0, stream>>>(pa);

  // ---- self rms + lows ----
  k_start<<<dim3(256), dim3(256), 0, stream>>>(f_inputs, f_ln1, f_qa, f_ka, f_va, xn, lowext_s);

  // ---- big QKV: self (N=3072, S2) + crossKV (N=2048, S2) ----
  {
    GX g;
    const size_t PS = (size_t)2048 * 3072, PC = (size_t)2048 * 2048;
    g.s[0] = { xn, lowext_s, wt, bmext_s, bqs,            (size_t)3072 * 128, 3072, 24, 0, 9 };
    g.s[1] = { xn, lowext_s, wt, bmext_s, bqs + PS,       (size_t)3072 * 128, 3072, 24, 9, 18 };
    g.s[2] = { encbf, lowext_c, wt + (size_t)5120 * 1024, bmext_c, bqc,      (size_t)2048 * 128, 2048, 16, 0, 9 };
    g.s[3] = { encbf, lowext_c, wt + (size_t)5120 * 1024, bmext_c, bqc + PC, (size_t)2048 * 128, 2048, 16, 9, 18 };
    k_gemmx<<<dim3(24, 16, 4), dim3(256), 0, stream>>>(g);
  }
  k_qkvsum<<<dim3(256, 2), dim3(256), 0, stream>>>(bqs, bqc, qbf, kbf, vtb, kbf2, vtb2);

  k_flash<true, false><<<dim3(8, 64), dim3(256), 0, stream>>>(qbf, nullptr, kbf, vtb, rb, ctxb);

  // ---- self out-proj (K-ext lora_o, S4) ----
  k_lowbf<<<dim3(256), dim3(256), 0, stream>>>(ctxb, f_oa, lowext_o);
  {
    GX g;
    for (int s = 0; s < 4; ++s)
      g.s[s] = { ctxb, lowext_o, wt + (size_t)3072 * 1024, bmext_o, op_s + (size_t)s * PART,
                 (size_t)1024 * 128, 1024, 8, s * 18 / 4, (s + 1) * 18 / 4 };
    k_gemmx<<<dim3(8, 16, 4), dim3(256), 0, stream>>>(g);
  }
  k_addbrms<true><<<dim3(256), dim3(256), 0, stream>>>(op_s, f_inputs, f_ln2, xres, xn,
                                                       f_qa + SEL1, lowext_q);

  // ---- cross-Q (K-ext, S4) ----
  {
    GX g;
    for (int s = 0; s < 4; ++s)
      g.s[s] = { xn, lowext_q, wt + (size_t)4096 * 1024, bmext_q, qp_c + (size_t)s * PART,
                 (size_t)1024 * 128, 1024, 8, s * 18 / 4, (s + 1) * 18 / 4 };
    k_gemmx<<<dim3(8, 16, 4), dim3(256), 0, stream>>>(g);
  }
  k_flash<false, true><<<dim3(8, 64), dim3(256), 0, stream>>>(nullptr, qp_c, kbf2, vtb2, rb, ctxb);

  // ---- cross out-proj (K-ext lora_o sel1, S4) ----
  k_lowbf<<<dim3(256), dim3(256), 0, stream>>>(ctxb, f_oa + SEL1, lowext_o);
  {
    GX g;
    for (int s = 0; s < 4; ++s)
      g.s[s] = { ctxb, lowext_o, wt + (size_t)7168 * 1024, bmext_o2, op_c + (size_t)s * PART,
                 (size_t)1024 * 128, 1024, 8, s * 18 / 4, (s + 1) * 18 / 4 };
    k_gemmx<<<dim3(8, 16, 4), dim3(256), 0, stream>>>(g);
  }
  k_addbrms<false><<<dim3(256), dim3(256), 0, stream>>>(op_c, xres, f_ln3, yres, xn,
                                                        nullptr, nullptr);

  // ---- MLP ----
  k_mlp<<<dim3(32, 16), dim3(512), 0, stream>>>(xn, wc, hbf);
  k_gemm1s<<<dim3(8, 16, 4), dim3(256), 0, stream>>>(hbf, wot, fp, PART, 1024, 4096, 4096, 1024);
  k_sum4<<<dim3(2048), dim3(256), 0, stream>>>(fp, PART, yres, (float*)d_out);
}

// Round 10
// 621.622 us; speedup vs baseline: 1.3195x; 1.0204x over previous
//
#include <hip/hip_runtime.h>
#include <math.h>

// ---------------------------------------------------------------------------
// LoRA T5 decoder layer on MI355X (gfx950).
// B=4, L=ENC=512, D=1024, H=16, HD=64, MLP=4096, R=32.
// R9->R10: k_qkvsum's V scatter (2-byte stores at 1024-B stride, ~32x write
// amplification -> 142 MB WRITE_SIZE, 65 us) split into an LDS-tiled
// transpose k_vtrans2 (full-line coalesced stores, reads the two fp32
// partials directly). k_qkvsum keeps only the flat q/k sections.
// Everything else unchanged from R9 (634 us, replay-stable).
// ---------------------------------------------------------------------------

#define DEV __device__ __forceinline__

typedef __bf16 bf16x8 __attribute__((ext_vector_type(8)));
typedef float floatx4 __attribute__((ext_vector_type(4)));

typedef __attribute__((address_space(1))) void* gas_ptr;
typedef __attribute__((address_space(3))) void* las_ptr;

DEV unsigned short f2bf(float f) {
  union { float f; unsigned int u; } v; v.f = f;
  unsigned int r = v.u + 0x7fffu + ((v.u >> 16) & 1u);
  return (unsigned short)(r >> 16);
}
DEV float bf2f(unsigned short u) {
  union { unsigned int u; float f; } v; v.u = ((unsigned int)u) << 16;
  return v.f;
}

#define GLOAD_LDS16(g, l) __builtin_amdgcn_global_load_lds((gas_ptr)(g), (las_ptr)(l), 16, 0, 0)

// Stage nrows x 64 bf16 (128 B rows) from global (row stride ldbytes) into LDS.
template<int NW>
DEV void stage_tile(const char* gbase, char* lds, int nrows, int ldbytes, int wave, int lane) {
  int nchunks = nrows >> 3;
  for (int c = wave; c < nchunks; c += NW) {
    int row  = (c << 3) + (lane >> 3);
    int colb = (lane & 7) << 4;
    GLOAD_LDS16(gbase + (size_t)row * ldbytes + colb, lds + (c << 10));
  }
}

// Stage nrows x 128 bf16 (256 B rows) from global (row stride ldbytes) into LDS.
template<int NW>
DEV void stage_tile256(const char* gbase, char* lds, int nrows, int ldbytes, int wave, int lane) {
  int nchunks = nrows >> 2;
  for (int c = wave; c < nchunks; c += NW) {
    int row  = (c << 2) + (lane >> 4);
    int colb = (lane & 15) << 4;
    GLOAD_LDS16(gbase + (size_t)row * ldbytes + colb, lds + (c << 10));
  }
}

// ---------------- generic bf16 GEMM core (fp32 out), 128x128 tile ----------
template<int WM, int WN>
DEV void gemm_core(const unsigned short* A, const unsigned short* Bt, float* C,
                   int K, int lda, int ldb, int ldc, int m0, int n0,
                   char* ldsA, char* ldsB) {
  constexpr int NW = WM * WN;
  const int tid  = threadIdx.x;
  const int lane = tid & 63;
  const int wave = tid >> 6;
  const int wm   = wave % WM;
  const int wn   = wave / WM;
  const int quad = lane >> 4;
  const int l15  = lane & 15;

  floatx4 acc[4][4];
#pragma unroll
  for (int i = 0; i < 4; ++i)
#pragma unroll
    for (int j = 0; j < 4; ++j) acc[i][j] = (floatx4){0.f, 0.f, 0.f, 0.f};

  const char* gA = (const char*)(A + (size_t)m0 * lda);
  const char* gB = (const char*)(Bt + (size_t)n0 * ldb);

  for (int k0 = 0; k0 < K; k0 += 64) {
    stage_tile<NW>(gA + (size_t)k0 * 2, ldsA, WM * 64, lda * 2, wave, lane);
    stage_tile<NW>(gB + (size_t)k0 * 2, ldsB, WN * 64, ldb * 2, wave, lane);
    __syncthreads();
#pragma unroll
    for (int kk = 0; kk < 64; kk += 32) {
      bf16x8 af[4], bv[4];
      const char* baseA = ldsA + (size_t)(wm * 64 + l15) * 128 + (kk + quad * 8) * 2;
      const char* baseB = ldsB + (size_t)(wn * 64 + l15) * 128 + (kk + quad * 8) * 2;
#pragma unroll
      for (int mi = 0; mi < 4; ++mi) af[mi] = *(const bf16x8*)(baseA + mi * 2048);
#pragma unroll
      for (int ni = 0; ni < 4; ++ni) bv[ni] = *(const bf16x8*)(baseB + ni * 2048);
#pragma unroll
      for (int mi = 0; mi < 4; ++mi)
#pragma unroll
        for (int ni = 0; ni < 4; ++ni)
          acc[mi][ni] = __builtin_amdgcn_mfma_f32_16x16x32_bf16(af[mi], bv[ni], acc[mi][ni], 0, 0, 0);
    }
    __syncthreads();
  }

#pragma unroll
  for (int mi = 0; mi < 4; ++mi) {
#pragma unroll
    for (int r = 0; r < 4; ++r) {
      int row = m0 + wm * 64 + mi * 16 + quad * 4 + r;
#pragma unroll
      for (int ni = 0; ni < 4; ++ni) {
        int col = n0 + wn * 64 + ni * 16 + l15;
        C[(size_t)row * ldc + col] = acc[mi][ni][r];
      }
    }
  }
}

__global__ __launch_bounds__(256) void k_gemm1s(const unsigned short* A, const unsigned short* Bt,
                                                float* Cpart, size_t pstride,
                                                int Kchunk, int lda, int ldb, int ldc) {
  __shared__ char lds[32768];
  int s = blockIdx.z;
  size_t koff = (size_t)s * Kchunk;
  gemm_core<2, 2>(A + koff, Bt + koff, Cpart + (size_t)s * pstride,
                  Kchunk, lda, ldb, ldc,
                  blockIdx.y * 128, blockIdx.x * 128, lds, lds + 16384);
}

// ---------------- K-extended GEMM: C = [A0|Aext] @ [B0|Bext(b)]^T ----------
struct GXSlice {
  const unsigned short* A0;
  const unsigned short* Aext;
  const unsigned short* B0;
  const unsigned short* Bext;
  float* C;
  size_t bextb;            // per-b element stride of Bext (= N*128)
  int ldc, nxa, it0, it1;
};
struct GX { GXSlice s[4]; };

__global__ __launch_bounds__(256) void k_gemmx(GX g) {
  __shared__ char lds[32768];
  char* ldsA = lds;
  char* ldsB = lds + 16384;
  GXSlice sl = g.s[blockIdx.z];
  if ((int)blockIdx.x >= sl.nxa) return;
  const int m0 = blockIdx.y * 128, n0 = blockIdx.x * 128;
  const int b = m0 >> 9;
  const int tid = threadIdx.x, lane = tid & 63, wave = tid >> 6;
  const int wm = wave & 1, wn = wave >> 1;
  const int quad = lane >> 4, l15 = lane & 15;

  floatx4 acc[4][4];
#pragma unroll
  for (int i = 0; i < 4; ++i)
#pragma unroll
    for (int j = 0; j < 4; ++j) acc[i][j] = (floatx4){0.f, 0.f, 0.f, 0.f};

  for (int it = sl.it0; it < sl.it1; ++it) {
    if (it < 16) {
      stage_tile<4>((const char*)sl.A0 + (size_t)m0 * 2048 + it * 128, ldsA, 128, 2048, wave, lane);
      stage_tile<4>((const char*)sl.B0 + (size_t)n0 * 2048 + it * 128, ldsB, 128, 2048, wave, lane);
    } else {
      int eb = (it - 16) * 128;
      stage_tile<4>((const char*)sl.Aext + (size_t)m0 * 256 + eb, ldsA, 128, 256, wave, lane);
      stage_tile<4>((const char*)(sl.Bext + (size_t)b * sl.bextb) + (size_t)n0 * 256 + eb,
                    ldsB, 128, 256, wave, lane);
    }
    __syncthreads();
#pragma unroll
    for (int kk = 0; kk < 64; kk += 32) {
      bf16x8 af[4], bv[4];
      const char* baseA = ldsA + (size_t)(wm * 64 + l15) * 128 + (kk + quad * 8) * 2;
      const char* baseB = ldsB + (size_t)(wn * 64 + l15) * 128 + (kk + quad * 8) * 2;
#pragma unroll
      for (int mi = 0; mi < 4; ++mi) af[mi] = *(const bf16x8*)(baseA + mi * 2048);
#pragma unroll
      for (int ni = 0; ni < 4; ++ni) bv[ni] = *(const bf16x8*)(baseB + ni * 2048);
#pragma unroll
      for (int mi = 0; mi < 4; ++mi)
#pragma unroll
        for (int ni = 0; ni < 4; ++ni)
          acc[mi][ni] = __builtin_amdgcn_mfma_f32_16x16x32_bf16(af[mi], bv[ni], acc[mi][ni], 0, 0, 0);
    }
    __syncthreads();
  }

#pragma unroll
  for (int mi = 0; mi < 4; ++mi) {
#pragma unroll
    for (int r = 0; r < 4; ++r) {
      int row = m0 + wm * 64 + mi * 16 + quad * 4 + r;
#pragma unroll
      for (int ni = 0; ni < 4; ++ni) {
        int col = n0 + wn * 64 + ni * 16 + l15;
        sl.C[(size_t)row * sl.ldc + col] = acc[mi][ni][r];
      }
    }
  }
}

// ---------------- QKV sum: splitK(2) sum + bf16 cast, q/k sections only ---
// z=0: self [2048][3072] secs 0,1 -> qbf,kbf flat.
// z=1: cross [2048][2048] sec 0 -> kbf2 flat.
__global__ __launch_bounds__(256) void k_qkvsum(const float* bqs, const float* bqc,
                                                unsigned short* qbf, unsigned short* kbf,
                                                unsigned short* kbf2) {
  const size_t PS = (size_t)2048 * 3072, PC = (size_t)2048 * 2048;
  int t = threadIdx.x;
  int row0 = blockIdx.x * 8;
  int zc = blockIdx.y;
  for (int j = 0; j < 8; ++j) {
    int row = row0 + j;
    int nsec = zc ? 1 : 2;
    for (int sec = 0; sec < nsec; ++sec) {
      const float* base = zc ? (bqc + (size_t)row * 2048 + sec * 1024)
                             : (bqs + (size_t)row * 3072 + sec * 1024);
      float4 a = ((const float4*)base)[t];
      float4 c = ((const float4*)(base + (zc ? PC : PS)))[t];
      float4 s; s.x = a.x + c.x; s.y = a.y + c.y; s.z = a.z + c.z; s.w = a.w + c.w;
      ushort4 o; o.x = f2bf(s.x); o.y = f2bf(s.y); o.z = f2bf(s.z); o.w = f2bf(s.w);
      unsigned short* dst = zc ? kbf2 : (sec == 0 ? qbf : kbf);
      ((ushort4*)(dst + (size_t)row * 1024))[t] = o;
    }
  }
}

// ---------------- V transpose from fp32 partials (LDS-tiled) --------------
// block = (ktile, z, which): sum the 2 split-K partials of the V section and
// write vtb[z][d][k] with full-line coalesced 32-B stores.
__global__ __launch_bounds__(256) void k_vtrans2(const float* bqs, const float* bqc,
                                                 unsigned short* vtb, unsigned short* vtb2) {
  __shared__ float tl[64][65];
  int which = blockIdx.z;                 // 0 = self, 1 = cross
  int z = blockIdx.y, b = z >> 4, h = z & 15;
  int k0 = blockIdx.x * 64;
  int ld = which ? 2048 : 3072;
  int voff = which ? 1024 : 2048;
  const float* src = which ? bqc : bqs;
  size_t PARTW = (size_t)2048 * ld;
  unsigned short* dst = which ? vtb2 : vtb;
  int t = threadIdx.x;
  {
    int kr = t >> 2, c0 = (t & 3) * 16;
    const float* p = src + (size_t)(b * 512 + k0 + kr) * ld + voff + h * 64 + c0;
#pragma unroll
    for (int i = 0; i < 4; ++i) {
      float4 v0 = *(const float4*)(p + i * 4);
      float4 v1 = *(const float4*)(p + PARTW + i * 4);
      tl[kr][c0 + i * 4 + 0] = v0.x + v1.x;
      tl[kr][c0 + i * 4 + 1] = v0.y + v1.y;
      tl[kr][c0 + i * 4 + 2] = v0.z + v1.z;
      tl[kr][c0 + i * 4 + 3] = v0.w + v1.w;
    }
  }
  __syncthreads();
  {
    int dw = t >> 2, kc = (t & 3) * 16;
    union { unsigned short us[16]; uint4 q[2]; } pk;
#pragma unroll
    for (int j = 0; j < 16; ++j) pk.us[j] = f2bf(tl[kc + j][dw]);
    uint4* dp = (uint4*)(dst + ((size_t)z * 64 + dw) * 512 + k0 + kc);
    dp[0] = pk.q[0]; dp[1] = pk.q[1];
  }
}

// ---------------- flash attention ----------------
template<bool CAUSAL, bool QSUM>
__global__ __launch_bounds__(256) void k_flash(const unsigned short* qmat, const float* qparts,
                                               const unsigned short* kmat, const unsigned short* vt,
                                               const float* rb, unsigned short* ctxb) {
  __shared__ char ldsQ[8192];    // [64 q][64 d]
  __shared__ char ldsK[16384];   // [128 k][64 d]
  __shared__ char ldsV[16384];   // [64 d][128 k]
  __shared__ char ldsP[16384];   // [64 q][128 k]
  __shared__ float lrb[512];

  const size_t PART = (size_t)2048 * 1024;
  const int z = blockIdx.y, b = z >> 4, h = z & 15;
  const int q0 = blockIdx.x * 64;
  const int tid = threadIdx.x, lane = tid & 63, wave = tid >> 6;
  const int quad = lane >> 4, l15 = lane & 15;

  const unsigned short* K = kmat + (size_t)b * 512 * 1024 + h * 64;
  const unsigned short* V = vt + (size_t)z * 64 * 512;

  if (QSUM) {
#pragma unroll
    for (int rr = 0; rr < 4; ++rr) {
      int row = rr * 16 + (tid >> 4);
      int c4 = tid & 15;
      const float* src = qparts + (size_t)(q0 + row) * 1024 + h * 64 + c4 * 4;
      float4 s0 = *(const float4*)src;
      float4 s1 = *(const float4*)(src + PART);
      float4 s2 = *(const float4*)(src + 2 * PART);
      float4 s3 = *(const float4*)(src + 3 * PART);
      ushort4 o;
      o.x = f2bf(s0.x + s1.x + s2.x + s3.x);
      o.y = f2bf(s0.y + s1.y + s2.y + s3.y);
      o.z = f2bf(s0.z + s1.z + s2.z + s3.z);
      o.w = f2bf(s0.w + s1.w + s2.w + s3.w);
      *(ushort4*)(ldsQ + (size_t)row * 128 + c4 * 8) = o;
    }
  } else {
    const unsigned short* Q = qmat + (size_t)b * 512 * 1024 + h * 64;
    stage_tile<4>((const char*)(Q + (size_t)q0 * 1024), ldsQ, 64, 2048, wave, lane);
  }
  if (CAUSAL)
    for (int i = tid; i < 512; i += 256) lrb[i] = rb[h * 512 + i];

  float m_run[4], l_run[4];
  floatx4 oacc[4];
#pragma unroll
  for (int r = 0; r < 4; ++r) { m_run[r] = -1e30f; l_run[r] = 0.f; }
#pragma unroll
  for (int ni = 0; ni < 4; ++ni) oacc[ni] = (floatx4){0.f, 0.f, 0.f, 0.f};

  const int ktend = CAUSAL ? (blockIdx.x / 2 + 1) : 4;
  for (int kt = 0; kt < ktend; ++kt) {
    __syncthreads();
    stage_tile<4>((const char*)(K + (size_t)kt * 128 * 1024), ldsK, 128, 2048, wave, lane);
    stage_tile256<4>((const char*)(V + kt * 128), ldsV, 64, 1024, wave, lane);
    __syncthreads();

    floatx4 sacc[8];
#pragma unroll
    for (int ct = 0; ct < 8; ++ct) sacc[ct] = (floatx4){0.f, 0.f, 0.f, 0.f};
    const char* aBase = ldsQ + (size_t)(wave * 16 + l15) * 128 + quad * 16;
#pragma unroll
    for (int kd = 0; kd < 2; ++kd) {
      bf16x8 af = *(const bf16x8*)(aBase + kd * 64);
#pragma unroll
      for (int ct = 0; ct < 8; ++ct) {
        bf16x8 bf = *(const bf16x8*)(ldsK + (size_t)(ct * 16 + l15) * 128 + quad * 16 + kd * 64);
        sacc[ct] = __builtin_amdgcn_mfma_f32_16x16x32_bf16(af, bf, sacc[ct], 0, 0, 0);
      }
    }

    float sv[8][4];
#pragma unroll
    for (int ct = 0; ct < 8; ++ct)
#pragma unroll
      for (int r = 0; r < 4; ++r) {
        float v = sacc[ct][r] * 0.125f;
        if (CAUSAL) {
          int qq = q0 + wave * 16 + quad * 4 + r;
          int kk = kt * 128 + ct * 16 + l15;
          v = (kk <= qq) ? v + lrb[qq - kk] : -1e30f;
        }
        sv[ct][r] = v;
      }

    float mx[4];
#pragma unroll
    for (int r = 0; r < 4; ++r) {
      mx[r] = sv[0][r];
#pragma unroll
      for (int ct = 1; ct < 8; ++ct) mx[r] = fmaxf(mx[r], sv[ct][r]);
    }
#pragma unroll
    for (int o = 1; o < 16; o <<= 1)
#pragma unroll
      for (int r = 0; r < 4; ++r) mx[r] = fmaxf(mx[r], __shfl_xor(mx[r], o));

    float alpha[4], rs[4];
#pragma unroll
    for (int r = 0; r < 4; ++r) {
      float mn = fmaxf(m_run[r], mx[r]);
      alpha[r] = __expf(m_run[r] - mn);
      m_run[r] = mn;
      rs[r] = 0.f;
    }
#pragma unroll
    for (int ct = 0; ct < 8; ++ct)
#pragma unroll
      for (int r = 0; r < 4; ++r) {
        float p = __expf(sv[ct][r] - m_run[r]);
        sv[ct][r] = p;
        rs[r] += p;
      }
#pragma unroll
    for (int o = 1; o < 16; o <<= 1)
#pragma unroll
      for (int r = 0; r < 4; ++r) rs[r] += __shfl_xor(rs[r], o);
#pragma unroll
    for (int r = 0; r < 4; ++r) l_run[r] = l_run[r] * alpha[r] + rs[r];
#pragma unroll
    for (int ni = 0; ni < 4; ++ni)
#pragma unroll
      for (int r = 0; r < 4; ++r) oacc[ni][r] *= alpha[r];

#pragma unroll
    for (int ct = 0; ct < 8; ++ct)
#pragma unroll
      for (int r = 0; r < 4; ++r)
        *(unsigned short*)(ldsP + (size_t)(wave * 16 + quad * 4 + r) * 256 + (ct * 16 + l15) * 2)
            = f2bf(sv[ct][r]);
    __syncthreads();

    const char* pBase = ldsP + (size_t)(wave * 16 + l15) * 256 + quad * 16;
#pragma unroll
    for (int kk = 0; kk < 4; ++kk) {
      bf16x8 pf = *(const bf16x8*)(pBase + kk * 64);
#pragma unroll
      for (int ni = 0; ni < 4; ++ni) {
        bf16x8 vf8 = *(const bf16x8*)(ldsV + (size_t)(ni * 16 + l15) * 256 + quad * 16 + kk * 64);
        oacc[ni] = __builtin_amdgcn_mfma_f32_16x16x32_bf16(pf, vf8, oacc[ni], 0, 0, 0);
      }
    }
  }

#pragma unroll
  for (int r = 0; r < 4; ++r) {
    int q = q0 + wave * 16 + quad * 4 + r;
    float inv = 1.0f / l_run[r];
    unsigned short* dst = ctxb + ((size_t)b * 512 + q) * 1024 + h * 64;
#pragma unroll
    for (int ni = 0; ni < 4; ++ni)
      dst[ni * 16 + l15] = f2bf(oacc[ni][r] * inv);
  }
}

// ---------------- fused MLP ----------------
__global__ __launch_bounds__(512) void k_mlp(const unsigned short* A, const unsigned short* Wc,
                                             unsigned short* hbf) {
  __shared__ char lds[49152];
  char* ldsA = lds;
  char* ldsB = lds + 16384;
  const int m0 = blockIdx.y * 128;
  const int n0 = blockIdx.x * 128;
  const int tid = threadIdx.x, lane = tid & 63, wave = tid >> 6;
  const int half = wave >> 2, wl = wave & 3;
  const int wm = wl & 1, wn = wl >> 1;
  const int quad = lane >> 4, l15 = lane & 15;

  floatx4 acc[4][4];
#pragma unroll
  for (int i = 0; i < 4; ++i)
#pragma unroll
    for (int j = 0; j < 4; ++j) acc[i][j] = (floatx4){0.f, 0.f, 0.f, 0.f};

  const char* gA = (const char*)(A + (size_t)m0 * 1024);
  const char* gB = (const char*)(Wc + (size_t)blockIdx.x * 256 * 1024);

  for (int k0 = 0; k0 < 1024; k0 += 64) {
    stage_tile<8>(gA + (size_t)k0 * 2, ldsA, 128, 2048, wave, lane);
    stage_tile<8>(gB + (size_t)k0 * 2, ldsB, 256, 2048, wave, lane);
    __syncthreads();
#pragma unroll
    for (int kk = 0; kk < 64; kk += 32) {
      bf16x8 af[4], bv[4];
      const char* baseA = ldsA + (size_t)(wm * 64 + l15) * 128 + (kk + quad * 8) * 2;
      const char* baseB = ldsB + (size_t)(half * 128 + wn * 64 + l15) * 128 + (kk + quad * 8) * 2;
#pragma unroll
      for (int mi = 0; mi < 4; ++mi) af[mi] = *(const bf16x8*)(baseA + mi * 2048);
#pragma unroll
      for (int ni = 0; ni < 4; ++ni) bv[ni] = *(const bf16x8*)(baseB + ni * 2048);
#pragma unroll
      for (int mi = 0; mi < 4; ++mi)
#pragma unroll
        for (int ni = 0; ni < 4; ++ni)
          acc[mi][ni] = __builtin_amdgcn_mfma_f32_16x16x32_bf16(af[mi], bv[ni], acc[mi][ni], 0, 0, 0);
    }
    __syncthreads();
  }

  if (half == 1) {
#pragma unroll
    for (int mi = 0; mi < 4; ++mi)
#pragma unroll
      for (int r = 0; r < 4; ++r) {
        int row = wm * 64 + mi * 16 + quad * 4 + r;
#pragma unroll
        for (int ni = 0; ni < 4; ++ni) {
          int col = wn * 64 + ni * 16 + l15;
          *(unsigned short*)(ldsB + (size_t)row * 256 + col * 2) = f2bf(acc[mi][ni][r]);
        }
      }
  }
  __syncthreads();
  if (half == 0) {
#pragma unroll
    for (int mi = 0; mi < 4; ++mi)
#pragma unroll
      for (int r = 0; r < 4; ++r) {
        int row = wm * 64 + mi * 16 + quad * 4 + r;
#pragma unroll
        for (int ni = 0; ni < 4; ++ni) {
          int col = wn * 64 + ni * 16 + l15;
          float h1 = bf2f(*(const unsigned short*)(ldsB + (size_t)row * 256 + col * 2));
          float g = acc[mi][ni][r];
          float v = 0.5f * g * (1.0f + erff(g * 0.70710678f)) * h1;
          hbf[(size_t)(m0 + row) * 4096 + n0 + col] = f2bf(v);
        }
      }
  }
}

// ---------------- prep: fast transpose + encbf + relbias + bmext + lowc ---
struct PrepArgs {
  const float* src[11];
  unsigned short* dst[11];
  int K[11], N[11], mode[11];
  int tstart[12];
  const float* encoded;
  unsigned short* encbf;
  const float* table;
  float* rb;
  unsigned short* bmdst[5];
  const float* bmsrc[5][3];
  int bmnrg[5];
  int bmstart[6];
  const float* lca[2];
  unsigned short* lowc;
  int nwt, nf2bf, nbm;
};
__global__ __launch_bounds__(256) void k_prep(PrepArgs a) {
  __shared__ char shm[49152];
  int bid = blockIdx.x;
  int t = threadIdx.x;
  if (bid < a.nwt) {
    float (*tl)[65] = (float(*)[65])shm;   // 16.6 KB
    int z = 0;
    while (z < 10 && bid >= a.tstart[z + 1]) ++z;
    int tile = bid - a.tstart[z];
    int N = a.N[z], K = a.K[z], mode = a.mode[z];
    int ntn = N >> 6;
    int tn = tile % ntn, tk = tile / ntn;
    const float* src = a.src[z] + (size_t)(tk * 64) * N + tn * 64;
    unsigned short* dst = a.dst[z];
    {
      int rq = t >> 4, c4 = (t & 15) * 4;
#pragma unroll
      for (int i = 0; i < 4; ++i) {
        int r = rq + i * 16;
        float4 v = *(const float4*)(src + (size_t)r * N + c4);
        tl[r][c4] = v.x; tl[r][c4 + 1] = v.y; tl[r][c4 + 2] = v.z; tl[r][c4 + 3] = v.w;
      }
    }
    __syncthreads();
    {
      int nl = t >> 2, kseg = (t & 3) * 16;
      int n = tn * 64 + nl;
      int orow = (mode == 0) ? n : ((n >> 7) * 256 + ((mode == 2) ? 128 : 0) + (n & 127));
      union { unsigned short us[16]; uint4 q[2]; } pk;
#pragma unroll
      for (int j = 0; j < 16; ++j) pk.us[j] = f2bf(tl[kseg + j][nl]);
      uint4* dp = (uint4*)(dst + (size_t)orow * K + tk * 64 + kseg);
      dp[0] = pk.q[0]; dp[1] = pk.q[1];
    }
    return;
  }
  bid -= a.nwt;
  if (bid < a.nf2bf) {
    int i = bid * 256 + t;
    float4 v = ((const float4*)a.encoded)[i];
    ushort4 o;
    o.x = f2bf(v.x); o.y = f2bf(v.y); o.z = f2bf(v.z); o.w = f2bf(v.w);
    ((ushort4*)a.encbf)[i] = o;
    return;
  }
  bid -= a.nf2bf;
  if (bid < 32) {
    int i = bid * 256 + t;
    if (i < 16 * 512) {
      int h = i >> 9, d = i & 511;
      int bucket;
      if (d < 16) bucket = d;
      else {
        int lb = 16 + (int)(logf((float)d / 16.0f) / logf(8.0f) * 16.0f);
        bucket = lb < 31 ? lb : 31;
      }
      a.rb[i] = a.table[bucket * 16 + h];
    }
    return;
  }
  bid -= 32;
  if (bid < a.nbm) {
    // bmext fill: Bext[b][row=n0+n][c] = (c>>5==sec) ? b_sec[b][c&31][(n0&1023)+n] : 0
    int m = 0;
    while (m < 4 && bid >= a.bmstart[m + 1]) ++m;
    int idx = bid - a.bmstart[m];
    int nrg = a.bmnrg[m];
    int b = idx / nrg, rg = idx % nrg;
    int n0 = rg * 128;
    int sec = n0 >> 10;
    const float* src = a.bmsrc[m][sec] + (size_t)b * 65536;
    unsigned short* dst = a.bmdst[m] + ((size_t)b * nrg * 128 + n0) * 128;
    int n = t & 127, coff = (t >> 7) * 64;
    int ncol = (n0 & 1023) + n;
    unsigned short* drow = dst + (size_t)n * 128 + coff;
    for (int c4 = 0; c4 < 16; ++c4) {
      ushort4 o;
#pragma unroll
      for (int e = 0; e < 4; ++e) {
        int c = coff + c4 * 4 + e;
        float v = ((c >> 5) == sec) ? src[(size_t)(c & 31) * 1024 + ncol] : 0.f;
        ((unsigned short*)&o)[e] = f2bf(v);
      }
      *(ushort4*)(drow + c4 * 4) = o;
    }
    return;
  }
  bid -= a.nbm;
  {
    // cross-KV lows from fp32 encoded: 8 rows/block
    float* rowsF = (float*)shm;                       // [8][1024] = 32 KB
    float* pacc = (float*)(shm + 32768);              // [2][8][8][32] = 16 KB
    int row0 = bid * 8;
    int b = row0 >> 9;
    for (int j = 0; j < 8; ++j)
      ((float4*)(rowsF + j * 1024))[t] = ((const float4*)(a.encoded + (size_t)(row0 + j) * 1024))[t];
    __syncthreads();
    int r = t & 31, g = t >> 5;
    float acc[2][8];
#pragma unroll
    for (int p = 0; p < 2; ++p)
#pragma unroll
      for (int j = 0; j < 8; ++j) acc[p][j] = 0.f;
    const float* a0 = a.lca[0] + (size_t)b * 65536;
    const float* a1 = a.lca[1] + (size_t)b * 65536;
    for (int i = 0; i < 128; ++i) {
      int k = g * 128 + i;
      float ak = a0[(size_t)k * 32 + r];
      float av = a1[(size_t)k * 32 + r];
#pragma unroll
      for (int j = 0; j < 8; ++j) {
        float x = rowsF[j * 1024 + k];
        acc[0][j] += x * ak;
        acc[1][j] += x * av;
      }
    }
#pragma unroll
    for (int p = 0; p < 2; ++p)
#pragma unroll
      for (int j = 0; j < 8; ++j)
        pacc[((p * 8 + j) * 8 + g) * 32 + r] = acc[p][j];
    __syncthreads();
    for (int j = 0; j < 8; ++j) {
      if (t < 64) {
        int p = t >> 5, r2 = t & 31;
        float s = 0.f;
        for (int gg = 0; gg < 8; ++gg) s += pacc[((p * 8 + j) * 8 + gg) * 32 + r2];
        a.lowc[(size_t)(row0 + j) * 128 + p * 32 + r2] = f2bf(s);
      } else if (t < 128) {
        a.lowc[(size_t)(row0 + j) * 128 + t] = 0;
      }
    }
  }
}

// ---------------- k_start: rmsnorm + self q/k/v lows ----------------------
__global__ __launch_bounds__(256) void k_start(const float* x, const float* sc,
                                               const float* qa, const float* ka, const float* va,
                                               unsigned short* xn, unsigned short* lowext) {
  __shared__ unsigned short lrows[8][1024];   // 16 KB
  __shared__ float pacc[3 * 8 * 8 * 32];      // 24 KB
  __shared__ float red[4];
  int t = threadIdx.x;
  int row0 = blockIdx.x * 8;
  int b = row0 >> 9;
  float4 s4 = ((const float4*)sc)[t];
  for (int j = 0; j < 8; ++j) {
    int row = row0 + j;
    float4 v = ((const float4*)(x + (size_t)row * 1024))[t];
    float ss = v.x * v.x + v.y * v.y + v.z * v.z + v.w * v.w;
    for (int o = 32; o; o >>= 1) ss += __shfl_down(ss, o);
    if ((t & 63) == 0) red[t >> 6] = ss;
    __syncthreads();
    float tot = red[0] + red[1] + red[2] + red[3];
    float rs = rsqrtf(tot * (1.0f / 1024.0f) + 1e-6f);
    ushort4 o;
    o.x = f2bf(v.x * rs * s4.x); o.y = f2bf(v.y * rs * s4.y);
    o.z = f2bf(v.z * rs * s4.z); o.w = f2bf(v.w * rs * s4.w);
    ((ushort4*)(xn + (size_t)row * 1024))[t] = o;
    *(ushort4*)(&lrows[j][t * 4]) = o;
    __syncthreads();
  }
  int r = t & 31, g = t >> 5;
  float acc[3][8];
#pragma unroll
  for (int p = 0; p < 3; ++p)
#pragma unroll
    for (int j = 0; j < 8; ++j) acc[p][j] = 0.f;
  const float* aq = qa + (size_t)b * 65536;
  const float* ak = ka + (size_t)b * 65536;
  const float* av = va + (size_t)b * 65536;
  for (int i = 0; i < 128; ++i) {
    int k = g * 128 + i;
    float a0 = aq[(size_t)k * 32 + r];
    float a1 = ak[(size_t)k * 32 + r];
    float a2 = av[(size_t)k * 32 + r];
#pragma unroll
    for (int j = 0; j < 8; ++j) {
      float xv = bf2f(lrows[j][k]);
      acc[0][j] += xv * a0;
      acc[1][j] += xv * a1;
      acc[2][j] += xv * a2;
    }
  }
#pragma unroll
  for (int p = 0; p < 3; ++p)
#pragma unroll
    for (int j = 0; j < 8; ++j)
      pacc[((p * 8 + j) * 8 + g) * 32 + r] = acc[p][j];
  __syncthreads();
  for (int j = 0; j < 8; ++j) {
    if (t < 96) {
      int p = t >> 5, r2 = t & 31;
      float s = 0.f;
      for (int gg = 0; gg < 8; ++gg) s += pacc[((p * 8 + j) * 8 + gg) * 32 + r2];
      lowext[(size_t)(row0 + j) * 128 + p * 32 + r2] = f2bf(s);
    } else if (t < 128) {
      lowext[(size_t)(row0 + j) * 128 + t] = 0;
    }
  }
}

// ---------------- k_addbrms: 4-partial sum + resid + rms (+ next low) -----
template<bool LOW>
__global__ __launch_bounds__(256) void k_addbrms(const float* parts, const float* resid,
                                                 const float* sc, float* resout,
                                                 unsigned short* xn,
                                                 const float* aP, unsigned short* lowext) {
  __shared__ unsigned short lrows[8][1024];
  __shared__ float pacc[8 * 8 * 32];
  __shared__ float red[4];
  const size_t PART = (size_t)2048 * 1024;
  int t = threadIdx.x;
  int row0 = blockIdx.x * 8;
  int b = row0 >> 9;
  float4 s4 = ((const float4*)sc)[t];
  for (int j = 0; j < 8; ++j) {
    int row = row0 + j;
    const float* p0 = parts + (size_t)row * 1024;
    float4 v = ((const float4*)p0)[t];
    float4 v1 = ((const float4*)(p0 + PART))[t];
    float4 v2 = ((const float4*)(p0 + 2 * PART))[t];
    float4 v3 = ((const float4*)(p0 + 3 * PART))[t];
    float4 rv = ((const float4*)(resid + (size_t)row * 1024))[t];
    float4 s;
    s.x = v.x + v1.x + v2.x + v3.x + rv.x;
    s.y = v.y + v1.y + v2.y + v3.y + rv.y;
    s.z = v.z + v1.z + v2.z + v3.z + rv.z;
    s.w = v.w + v1.w + v2.w + v3.w + rv.w;
    ((float4*)(resout + (size_t)row * 1024))[t] = s;
    float ss = s.x * s.x + s.y * s.y + s.z * s.z + s.w * s.w;
    for (int o = 32; o; o >>= 1) ss += __shfl_down(ss, o);
    if ((t & 63) == 0) red[t >> 6] = ss;
    __syncthreads();
    float tot = red[0] + red[1] + red[2] + red[3];
    float rs = rsqrtf(tot * (1.0f / 1024.0f) + 1e-6f);
    ushort4 o;
    o.x = f2bf(s.x * rs * s4.x); o.y = f2bf(s.y * rs * s4.y);
    o.z = f2bf(s.z * rs * s4.z); o.w = f2bf(s.w * rs * s4.w);
    ((ushort4*)(xn + (size_t)row * 1024))[t] = o;
    if (LOW) *(ushort4*)(&lrows[j][t * 4]) = o;
    __syncthreads();
  }
  if (LOW) {
    int r = t & 31, g = t >> 5;
    float acc[8];
#pragma unroll
    for (int j = 0; j < 8; ++j) acc[j] = 0.f;
    const float* ap = aP + (size_t)b * 65536;
    for (int i = 0; i < 128; ++i) {
      int k = g * 128 + i;
      float a0 = ap[(size_t)k * 32 + r];
#pragma unroll
      for (int j = 0; j < 8; ++j) acc[j] += bf2f(lrows[j][k]) * a0;
    }
#pragma unroll
    for (int j = 0; j < 8; ++j) pacc[(j * 8 + g) * 32 + r] = acc[j];
    __syncthreads();
    for (int j = 0; j < 8; ++j) {
      if (t < 32) {
        float s = 0.f;
        for (int gg = 0; gg < 8; ++gg) s += pacc[(j * 8 + gg) * 32 + t];
        lowext[(size_t)(row0 + j) * 128 + t] = f2bf(s);
      } else if (t < 128) {
        lowext[(size_t)(row0 + j) * 128 + t] = 0;
      }
    }
  }
}

// ---------------- low for out-proj (ctx bf16 -> lowext bf16) --------------
__global__ __launch_bounds__(256) void k_lowbf(const unsigned short* x, const float* a,
                                               unsigned short* lowext) {
  int row0 = blockIdx.x * 8;
  int b = row0 >> 9;
  int t = threadIdx.x, r = t & 31, j = t >> 5;
  int row = row0 + j;
  const bf16x8* xv = (const bf16x8*)(x + (size_t)row * 1024);
  const float* ap = a + (size_t)b * 65536;
  float s = 0.f;
  for (int kb = 0; kb < 128; ++kb) {
    bf16x8 v = xv[kb];
#pragma unroll
    for (int u = 0; u < 8; ++u)
      s += (float)v[u] * ap[(size_t)(kb * 8 + u) * 32 + r];
  }
  lowext[(size_t)row * 128 + r] = f2bf(s);
  lowext[(size_t)row * 128 + 32 + r] = 0;
  lowext[(size_t)row * 128 + 64 + r] = 0;
  lowext[(size_t)row * 128 + 96 + r] = 0;
}

// ---------------- final sum ----------------
__global__ void k_sum4(const float* p, size_t pstride, const float* resid, float* out) {
  int i = blockIdx.x * 256 + threadIdx.x;
  float4 a = ((const float4*)p)[i];
  float4 b = ((const float4*)(p + pstride))[i];
  float4 c = ((const float4*)(p + 2 * pstride))[i];
  float4 d = ((const float4*)(p + 3 * pstride))[i];
  float4 r = ((const float4*)resid)[i];
  float4 o;
  o.x = a.x + b.x + c.x + d.x + r.x;
  o.y = a.y + b.y + c.y + d.y + r.y;
  o.z = a.z + b.z + c.z + d.z + r.z;
  o.w = a.w + b.w + c.w + d.w + r.w;
  ((float4*)out)[i] = o;
}

// ---------------------------------------------------------------------------

extern "C" void kernel_launch(void* const* d_in, const int* in_sizes, int n_in,
                              void* d_out, int out_size, void* d_ws, size_t ws_size,
                              hipStream_t stream) {
  const float* f_inputs  = (const float*)d_in[0];
  const float* f_encoded = (const float*)d_in[1];
  const float* f_qa = (const float*)d_in[2];
  const float* f_qb = (const float*)d_in[3];
  const float* f_ka = (const float*)d_in[4];
  const float* f_kb = (const float*)d_in[5];
  const float* f_va = (const float*)d_in[6];
  const float* f_vb = (const float*)d_in[7];
  const float* f_oa = (const float*)d_in[8];
  const float* f_ob = (const float*)d_in[9];
  const float* f_table = (const float*)d_in[10];
  const float* f_ln1 = (const float*)d_in[11];
  const float* f_ln2 = (const float*)d_in[12];
  const float* f_ln3 = (const float*)d_in[13];
  const float* f_W[8] = { (const float*)d_in[14], (const float*)d_in[15],
                          (const float*)d_in[16], (const float*)d_in[17],
                          (const float*)d_in[18], (const float*)d_in[19],
                          (const float*)d_in[20], (const float*)d_in[21] };
  const float* f_wi0 = (const float*)d_in[22];
  const float* f_wi1 = (const float*)d_in[23];
  const float* f_wo  = (const float*)d_in[24];

  const size_t SEL1 = 32768;
  const size_t PART = (size_t)2048 * 1024;

  char* w = (char*)d_ws;
  size_t off = 0;
  auto alloc = [&](size_t bytes) -> char* {
    off = (off + 255) & ~(size_t)255;
    char* p = w + off;
    off += bytes;
    return p;
  };
  unsigned short* wt  = (unsigned short*)alloc((size_t)8192 * 1024 * 2); // q,k,v,o,cq,ck,cv,co
  unsigned short* wc  = (unsigned short*)alloc((size_t)8192 * 1024 * 2); // interleaved wi0/wi1
  unsigned short* wot = (unsigned short*)alloc((size_t)1024 * 4096 * 2);
  unsigned short* encbf = (unsigned short*)alloc(2048 * 1024 * 2);
  float* rb = (float*)alloc(16 * 512 * 4);
  unsigned short* xn  = (unsigned short*)alloc(2048 * 1024 * 2);
  unsigned short* qbf = (unsigned short*)alloc(2048 * 1024 * 2);
  unsigned short* kbf = (unsigned short*)alloc(2048 * 1024 * 2);
  unsigned short* vtb = (unsigned short*)alloc((size_t)64 * 64 * 512 * 2);
  unsigned short* kbf2 = (unsigned short*)alloc(2048 * 1024 * 2);
  unsigned short* vtb2 = (unsigned short*)alloc((size_t)64 * 64 * 512 * 2);
  unsigned short* lowext_s = (unsigned short*)alloc(2048 * 128 * 2);
  unsigned short* lowext_c = (unsigned short*)alloc(2048 * 128 * 2);
  unsigned short* lowext_q = (unsigned short*)alloc(2048 * 128 * 2);
  unsigned short* lowext_o = (unsigned short*)alloc(2048 * 128 * 2);
  unsigned short* bmext_s  = (unsigned short*)alloc((size_t)4 * 3072 * 128 * 2);
  unsigned short* bmext_c  = (unsigned short*)alloc((size_t)4 * 2048 * 128 * 2);
  unsigned short* bmext_q  = (unsigned short*)alloc((size_t)4 * 1024 * 128 * 2);
  unsigned short* bmext_o  = (unsigned short*)alloc((size_t)4 * 1024 * 128 * 2);
  unsigned short* bmext_o2 = (unsigned short*)alloc((size_t)4 * 1024 * 128 * 2);
  unsigned short* ctxb = (unsigned short*)alloc(2048 * 1024 * 2);
  float* xres = (float*)alloc(2048 * 1024 * 4);
  float* yres = (float*)alloc(2048 * 1024 * 4);
  char*  big  = alloc((size_t)84 << 20);
  // big aliases (stream-serial lifetimes):
  float* bqs  = (float*)big;                           // self QKV partials 2x[2048][3072] = 48 MB
  float* bqc  = (float*)(big + ((size_t)48 << 20));    // cross KV partials 2x[2048][2048] = 32 MB
  float* op_s = (float*)big;                           // self out-proj partials 4x8 MB
  float* qp_c = (float*)(big + ((size_t)32 << 20));    // cross-Q partials 4x8 MB
  float* op_c = (float*)big;                           // cross out-proj partials 4x8 MB
  unsigned short* hbf = (unsigned short*)big;          // 16 MB
  float* fp   = (float*)(big + ((size_t)16 << 20));    // final partials 4x8 MB
  (void)ws_size; (void)in_sizes; (void)n_in; (void)out_size;

  // ---- prep ----
  PrepArgs pa;
  int ts = 0;
  for (int i = 0; i < 8; ++i) {
    pa.src[i] = f_W[i]; pa.dst[i] = wt + (size_t)i * 1024 * 1024;
    pa.K[i] = 1024; pa.N[i] = 1024; pa.mode[i] = 0;
    pa.tstart[i] = ts; ts += 256;                     // (1024/64)^2
  }
  pa.src[8] = f_wi0; pa.dst[8] = wc; pa.K[8] = 1024; pa.N[8] = 4096; pa.mode[8] = 1;
  pa.tstart[8] = ts; ts += 1024;                      // 16 x 64
  pa.src[9] = f_wi1; pa.dst[9] = wc; pa.K[9] = 1024; pa.N[9] = 4096; pa.mode[9] = 2;
  pa.tstart[9] = ts; ts += 1024;
  pa.src[10] = f_wo; pa.dst[10] = wot; pa.K[10] = 4096; pa.N[10] = 1024; pa.mode[10] = 0;
  pa.tstart[10] = ts; ts += 1024;                     // 64 x 16
  pa.tstart[11] = ts;
  pa.nwt = ts;
  pa.encoded = f_encoded; pa.encbf = encbf;
  pa.table = f_table; pa.rb = rb;
  pa.nf2bf = 2048;
  pa.bmdst[0] = bmext_s;  pa.bmnrg[0] = 24;
  pa.bmsrc[0][0] = f_qb; pa.bmsrc[0][1] = f_kb; pa.bmsrc[0][2] = f_vb;
  pa.bmdst[1] = bmext_c;  pa.bmnrg[1] = 16;
  pa.bmsrc[1][0] = f_kb + SEL1; pa.bmsrc[1][1] = f_vb + SEL1; pa.bmsrc[1][2] = nullptr;
  pa.bmdst[2] = bmext_q;  pa.bmnrg[2] = 8;
  pa.bmsrc[2][0] = f_qb + SEL1; pa.bmsrc[2][1] = nullptr; pa.bmsrc[2][2] = nullptr;
  pa.bmdst[3] = bmext_o;  pa.bmnrg[3] = 8;
  pa.bmsrc[3][0] = f_ob; pa.bmsrc[3][1] = nullptr; pa.bmsrc[3][2] = nullptr;
  pa.bmdst[4] = bmext_o2; pa.bmnrg[4] = 8;
  pa.bmsrc[4][0] = f_ob + SEL1; pa.bmsrc[4][1] = nullptr; pa.bmsrc[4][2] = nullptr;
  int bs = 0;
  for (int m = 0; m < 5; ++m) { pa.bmstart[m] = bs; bs += pa.bmnrg[m] * 4; }
  pa.bmstart[5] = bs;
  pa.nbm = bs;
  pa.lca[0] = f_ka + SEL1; pa.lca[1] = f_va + SEL1;
  pa.lowc = lowext_c;
  int totblk = pa.nwt + pa.nf2bf + 32 + pa.nbm + 256;
  k_prep<<<dim3(totblk), dim3(256), 0, stream>>>(pa);

  // ---- self rms + lows ----
  k_start<<<dim3(256), dim3(256), 0, stream>>>(f_inputs, f_ln1, f_qa, f_ka, f_va, xn, lowext_s);

  // ---- big QKV: self (N=3072, S2) + crossKV (N=2048, S2) ----
  {
    GX g;
    const size_t PS = (size_t)2048 * 3072, PC = (size_t)2048 * 2048;
    g.s[0] = { xn, lowext_s, wt, bmext_s, bqs,            (size_t)3072 * 128, 3072, 24, 0, 9 };
    g.s[1] = { xn, lowext_s, wt, bmext_s, bqs + PS,       (size_t)3072 * 128, 3072, 24, 9, 18 };
    g.s[2] = { encbf, lowext_c, wt + (size_t)5120 * 1024, bmext_c, bqc,      (size_t)2048 * 128, 2048, 16, 0, 9 };
    g.s[3] = { encbf, lowext_c, wt + (size_t)5120 * 1024, bmext_c, bqc + PC, (size_t)2048 * 128, 2048, 16, 9, 18 };
    k_gemmx<<<dim3(24, 16, 4), dim3(256), 0, stream>>>(g);
  }
  k_qkvsum<<<dim3(256, 2), dim3(256), 0, stream>>>(bqs, bqc, qbf, kbf, kbf2);
  k_vtrans2<<<dim3(8, 64, 2), dim3(256), 0, stream>>>(bqs, bqc, vtb, vtb2);

  k_flash<true, false><<<dim3(8, 64), dim3(256), 0, stream>>>(qbf, nullptr, kbf, vtb, rb, ctxb);

  // ---- self out-proj (K-ext lora_o, S4) ----
  k_lowbf<<<dim3(256), dim3(256), 0, stream>>>(ctxb, f_oa, lowext_o);
  {
    GX g;
    for (int s = 0; s < 4; ++s)
      g.s[s] = { ctxb, lowext_o, wt + (size_t)3072 * 1024, bmext_o, op_s + (size_t)s * PART,
                 (size_t)1024 * 128, 1024, 8, s * 18 / 4, (s + 1) * 18 / 4 };
    k_gemmx<<<dim3(8, 16, 4), dim3(256), 0, stream>>>(g);
  }
  k_addbrms<true><<<dim3(256), dim3(256), 0, stream>>>(op_s, f_inputs, f_ln2, xres, xn,
                                                       f_qa + SEL1, lowext_q);

  // ---- cross-Q (K-ext, S4) ----
  {
    GX g;
    for (int s = 0; s < 4; ++s)
      g.s[s] = { xn, lowext_q, wt + (size_t)4096 * 1024, bmext_q, qp_c + (size_t)s * PART,
                 (size_t)1024 * 128, 1024, 8, s * 18 / 4, (s + 1) * 18 / 4 };
    k_gemmx<<<dim3(8, 16, 4), dim3(256), 0, stream>>>(g);
  }
  k_flash<false, true><<<dim3(8, 64), dim3(256), 0, stream>>>(nullptr, qp_c, kbf2, vtb2, rb, ctxb);

  // ---- cross out-proj (K-ext lora_o sel1, S4) ----
  k_lowbf<<<dim3(256), dim3(256), 0, stream>>>(ctxb, f_oa + SEL1, lowext_o);
  {
    GX g;
    for (int s = 0; s < 4; ++s)
      g.s[s] = { ctxb, lowext_o, wt + (size_t)7168 * 1024, bmext_o2, op_c + (size_t)s * PART,
                 (size_t)1024 * 128, 1024, 8, s * 18 / 4, (s + 1) * 18 / 4 };
    k_gemmx<<<dim3(8, 16, 4), dim3(256), 0, stream>>>(g);
  }
  k_addbrms<false><<<dim3(256), dim3(256), 0, stream>>>(op_c, xres, f_ln3, yres, xn,
                                                        nullptr, nullptr);

  // ---- MLP ----
  k_mlp<<<dim3(32, 16), dim3(512), 0, stream>>>(xn, wc, hbf);
  k_gemm1s<<<dim3(8, 16, 4), dim3(256), 0, stream>>>(hbf, wot, fp, PART, 1024, 4096, 4096, 1024);
  k_sum4<<<dim3(2048), dim3(256), 0, stream>>>(fp, PART, yres, (float*)d_out);
}

// Round 11
// 612.145 us; speedup vs baseline: 1.3400x; 1.0155x over previous
//
#include <hip/hip_runtime.h>
#include <math.h>

// ---------------------------------------------------------------------------
// LoRA T5 decoder layer on MI355X (gfx950).
// B=4, L=ENC=512, D=1024, H=16, HD=64, MLP=4096, R=32.
// R10->R11: XOR-swizzled LDS for all GEMM kernels. The m97 fragment layout
// puts all 16 lanes of a quarter-wave on one 4-bank group (128-B row stride)
// -> 16-way conflicts = ~25% of CU time (SQ_LDS_BANK_CONFLICT 1.31e7/dispatch).
// Staging permutes the global source chunk ((lane&7)^((lane>>3)&7)) so LDS
// physical col = logical ^ (row&7); fragment reads XOR col16 with l15&7.
// global_load_lds-compatible (no per-lane scatter needed), coalescing kept.
// Flash left unswizzled this round (blast-radius control).
// ---------------------------------------------------------------------------

#define DEV __device__ __forceinline__

typedef __bf16 bf16x8 __attribute__((ext_vector_type(8)));
typedef float floatx4 __attribute__((ext_vector_type(4)));

typedef __attribute__((address_space(1))) void* gas_ptr;
typedef __attribute__((address_space(3))) void* las_ptr;

DEV unsigned short f2bf(float f) {
  union { float f; unsigned int u; } v; v.f = f;
  unsigned int r = v.u + 0x7fffu + ((v.u >> 16) & 1u);
  return (unsigned short)(r >> 16);
}
DEV float bf2f(unsigned short u) {
  union { unsigned int u; float f; } v; v.u = ((unsigned int)u) << 16;
  return v.f;
}

#define GLOAD_LDS16(g, l) __builtin_amdgcn_global_load_lds((gas_ptr)(g), (las_ptr)(l), 16, 0, 0)

// Plain staging (flash): nrows x 64 bf16 (128 B rows), LDS row-major.
template<int NW>
DEV void stage_tile(const char* gbase, char* lds, int nrows, int ldbytes, int wave, int lane) {
  int nchunks = nrows >> 3;
  for (int c = wave; c < nchunks; c += NW) {
    int row  = (c << 3) + (lane >> 3);
    int colb = (lane & 7) << 4;
    GLOAD_LDS16(gbase + (size_t)row * ldbytes + colb, lds + (c << 10));
  }
}

// Swizzled staging (GEMMs): LDS physical chunk-col p of row r holds logical
// chunk (p ^ (r&7)). Lane p=(lane&7), r&7=(lane>>3)&7 -> load logical col
// (lane&7)^((lane>>3)&7). Same 128-B segments per wave => coalescing kept.
template<int NW>
DEV void stage_tile_sw(const char* gbase, char* lds, int nrows, int ldbytes, int wave, int lane) {
  int nchunks = nrows >> 3;
  int colb = (((lane & 7) ^ ((lane >> 3) & 7)) << 4);
  for (int c = wave; c < nchunks; c += NW) {
    int row = (c << 3) + (lane >> 3);
    GLOAD_LDS16(gbase + (size_t)row * ldbytes + colb, lds + (c << 10));
  }
}

// Stage nrows x 128 bf16 (256 B rows) from global (flash V path, unswizzled).
template<int NW>
DEV void stage_tile256(const char* gbase, char* lds, int nrows, int ldbytes, int wave, int lane) {
  int nchunks = nrows >> 2;
  for (int c = wave; c < nchunks; c += NW) {
    int row  = (c << 2) + (lane >> 4);
    int colb = (lane & 15) << 4;
    GLOAD_LDS16(gbase + (size_t)row * ldbytes + colb, lds + (c << 10));
  }
}

// ---------------- generic bf16 GEMM core (fp32 out), 128x128 tile ----------
// Swizzled LDS: fragment read col16 = ((kk>>3)+quad) ^ (l15&7).
template<int WM, int WN>
DEV void gemm_core(const unsigned short* A, const unsigned short* Bt, float* C,
                   int K, int lda, int ldb, int ldc, int m0, int n0,
                   char* ldsA, char* ldsB) {
  constexpr int NW = WM * WN;
  const int tid  = threadIdx.x;
  const int lane = tid & 63;
  const int wave = tid >> 6;
  const int wm   = wave % WM;
  const int wn   = wave / WM;
  const int quad = lane >> 4;
  const int l15  = lane & 15;
  const int key  = l15 & 7;

  floatx4 acc[4][4];
#pragma unroll
  for (int i = 0; i < 4; ++i)
#pragma unroll
    for (int j = 0; j < 4; ++j) acc[i][j] = (floatx4){0.f, 0.f, 0.f, 0.f};

  const char* gA = (const char*)(A + (size_t)m0 * lda);
  const char* gB = (const char*)(Bt + (size_t)n0 * ldb);

  for (int k0 = 0; k0 < K; k0 += 64) {
    stage_tile_sw<NW>(gA + (size_t)k0 * 2, ldsA, WM * 64, lda * 2, wave, lane);
    stage_tile_sw<NW>(gB + (size_t)k0 * 2, ldsB, WN * 64, ldb * 2, wave, lane);
    __syncthreads();
#pragma unroll
    for (int kk = 0; kk < 64; kk += 32) {
      bf16x8 af[4], bv[4];
      int off = (((kk >> 3) + quad) ^ key) << 4;
      const char* baseA = ldsA + (size_t)(wm * 64 + l15) * 128 + off;
      const char* baseB = ldsB + (size_t)(wn * 64 + l15) * 128 + off;
#pragma unroll
      for (int mi = 0; mi < 4; ++mi) af[mi] = *(const bf16x8*)(baseA + mi * 2048);
#pragma unroll
      for (int ni = 0; ni < 4; ++ni) bv[ni] = *(const bf16x8*)(baseB + ni * 2048);
#pragma unroll
      for (int mi = 0; mi < 4; ++mi)
#pragma unroll
        for (int ni = 0; ni < 4; ++ni)
          acc[mi][ni] = __builtin_amdgcn_mfma_f32_16x16x32_bf16(af[mi], bv[ni], acc[mi][ni], 0, 0, 0);
    }
    __syncthreads();
  }

#pragma unroll
  for (int mi = 0; mi < 4; ++mi) {
#pragma unroll
    for (int r = 0; r < 4; ++r) {
      int row = m0 + wm * 64 + mi * 16 + quad * 4 + r;
#pragma unroll
      for (int ni = 0; ni < 4; ++ni) {
        int col = n0 + wn * 64 + ni * 16 + l15;
        C[(size_t)row * ldc + col] = acc[mi][ni][r];
      }
    }
  }
}

__global__ __launch_bounds__(256) void k_gemm1s(const unsigned short* A, const unsigned short* Bt,
                                                float* Cpart, size_t pstride,
                                                int Kchunk, int lda, int ldb, int ldc) {
  __shared__ char lds[32768];
  int s = blockIdx.z;
  size_t koff = (size_t)s * Kchunk;
  gemm_core<2, 2>(A + koff, Bt + koff, Cpart + (size_t)s * pstride,
                  Kchunk, lda, ldb, ldc,
                  blockIdx.y * 128, blockIdx.x * 128, lds, lds + 16384);
}

// ---------------- K-extended GEMM: C = [A0|Aext] @ [B0|Bext(b)]^T ----------
struct GXSlice {
  const unsigned short* A0;
  const unsigned short* Aext;
  const unsigned short* B0;
  const unsigned short* Bext;
  float* C;
  size_t bextb;            // per-b element stride of Bext (= N*128)
  int ldc, nxa, it0, it1;
};
struct GX { GXSlice s[4]; };

__global__ __launch_bounds__(256) void k_gemmx(GX g) {
  __shared__ char lds[32768];
  char* ldsA = lds;
  char* ldsB = lds + 16384;
  GXSlice sl = g.s[blockIdx.z];
  if ((int)blockIdx.x >= sl.nxa) return;
  const int m0 = blockIdx.y * 128, n0 = blockIdx.x * 128;
  const int b = m0 >> 9;
  const int tid = threadIdx.x, lane = tid & 63, wave = tid >> 6;
  const int wm = wave & 1, wn = wave >> 1;
  const int quad = lane >> 4, l15 = lane & 15;
  const int key = l15 & 7;

  floatx4 acc[4][4];
#pragma unroll
  for (int i = 0; i < 4; ++i)
#pragma unroll
    for (int j = 0; j < 4; ++j) acc[i][j] = (floatx4){0.f, 0.f, 0.f, 0.f};

  for (int it = sl.it0; it < sl.it1; ++it) {
    if (it < 16) {
      stage_tile_sw<4>((const char*)sl.A0 + (size_t)m0 * 2048 + it * 128, ldsA, 128, 2048, wave, lane);
      stage_tile_sw<4>((const char*)sl.B0 + (size_t)n0 * 2048 + it * 128, ldsB, 128, 2048, wave, lane);
    } else {
      int eb = (it - 16) * 128;
      stage_tile_sw<4>((const char*)sl.Aext + (size_t)m0 * 256 + eb, ldsA, 128, 256, wave, lane);
      stage_tile_sw<4>((const char*)(sl.Bext + (size_t)b * sl.bextb) + (size_t)n0 * 256 + eb,
                       ldsB, 128, 256, wave, lane);
    }
    __syncthreads();
#pragma unroll
    for (int kk = 0; kk < 64; kk += 32) {
      bf16x8 af[4], bv[4];
      int off = (((kk >> 3) + quad) ^ key) << 4;
      const char* baseA = ldsA + (size_t)(wm * 64 + l15) * 128 + off;
      const char* baseB = ldsB + (size_t)(wn * 64 + l15) * 128 + off;
#pragma unroll
      for (int mi = 0; mi < 4; ++mi) af[mi] = *(const bf16x8*)(baseA + mi * 2048);
#pragma unroll
      for (int ni = 0; ni < 4; ++ni) bv[ni] = *(const bf16x8*)(baseB + ni * 2048);
#pragma unroll
      for (int mi = 0; mi < 4; ++mi)
#pragma unroll
        for (int ni = 0; ni < 4; ++ni)
          acc[mi][ni] = __builtin_amdgcn_mfma_f32_16x16x32_bf16(af[mi], bv[ni], acc[mi][ni], 0, 0, 0);
    }
    __syncthreads();
  }

#pragma unroll
  for (int mi = 0; mi < 4; ++mi) {
#pragma unroll
    for (int r = 0; r < 4; ++r) {
      int row = m0 + wm * 64 + mi * 16 + quad * 4 + r;
#pragma unroll
      for (int ni = 0; ni < 4; ++ni) {
        int col = n0 + wn * 64 + ni * 16 + l15;
        sl.C[(size_t)row * sl.ldc + col] = acc[mi][ni][r];
      }
    }
  }
}

// ---------------- QKV sum: splitK(2) sum + bf16 cast, q/k sections only ---
__global__ __launch_bounds__(256) void k_qkvsum(const float* bqs, const float* bqc,
                                                unsigned short* qbf, unsigned short* kbf,
                                                unsigned short* kbf2) {
  const size_t PS = (size_t)2048 * 3072, PC = (size_t)2048 * 2048;
  int t = threadIdx.x;
  int row0 = blockIdx.x * 8;
  int zc = blockIdx.y;
  for (int j = 0; j < 8; ++j) {
    int row = row0 + j;
    int nsec = zc ? 1 : 2;
    for (int sec = 0; sec < nsec; ++sec) {
      const float* base = zc ? (bqc + (size_t)row * 2048 + sec * 1024)
                             : (bqs + (size_t)row * 3072 + sec * 1024);
      float4 a = ((const float4*)base)[t];
      float4 c = ((const float4*)(base + (zc ? PC : PS)))[t];
      float4 s; s.x = a.x + c.x; s.y = a.y + c.y; s.z = a.z + c.z; s.w = a.w + c.w;
      ushort4 o; o.x = f2bf(s.x); o.y = f2bf(s.y); o.z = f2bf(s.z); o.w = f2bf(s.w);
      unsigned short* dst = zc ? kbf2 : (sec == 0 ? qbf : kbf);
      ((ushort4*)(dst + (size_t)row * 1024))[t] = o;
    }
  }
}

// ---------------- V transpose from fp32 partials (LDS-tiled) --------------
__global__ __launch_bounds__(256) void k_vtrans2(const float* bqs, const float* bqc,
                                                 unsigned short* vtb, unsigned short* vtb2) {
  __shared__ float tl[64][65];
  int which = blockIdx.z;                 // 0 = self, 1 = cross
  int z = blockIdx.y, b = z >> 4, h = z & 15;
  int k0 = blockIdx.x * 64;
  int ld = which ? 2048 : 3072;
  int voff = which ? 1024 : 2048;
  const float* src = which ? bqc : bqs;
  size_t PARTW = (size_t)2048 * ld;
  unsigned short* dst = which ? vtb2 : vtb;
  int t = threadIdx.x;
  {
    int kr = t >> 2, c0 = (t & 3) * 16;
    const float* p = src + (size_t)(b * 512 + k0 + kr) * ld + voff + h * 64 + c0;
#pragma unroll
    for (int i = 0; i < 4; ++i) {
      float4 v0 = *(const float4*)(p + i * 4);
      float4 v1 = *(const float4*)(p + PARTW + i * 4);
      tl[kr][c0 + i * 4 + 0] = v0.x + v1.x;
      tl[kr][c0 + i * 4 + 1] = v0.y + v1.y;
      tl[kr][c0 + i * 4 + 2] = v0.z + v1.z;
      tl[kr][c0 + i * 4 + 3] = v0.w + v1.w;
    }
  }
  __syncthreads();
  {
    int dw = t >> 2, kc = (t & 3) * 16;
    union { unsigned short us[16]; uint4 q[2]; } pk;
#pragma unroll
    for (int j = 0; j < 16; ++j) pk.us[j] = f2bf(tl[kc + j][dw]);
    uint4* dp = (uint4*)(dst + ((size_t)z * 64 + dw) * 512 + k0 + kc);
    dp[0] = pk.q[0]; dp[1] = pk.q[1];
  }
}

// ---------------- flash attention (unswizzled LDS this round) -------------
template<bool CAUSAL, bool QSUM>
__global__ __launch_bounds__(256) void k_flash(const unsigned short* qmat, const float* qparts,
                                               const unsigned short* kmat, const unsigned short* vt,
                                               const float* rb, unsigned short* ctxb) {
  __shared__ char ldsQ[8192];    // [64 q][64 d]
  __shared__ char ldsK[16384];   // [128 k][64 d]
  __shared__ char ldsV[16384];   // [64 d][128 k]
  __shared__ char ldsP[16384];   // [64 q][128 k]
  __shared__ float lrb[512];

  const size_t PART = (size_t)2048 * 1024;
  const int z = blockIdx.y, b = z >> 4, h = z & 15;
  const int q0 = blockIdx.x * 64;
  const int tid = threadIdx.x, lane = tid & 63, wave = tid >> 6;
  const int quad = lane >> 4, l15 = lane & 15;

  const unsigned short* K = kmat + (size_t)b * 512 * 1024 + h * 64;
  const unsigned short* V = vt + (size_t)z * 64 * 512;

  if (QSUM) {
#pragma unroll
    for (int rr = 0; rr < 4; ++rr) {
      int row = rr * 16 + (tid >> 4);
      int c4 = tid & 15;
      const float* src = qparts + (size_t)(q0 + row) * 1024 + h * 64 + c4 * 4;
      float4 s0 = *(const float4*)src;
      float4 s1 = *(const float4*)(src + PART);
      float4 s2 = *(const float4*)(src + 2 * PART);
      float4 s3 = *(const float4*)(src + 3 * PART);
      ushort4 o;
      o.x = f2bf(s0.x + s1.x + s2.x + s3.x);
      o.y = f2bf(s0.y + s1.y + s2.y + s3.y);
      o.z = f2bf(s0.z + s1.z + s2.z + s3.z);
      o.w = f2bf(s0.w + s1.w + s2.w + s3.w);
      *(ushort4*)(ldsQ + (size_t)row * 128 + c4 * 8) = o;
    }
  } else {
    const unsigned short* Q = qmat + (size_t)b * 512 * 1024 + h * 64;
    stage_tile<4>((const char*)(Q + (size_t)q0 * 1024), ldsQ, 64, 2048, wave, lane);
  }
  if (CAUSAL)
    for (int i = tid; i < 512; i += 256) lrb[i] = rb[h * 512 + i];

  float m_run[4], l_run[4];
  floatx4 oacc[4];
#pragma unroll
  for (int r = 0; r < 4; ++r) { m_run[r] = -1e30f; l_run[r] = 0.f; }
#pragma unroll
  for (int ni = 0; ni < 4; ++ni) oacc[ni] = (floatx4){0.f, 0.f, 0.f, 0.f};

  const int ktend = CAUSAL ? (blockIdx.x / 2 + 1) : 4;
  for (int kt = 0; kt < ktend; ++kt) {
    __syncthreads();
    stage_tile<4>((const char*)(K + (size_t)kt * 128 * 1024), ldsK, 128, 2048, wave, lane);
    stage_tile256<4>((const char*)(V + kt * 128), ldsV, 64, 1024, wave, lane);
    __syncthreads();

    floatx4 sacc[8];
#pragma unroll
    for (int ct = 0; ct < 8; ++ct) sacc[ct] = (floatx4){0.f, 0.f, 0.f, 0.f};
    const char* aBase = ldsQ + (size_t)(wave * 16 + l15) * 128 + quad * 16;
#pragma unroll
    for (int kd = 0; kd < 2; ++kd) {
      bf16x8 af = *(const bf16x8*)(aBase + kd * 64);
#pragma unroll
      for (int ct = 0; ct < 8; ++ct) {
        bf16x8 bf = *(const bf16x8*)(ldsK + (size_t)(ct * 16 + l15) * 128 + quad * 16 + kd * 64);
        sacc[ct] = __builtin_amdgcn_mfma_f32_16x16x32_bf16(af, bf, sacc[ct], 0, 0, 0);
      }
    }

    float sv[8][4];
#pragma unroll
    for (int ct = 0; ct < 8; ++ct)
#pragma unroll
      for (int r = 0; r < 4; ++r) {
        float v = sacc[ct][r] * 0.125f;
        if (CAUSAL) {
          int qq = q0 + wave * 16 + quad * 4 + r;
          int kk = kt * 128 + ct * 16 + l15;
          v = (kk <= qq) ? v + lrb[qq - kk] : -1e30f;
        }
        sv[ct][r] = v;
      }

    float mx[4];
#pragma unroll
    for (int r = 0; r < 4; ++r) {
      mx[r] = sv[0][r];
#pragma unroll
      for (int ct = 1; ct < 8; ++ct) mx[r] = fmaxf(mx[r], sv[ct][r]);
    }
#pragma unroll
    for (int o = 1; o < 16; o <<= 1)
#pragma unroll
      for (int r = 0; r < 4; ++r) mx[r] = fmaxf(mx[r], __shfl_xor(mx[r], o));

    float alpha[4], rs[4];
#pragma unroll
    for (int r = 0; r < 4; ++r) {
      float mn = fmaxf(m_run[r], mx[r]);
      alpha[r] = __expf(m_run[r] - mn);
      m_run[r] = mn;
      rs[r] = 0.f;
    }
#pragma unroll
    for (int ct = 0; ct < 8; ++ct)
#pragma unroll
      for (int r = 0; r < 4; ++r) {
        float p = __expf(sv[ct][r] - m_run[r]);
        sv[ct][r] = p;
        rs[r] += p;
      }
#pragma unroll
    for (int o = 1; o < 16; o <<= 1)
#pragma unroll
      for (int r = 0; r < 4; ++r) rs[r] += __shfl_xor(rs[r], o);
#pragma unroll
    for (int r = 0; r < 4; ++r) l_run[r] = l_run[r] * alpha[r] + rs[r];
#pragma unroll
    for (int ni = 0; ni < 4; ++ni)
#pragma unroll
      for (int r = 0; r < 4; ++r) oacc[ni][r] *= alpha[r];

#pragma unroll
    for (int ct = 0; ct < 8; ++ct)
#pragma unroll
      for (int r = 0; r < 4; ++r)
        *(unsigned short*)(ldsP + (size_t)(wave * 16 + quad * 4 + r) * 256 + (ct * 16 + l15) * 2)
            = f2bf(sv[ct][r]);
    __syncthreads();

    const char* pBase = ldsP + (size_t)(wave * 16 + l15) * 256 + quad * 16;
#pragma unroll
    for (int kk = 0; kk < 4; ++kk) {
      bf16x8 pf = *(const bf16x8*)(pBase + kk * 64);
#pragma unroll
      for (int ni = 0; ni < 4; ++ni) {
        bf16x8 vf8 = *(const bf16x8*)(ldsV + (size_t)(ni * 16 + l15) * 256 + quad * 16 + kk * 64);
        oacc[ni] = __builtin_amdgcn_mfma_f32_16x16x32_bf16(pf, vf8, oacc[ni], 0, 0, 0);
      }
    }
  }

#pragma unroll
  for (int r = 0; r < 4; ++r) {
    int q = q0 + wave * 16 + quad * 4 + r;
    float inv = 1.0f / l_run[r];
    unsigned short* dst = ctxb + ((size_t)b * 512 + q) * 1024 + h * 64;
#pragma unroll
    for (int ni = 0; ni < 4; ++ni)
      dst[ni * 16 + l15] = f2bf(oacc[ni][r] * inv);
  }
}

// ---------------- fused MLP (swizzled LDS) ----------------
__global__ __launch_bounds__(512) void k_mlp(const unsigned short* A, const unsigned short* Wc,
                                             unsigned short* hbf) {
  __shared__ char lds[49152];
  char* ldsA = lds;
  char* ldsB = lds + 16384;
  const int m0 = blockIdx.y * 128;
  const int n0 = blockIdx.x * 128;
  const int tid = threadIdx.x, lane = tid & 63, wave = tid >> 6;
  const int half = wave >> 2, wl = wave & 3;
  const int wm = wl & 1, wn = wl >> 1;
  const int quad = lane >> 4, l15 = lane & 15;
  const int key = l15 & 7;

  floatx4 acc[4][4];
#pragma unroll
  for (int i = 0; i < 4; ++i)
#pragma unroll
    for (int j = 0; j < 4; ++j) acc[i][j] = (floatx4){0.f, 0.f, 0.f, 0.f};

  const char* gA = (const char*)(A + (size_t)m0 * 1024);
  const char* gB = (const char*)(Wc + (size_t)blockIdx.x * 256 * 1024);

  for (int k0 = 0; k0 < 1024; k0 += 64) {
    stage_tile_sw<8>(gA + (size_t)k0 * 2, ldsA, 128, 2048, wave, lane);
    stage_tile_sw<8>(gB + (size_t)k0 * 2, ldsB, 256, 2048, wave, lane);
    __syncthreads();
#pragma unroll
    for (int kk = 0; kk < 64; kk += 32) {
      bf16x8 af[4], bv[4];
      int off = (((kk >> 3) + quad) ^ key) << 4;
      const char* baseA = ldsA + (size_t)(wm * 64 + l15) * 128 + off;
      const char* baseB = ldsB + (size_t)(half * 128 + wn * 64 + l15) * 128 + off;
#pragma unroll
      for (int mi = 0; mi < 4; ++mi) af[mi] = *(const bf16x8*)(baseA + mi * 2048);
#pragma unroll
      for (int ni = 0; ni < 4; ++ni) bv[ni] = *(const bf16x8*)(baseB + ni * 2048);
#pragma unroll
      for (int mi = 0; mi < 4; ++mi)
#pragma unroll
        for (int ni = 0; ni < 4; ++ni)
          acc[mi][ni] = __builtin_amdgcn_mfma_f32_16x16x32_bf16(af[mi], bv[ni], acc[mi][ni], 0, 0, 0);
    }
    __syncthreads();
  }

  if (half == 1) {
#pragma unroll
    for (int mi = 0; mi < 4; ++mi)
#pragma unroll
      for (int r = 0; r < 4; ++r) {
        int row = wm * 64 + mi * 16 + quad * 4 + r;
#pragma unroll
        for (int ni = 0; ni < 4; ++ni) {
          int col = wn * 64 + ni * 16 + l15;
          *(unsigned short*)(ldsB + (size_t)row * 256 + col * 2) = f2bf(acc[mi][ni][r]);
        }
      }
  }
  __syncthreads();
  if (half == 0) {
#pragma unroll
    for (int mi = 0; mi < 4; ++mi)
#pragma unroll
      for (int r = 0; r < 4; ++r) {
        int row = wm * 64 + mi * 16 + quad * 4 + r;
#pragma unroll
        for (int ni = 0; ni < 4; ++ni) {
          int col = wn * 64 + ni * 16 + l15;
          float h1 = bf2f(*(const unsigned short*)(ldsB + (size_t)row * 256 + col * 2));
          float g = acc[mi][ni][r];
          float v = 0.5f * g * (1.0f + erff(g * 0.70710678f)) * h1;
          hbf[(size_t)(m0 + row) * 4096 + n0 + col] = f2bf(v);
        }
      }
  }
}

// ---------------- prep: fast transpose + encbf + relbias + bmext + lowc ---
struct PrepArgs {
  const float* src[11];
  unsigned short* dst[11];
  int K[11], N[11], mode[11];
  int tstart[12];
  const float* encoded;
  unsigned short* encbf;
  const float* table;
  float* rb;
  unsigned short* bmdst[5];
  const float* bmsrc[5][3];
  int bmnrg[5];
  int bmstart[6];
  const float* lca[2];
  unsigned short* lowc;
  int nwt, nf2bf, nbm;
};
__global__ __launch_bounds__(256) void k_prep(PrepArgs a) {
  __shared__ char shm[49152];
  int bid = blockIdx.x;
  int t = threadIdx.x;
  if (bid < a.nwt) {
    float (*tl)[65] = (float(*)[65])shm;   // 16.6 KB
    int z = 0;
    while (z < 10 && bid >= a.tstart[z + 1]) ++z;
    int tile = bid - a.tstart[z];
    int N = a.N[z], K = a.K[z], mode = a.mode[z];
    int ntn = N >> 6;
    int tn = tile % ntn, tk = tile / ntn;
    const float* src = a.src[z] + (size_t)(tk * 64) * N + tn * 64;
    unsigned short* dst = a.dst[z];
    {
      int rq = t >> 4, c4 = (t & 15) * 4;
#pragma unroll
      for (int i = 0; i < 4; ++i) {
        int r = rq + i * 16;
        float4 v = *(const float4*)(src + (size_t)r * N + c4);
        tl[r][c4] = v.x; tl[r][c4 + 1] = v.y; tl[r][c4 + 2] = v.z; tl[r][c4 + 3] = v.w;
      }
    }
    __syncthreads();
    {
      int nl = t >> 2, kseg = (t & 3) * 16;
      int n = tn * 64 + nl;
      int orow = (mode == 0) ? n : ((n >> 7) * 256 + ((mode == 2) ? 128 : 0) + (n & 127));
      union { unsigned short us[16]; uint4 q[2]; } pk;
#pragma unroll
      for (int j = 0; j < 16; ++j) pk.us[j] = f2bf(tl[kseg + j][nl]);
      uint4* dp = (uint4*)(dst + (size_t)orow * K + tk * 64 + kseg);
      dp[0] = pk.q[0]; dp[1] = pk.q[1];
    }
    return;
  }
  bid -= a.nwt;
  if (bid < a.nf2bf) {
    int i = bid * 256 + t;
    float4 v = ((const float4*)a.encoded)[i];
    ushort4 o;
    o.x = f2bf(v.x); o.y = f2bf(v.y); o.z = f2bf(v.z); o.w = f2bf(v.w);
    ((ushort4*)a.encbf)[i] = o;
    return;
  }
  bid -= a.nf2bf;
  if (bid < 32) {
    int i = bid * 256 + t;
    if (i < 16 * 512) {
      int h = i >> 9, d = i & 511;
      int bucket;
      if (d < 16) bucket = d;
      else {
        int lb = 16 + (int)(logf((float)d / 16.0f) / logf(8.0f) * 16.0f);
        bucket = lb < 31 ? lb : 31;
      }
      a.rb[i] = a.table[bucket * 16 + h];
    }
    return;
  }
  bid -= 32;
  if (bid < a.nbm) {
    // bmext fill: Bext[b][row=n0+n][c] = (c>>5==sec) ? b_sec[b][c&31][(n0&1023)+n] : 0
    int m = 0;
    while (m < 4 && bid >= a.bmstart[m + 1]) ++m;
    int idx = bid - a.bmstart[m];
    int nrg = a.bmnrg[m];
    int b = idx / nrg, rg = idx % nrg;
    int n0 = rg * 128;
    int sec = n0 >> 10;
    const float* src = a.bmsrc[m][sec] + (size_t)b * 65536;
    unsigned short* dst = a.bmdst[m] + ((size_t)b * nrg * 128 + n0) * 128;
    int n = t & 127, coff = (t >> 7) * 64;
    int ncol = (n0 & 1023) + n;
    unsigned short* drow = dst + (size_t)n * 128 + coff;
    for (int c4 = 0; c4 < 16; ++c4) {
      ushort4 o;
#pragma unroll
      for (int e = 0; e < 4; ++e) {
        int c = coff + c4 * 4 + e;
        float v = ((c >> 5) == sec) ? src[(size_t)(c & 31) * 1024 + ncol] : 0.f;
        ((unsigned short*)&o)[e] = f2bf(v);
      }
      *(ushort4*)(drow + c4 * 4) = o;
    }
    return;
  }
  bid -= a.nbm;
  {
    // cross-KV lows from fp32 encoded: 8 rows/block
    float* rowsF = (float*)shm;                       // [8][1024] = 32 KB
    float* pacc = (float*)(shm + 32768);              // [2][8][8][32] = 16 KB
    int row0 = bid * 8;
    int b = row0 >> 9;
    for (int j = 0; j < 8; ++j)
      ((float4*)(rowsF + j * 1024))[t] = ((const float4*)(a.encoded + (size_t)(row0 + j) * 1024))[t];
    __syncthreads();
    int r = t & 31, g = t >> 5;
    float acc[2][8];
#pragma unroll
    for (int p = 0; p < 2; ++p)
#pragma unroll
      for (int j = 0; j < 8; ++j) acc[p][j] = 0.f;
    const float* a0 = a.lca[0] + (size_t)b * 65536;
    const float* a1 = a.lca[1] + (size_t)b * 65536;
    for (int i = 0; i < 128; ++i) {
      int k = g * 128 + i;
      float ak = a0[(size_t)k * 32 + r];
      float av = a1[(size_t)k * 32 + r];
#pragma unroll
      for (int j = 0; j < 8; ++j) {
        float x = rowsF[j * 1024 + k];
        acc[0][j] += x * ak;
        acc[1][j] += x * av;
      }
    }
#pragma unroll
    for (int p = 0; p < 2; ++p)
#pragma unroll
      for (int j = 0; j < 8; ++j)
        pacc[((p * 8 + j) * 8 + g) * 32 + r] = acc[p][j];
    __syncthreads();
    for (int j = 0; j < 8; ++j) {
      if (t < 64) {
        int p = t >> 5, r2 = t & 31;
        float s = 0.f;
        for (int gg = 0; gg < 8; ++gg) s += pacc[((p * 8 + j) * 8 + gg) * 32 + r2];
        a.lowc[(size_t)(row0 + j) * 128 + p * 32 + r2] = f2bf(s);
      } else if (t < 128) {
        a.lowc[(size_t)(row0 + j) * 128 + t] = 0;
      }
    }
  }
}

// ---------------- k_start: rmsnorm + self q/k/v lows ----------------------
__global__ __launch_bounds__(256) void k_start(const float* x, const float* sc,
                                               const float* qa, const float* ka, const float* va,
                                               unsigned short* xn, unsigned short* lowext) {
  __shared__ unsigned short lrows[8][1024];   // 16 KB
  __shared__ float pacc[3 * 8 * 8 * 32];      // 24 KB
  __shared__ float red[4];
  int t = threadIdx.x;
  int row0 = blockIdx.x * 8;
  int b = row0 >> 9;
  float4 s4 = ((const float4*)sc)[t];
  for (int j = 0; j < 8; ++j) {
    int row = row0 + j;
    float4 v = ((const float4*)(x + (size_t)row * 1024))[t];
    float ss = v.x * v.x + v.y * v.y + v.z * v.z + v.w * v.w;
    for (int o = 32; o; o >>= 1) ss += __shfl_down(ss, o);
    if ((t & 63) == 0) red[t >> 6] = ss;
    __syncthreads();
    float tot = red[0] + red[1] + red[2] + red[3];
    float rs = rsqrtf(tot * (1.0f / 1024.0f) + 1e-6f);
    ushort4 o;
    o.x = f2bf(v.x * rs * s4.x); o.y = f2bf(v.y * rs * s4.y);
    o.z = f2bf(v.z * rs * s4.z); o.w = f2bf(v.w * rs * s4.w);
    ((ushort4*)(xn + (size_t)row * 1024))[t] = o;
    *(ushort4*)(&lrows[j][t * 4]) = o;
    __syncthreads();
  }
  int r = t & 31, g = t >> 5;
  float acc[3][8];
#pragma unroll
  for (int p = 0; p < 3; ++p)
#pragma unroll
    for (int j = 0; j < 8; ++j) acc[p][j] = 0.f;
  const float* aq = qa + (size_t)b * 65536;
  const float* ak = ka + (size_t)b * 65536;
  const float* av = va + (size_t)b * 65536;
  for (int i = 0; i < 128; ++i) {
    int k = g * 128 + i;
    float a0 = aq[(size_t)k * 32 + r];
    float a1 = ak[(size_t)k * 32 + r];
    float a2 = av[(size_t)k * 32 + r];
#pragma unroll
    for (int j = 0; j < 8; ++j) {
      float xv = bf2f(lrows[j][k]);
      acc[0][j] += xv * a0;
      acc[1][j] += xv * a1;
      acc[2][j] += xv * a2;
    }
  }
#pragma unroll
  for (int p = 0; p < 3; ++p)
#pragma unroll
    for (int j = 0; j < 8; ++j)
      pacc[((p * 8 + j) * 8 + g) * 32 + r] = acc[p][j];
  __syncthreads();
  for (int j = 0; j < 8; ++j) {
    if (t < 96) {
      int p = t >> 5, r2 = t & 31;
      float s = 0.f;
      for (int gg = 0; gg < 8; ++gg) s += pacc[((p * 8 + j) * 8 + gg) * 32 + r2];
      lowext[(size_t)(row0 + j) * 128 + p * 32 + r2] = f2bf(s);
    } else if (t < 128) {
      lowext[(size_t)(row0 + j) * 128 + t] = 0;
    }
  }
}

// ---------------- k_addbrms: 4-partial sum + resid + rms (+ next low) -----
template<bool LOW>
__global__ __launch_bounds__(256) void k_addbrms(const float* parts, const float* resid,
                                                 const float* sc, float* resout,
                                                 unsigned short* xn,
                                                 const float* aP, unsigned short* lowext) {
  __shared__ unsigned short lrows[8][1024];
  __shared__ float pacc[8 * 8 * 32];
  __shared__ float red[4];
  const size_t PART = (size_t)2048 * 1024;
  int t = threadIdx.x;
  int row0 = blockIdx.x * 8;
  int b = row0 >> 9;
  float4 s4 = ((const float4*)sc)[t];
  for (int j = 0; j < 8; ++j) {
    int row = row0 + j;
    const float* p0 = parts + (size_t)row * 1024;
    float4 v = ((const float4*)p0)[t];
    float4 v1 = ((const float4*)(p0 + PART))[t];
    float4 v2 = ((const float4*)(p0 + 2 * PART))[t];
    float4 v3 = ((const float4*)(p0 + 3 * PART))[t];
    float4 rv = ((const float4*)(resid + (size_t)row * 1024))[t];
    float4 s;
    s.x = v.x + v1.x + v2.x + v3.x + rv.x;
    s.y = v.y + v1.y + v2.y + v3.y + rv.y;
    s.z = v.z + v1.z + v2.z + v3.z + rv.z;
    s.w = v.w + v1.w + v2.w + v3.w + rv.w;
    ((float4*)(resout + (size_t)row * 1024))[t] = s;
    float ss = s.x * s.x + s.y * s.y + s.z * s.z + s.w * s.w;
    for (int o = 32; o; o >>= 1) ss += __shfl_down(ss, o);
    if ((t & 63) == 0) red[t >> 6] = ss;
    __syncthreads();
    float tot = red[0] + red[1] + red[2] + red[3];
    float rs = rsqrtf(tot * (1.0f / 1024.0f) + 1e-6f);
    ushort4 o;
    o.x = f2bf(s.x * rs * s4.x); o.y = f2bf(s.y * rs * s4.y);
    o.z = f2bf(s.z * rs * s4.z); o.w = f2bf(s.w * rs * s4.w);
    ((ushort4*)(xn + (size_t)row * 1024))[t] = o;
    if (LOW) *(ushort4*)(&lrows[j][t * 4]) = o;
    __syncthreads();
  }
  if (LOW) {
    int r = t & 31, g = t >> 5;
    float acc[8];
#pragma unroll
    for (int j = 0; j < 8; ++j) acc[j] = 0.f;
    const float* ap = aP + (size_t)b * 65536;
    for (int i = 0; i < 128; ++i) {
      int k = g * 128 + i;
      float a0 = ap[(size_t)k * 32 + r];
#pragma unroll
      for (int j = 0; j < 8; ++j) acc[j] += bf2f(lrows[j][k]) * a0;
    }
#pragma unroll
    for (int j = 0; j < 8; ++j) pacc[(j * 8 + g) * 32 + r] = acc[j];
    __syncthreads();
    for (int j = 0; j < 8; ++j) {
      if (t < 32) {
        float s = 0.f;
        for (int gg = 0; gg < 8; ++gg) s += pacc[(j * 8 + gg) * 32 + t];
        lowext[(size_t)(row0 + j) * 128 + t] = f2bf(s);
      } else if (t < 128) {
        lowext[(size_t)(row0 + j) * 128 + t] = 0;
      }
    }
  }
}

// ---------------- low for out-proj (ctx bf16 -> lowext bf16) --------------
__global__ __launch_bounds__(256) void k_lowbf(const unsigned short* x, const float* a,
                                               unsigned short* lowext) {
  int row0 = blockIdx.x * 8;
  int b = row0 >> 9;
  int t = threadIdx.x, r = t & 31, j = t >> 5;
  int row = row0 + j;
  const bf16x8* xv = (const bf16x8*)(x + (size_t)row * 1024);
  const float* ap = a + (size_t)b * 65536;
  float s = 0.f;
  for (int kb = 0; kb < 128; ++kb) {
    bf16x8 v = xv[kb];
#pragma unroll
    for (int u = 0; u < 8; ++u)
      s += (float)v[u] * ap[(size_t)(kb * 8 + u) * 32 + r];
  }
  lowext[(size_t)row * 128 + r] = f2bf(s);
  lowext[(size_t)row * 128 + 32 + r] = 0;
  lowext[(size_t)row * 128 + 64 + r] = 0;
  lowext[(size_t)row * 128 + 96 + r] = 0;
}

// ---------------- final sum ----------------
__global__ void k_sum4(const float* p, size_t pstride, const float* resid, float* out) {
  int i = blockIdx.x * 256 + threadIdx.x;
  float4 a = ((const float4*)p)[i];
  float4 b = ((const float4*)(p + pstride))[i];
  float4 c = ((const float4*)(p + 2 * pstride))[i];
  float4 d = ((const float4*)(p + 3 * pstride))[i];
  float4 r = ((const float4*)resid)[i];
  float4 o;
  o.x = a.x + b.x + c.x + d.x + r.x;
  o.y = a.y + b.y + c.y + d.y + r.y;
  o.z = a.z + b.z + c.z + d.z + r.z;
  o.w = a.w + b.w + c.w + d.w + r.w;
  ((float4*)out)[i] = o;
}

// ---------------------------------------------------------------------------

extern "C" void kernel_launch(void* const* d_in, const int* in_sizes, int n_in,
                              void* d_out, int out_size, void* d_ws, size_t ws_size,
                              hipStream_t stream) {
  const float* f_inputs  = (const float*)d_in[0];
  const float* f_encoded = (const float*)d_in[1];
  const float* f_qa = (const float*)d_in[2];
  const float* f_qb = (const float*)d_in[3];
  const float* f_ka = (const float*)d_in[4];
  const float* f_kb = (const float*)d_in[5];
  const float* f_va = (const float*)d_in[6];
  const float* f_vb = (const float*)d_in[7];
  const float* f_oa = (const float*)d_in[8];
  const float* f_ob = (const float*)d_in[9];
  const float* f_table = (const float*)d_in[10];
  const float* f_ln1 = (const float*)d_in[11];
  const float* f_ln2 = (const float*)d_in[12];
  const float* f_ln3 = (const float*)d_in[13];
  const float* f_W[8] = { (const float*)d_in[14], (const float*)d_in[15],
                          (const float*)d_in[16], (const float*)d_in[17],
                          (const float*)d_in[18], (const float*)d_in[19],
                          (const float*)d_in[20], (const float*)d_in[21] };
  const float* f_wi0 = (const float*)d_in[22];
  const float* f_wi1 = (const float*)d_in[23];
  const float* f_wo  = (const float*)d_in[24];

  const size_t SEL1 = 32768;
  const size_t PART = (size_t)2048 * 1024;

  char* w = (char*)d_ws;
  size_t off = 0;
  auto alloc = [&](size_t bytes) -> char* {
    off = (off + 255) & ~(size_t)255;
    char* p = w + off;
    off += bytes;
    return p;
  };
  unsigned short* wt  = (unsigned short*)alloc((size_t)8192 * 1024 * 2); // q,k,v,o,cq,ck,cv,co
  unsigned short* wc  = (unsigned short*)alloc((size_t)8192 * 1024 * 2); // interleaved wi0/wi1
  unsigned short* wot = (unsigned short*)alloc((size_t)1024 * 4096 * 2);
  unsigned short* encbf = (unsigned short*)alloc(2048 * 1024 * 2);
  float* rb = (float*)alloc(16 * 512 * 4);
  unsigned short* xn  = (unsigned short*)alloc(2048 * 1024 * 2);
  unsigned short* qbf = (unsigned short*)alloc(2048 * 1024 * 2);
  unsigned short* kbf = (unsigned short*)alloc(2048 * 1024 * 2);
  unsigned short* vtb = (unsigned short*)alloc((size_t)64 * 64 * 512 * 2);
  unsigned short* kbf2 = (unsigned short*)alloc(2048 * 1024 * 2);
  unsigned short* vtb2 = (unsigned short*)alloc((size_t)64 * 64 * 512 * 2);
  unsigned short* lowext_s = (unsigned short*)alloc(2048 * 128 * 2);
  unsigned short* lowext_c = (unsigned short*)alloc(2048 * 128 * 2);
  unsigned short* lowext_q = (unsigned short*)alloc(2048 * 128 * 2);
  unsigned short* lowext_o = (unsigned short*)alloc(2048 * 128 * 2);
  unsigned short* bmext_s  = (unsigned short*)alloc((size_t)4 * 3072 * 128 * 2);
  unsigned short* bmext_c  = (unsigned short*)alloc((size_t)4 * 2048 * 128 * 2);
  unsigned short* bmext_q  = (unsigned short*)alloc((size_t)4 * 1024 * 128 * 2);
  unsigned short* bmext_o  = (unsigned short*)alloc((size_t)4 * 1024 * 128 * 2);
  unsigned short* bmext_o2 = (unsigned short*)alloc((size_t)4 * 1024 * 128 * 2);
  unsigned short* ctxb = (unsigned short*)alloc(2048 * 1024 * 2);
  float* xres = (float*)alloc(2048 * 1024 * 4);
  float* yres = (float*)alloc(2048 * 1024 * 4);
  char*  big  = alloc((size_t)84 << 20);
  // big aliases (stream-serial lifetimes):
  float* bqs  = (float*)big;                           // self QKV partials 2x[2048][3072] = 48 MB
  float* bqc  = (float*)(big + ((size_t)48 << 20));    // cross KV partials 2x[2048][2048] = 32 MB
  float* op_s = (float*)big;                           // self out-proj partials 4x8 MB
  float* qp_c = (float*)(big + ((size_t)32 << 20));    // cross-Q partials 4x8 MB
  float* op_c = (float*)big;                           // cross out-proj partials 4x8 MB
  unsigned short* hbf = (unsigned short*)big;          // 16 MB
  float* fp   = (float*)(big + ((size_t)16 << 20));    // final partials 4x8 MB
  (void)ws_size; (void)in_sizes; (void)n_in; (void)out_size;

  // ---- prep ----
  PrepArgs pa;
  int ts = 0;
  for (int i = 0; i < 8; ++i) {
    pa.src[i] = f_W[i]; pa.dst[i] = wt + (size_t)i * 1024 * 1024;
    pa.K[i] = 1024; pa.N[i] = 1024; pa.mode[i] = 0;
    pa.tstart[i] = ts; ts += 256;                     // (1024/64)^2
  }
  pa.src[8] = f_wi0; pa.dst[8] = wc; pa.K[8] = 1024; pa.N[8] = 4096; pa.mode[8] = 1;
  pa.tstart[8] = ts; ts += 1024;                      // 16 x 64
  pa.src[9] = f_wi1; pa.dst[9] = wc; pa.K[9] = 1024; pa.N[9] = 4096; pa.mode[9] = 2;
  pa.tstart[9] = ts; ts += 1024;
  pa.src[10] = f_wo; pa.dst[10] = wot; pa.K[10] = 4096; pa.N[10] = 1024; pa.mode[10] = 0;
  pa.tstart[10] = ts; ts += 1024;                     // 64 x 16
  pa.tstart[11] = ts;
  pa.nwt = ts;
  pa.encoded = f_encoded; pa.encbf = encbf;
  pa.table = f_table; pa.rb = rb;
  pa.nf2bf = 2048;
  pa.bmdst[0] = bmext_s;  pa.bmnrg[0] = 24;
  pa.bmsrc[0][0] = f_qb; pa.bmsrc[0][1] = f_kb; pa.bmsrc[0][2] = f_vb;
  pa.bmdst[1] = bmext_c;  pa.bmnrg[1] = 16;
  pa.bmsrc[1][0] = f_kb + SEL1; pa.bmsrc[1][1] = f_vb + SEL1; pa.bmsrc[1][2] = nullptr;
  pa.bmdst[2] = bmext_q;  pa.bmnrg[2] = 8;
  pa.bmsrc[2][0] = f_qb + SEL1; pa.bmsrc[2][1] = nullptr; pa.bmsrc[2][2] = nullptr;
  pa.bmdst[3] = bmext_o;  pa.bmnrg[3] = 8;
  pa.bmsrc[3][0] = f_ob; pa.bmsrc[3][1] = nullptr; pa.bmsrc[3][2] = nullptr;
  pa.bmdst[4] = bmext_o2; pa.bmnrg[4] = 8;
  pa.bmsrc[4][0] = f_ob + SEL1; pa.bmsrc[4][1] = nullptr; pa.bmsrc[4][2] = nullptr;
  int bs = 0;
  for (int m = 0; m < 5; ++m) { pa.bmstart[m] = bs; bs += pa.bmnrg[m] * 4; }
  pa.bmstart[5] = bs;
  pa.nbm = bs;
  pa.lca[0] = f_ka + SEL1; pa.lca[1] = f_va + SEL1;
  pa.lowc = lowext_c;
  int totblk = pa.nwt + pa.nf2bf + 32 + pa.nbm + 256;
  k_prep<<<dim3(totblk), dim3(256), 0, stream>>>(pa);

  // ---- self rms + lows ----
  k_start<<<dim3(256), dim3(256), 0, stream>>>(f_inputs, f_ln1, f_qa, f_ka, f_va, xn, lowext_s);

  // ---- big QKV: self (N=3072, S2) + crossKV (N=2048, S2) ----
  {
    GX g;
    const size_t PS = (size_t)2048 * 3072, PC = (size_t)2048 * 2048;
    g.s[0] = { xn, lowext_s, wt, bmext_s, bqs,            (size_t)3072 * 128, 3072, 24, 0, 9 };
    g.s[1] = { xn, lowext_s, wt, bmext_s, bqs + PS,       (size_t)3072 * 128, 3072, 24, 9, 18 };
    g.s[2] = { encbf, lowext_c, wt + (size_t)5120 * 1024, bmext_c, bqc,      (size_t)2048 * 128, 2048, 16, 0, 9 };
    g.s[3] = { encbf, lowext_c, wt + (size_t)5120 * 1024, bmext_c, bqc + PC, (size_t)2048 * 128, 2048, 16, 9, 18 };
    k_gemmx<<<dim3(24, 16, 4), dim3(256), 0, stream>>>(g);
  }
  k_qkvsum<<<dim3(256, 2), dim3(256), 0, stream>>>(bqs, bqc, qbf, kbf, kbf2);
  k_vtrans2<<<dim3(8, 64, 2), dim3(256), 0, stream>>>(bqs, bqc, vtb, vtb2);

  k_flash<true, false><<<dim3(8, 64), dim3(256), 0, stream>>>(qbf, nullptr, kbf, vtb, rb, ctxb);

  // ---- self out-proj (K-ext lora_o, S4) ----
  k_lowbf<<<dim3(256), dim3(256), 0, stream>>>(ctxb, f_oa, lowext_o);
  {
    GX g;
    for (int s = 0; s < 4; ++s)
      g.s[s] = { ctxb, lowext_o, wt + (size_t)3072 * 1024, bmext_o, op_s + (size_t)s * PART,
                 (size_t)1024 * 128, 1024, 8, s * 18 / 4, (s + 1) * 18 / 4 };
    k_gemmx<<<dim3(8, 16, 4), dim3(256), 0, stream>>>(g);
  }
  k_addbrms<true><<<dim3(256), dim3(256), 0, stream>>>(op_s, f_inputs, f_ln2, xres, xn,
                                                       f_qa + SEL1, lowext_q);

  // ---- cross-Q (K-ext, S4) ----
  {
    GX g;
    for (int s = 0; s < 4; ++s)
      g.s[s] = { xn, lowext_q, wt + (size_t)4096 * 1024, bmext_q, qp_c + (size_t)s * PART,
                 (size_t)1024 * 128, 1024, 8, s * 18 / 4, (s + 1) * 18 / 4 };
    k_gemmx<<<dim3(8, 16, 4), dim3(256), 0, stream>>>(g);
  }
  k_flash<false, true><<<dim3(8, 64), dim3(256), 0, stream>>>(nullptr, qp_c, kbf2, vtb2, rb, ctxb);

  // ---- cross out-proj (K-ext lora_o sel1, S4) ----
  k_lowbf<<<dim3(256), dim3(256), 0, stream>>>(ctxb, f_oa + SEL1, lowext_o);
  {
    GX g;
    for (int s = 0; s < 4; ++s)
      g.s[s] = { ctxb, lowext_o, wt + (size_t)7168 * 1024, bmext_o2, op_c + (size_t)s * PART,
                 (size_t)1024 * 128, 1024, 8, s * 18 / 4, (s + 1) * 18 / 4 };
    k_gemmx<<<dim3(8, 16, 4), dim3(256), 0, stream>>>(g);
  }
  k_addbrms<false><<<dim3(256), dim3(256), 0, stream>>>(op_c, xres, f_ln3, yres, xn,
                                                        nullptr, nullptr);

  // ---- MLP ----
  k_mlp<<<dim3(32, 16), dim3(512), 0, stream>>>(xn, wc, hbf);
  k_gemm1s<<<dim3(8, 16, 4), dim3(256), 0, stream>>>(hbf, wot, fp, PART, 1024, 4096, 4096, 1024);
  k_sum4<<<dim3(2048), dim3(256), 0, stream>>>(fp, PART, yres, (float*)d_out);
}